// Round 2
// baseline (731.093 us; speedup 1.0000x reference)
//
#include <hip/hip_runtime.h>
#include <cstdint>
#include <cstddef>

#define BB 2
#define SS 2048
#define DD 1024
#define HH 16
#define DKK 64

typedef __attribute__((ext_vector_type(8))) short short8x;
typedef __attribute__((ext_vector_type(4))) float f32x4;

__device__ __forceinline__ unsigned short f2b(float f) {
  union { float f; unsigned u; } v; v.f = f;
  unsigned r = (v.u + 0x7fffu + ((v.u >> 16) & 1u)) >> 16;  // RNE
  return (unsigned short)r;
}

// hot-path bf16: round-half-up, 2 VALU (vs ~5 for RNE). Used only for Ps probabilities.
__device__ __forceinline__ unsigned short f2b_fast(float f) {
  union { float f; unsigned u; } v; v.f = f;
  return (unsigned short)((v.u + 0x8000u) >> 16);
}

__device__ __forceinline__ f32x4 mfma16(short8x a, short8x b, f32x4 c) {
  return __builtin_amdgcn_mfma_f32_16x16x32_bf16(a, b, c, 0, 0, 0);
}

// Fragment-major Q/K layout (R5): frag (bh,rb,ks) at ((bh*128+rb)*2+ks)*512 + lane*8.
// V^T frag (bh,rbv,kc) at ((bh*4+rbv)*64+kc)*512 + lane*8.
// R6: fixed m=0. R7: K-split across 2 blocks + combine. R8: raw-HW transcendentals.
// R9 (this round, resubmit after infra failure): occupancy quantization fix.
// Grid is exactly 8 blocks/CU for both flash (2048 blocks) and probsmean (2048
// blocks); launch_bounds 6 (flash) / 3 (probsmean) forced 2 / 3 scheduling rounds
// with a ragged tail -> measured 47% occupancy with no saturated pipe.
// flash: VGPR=40 <= 64 so 8 blocks/CU is legal -> __launch_bounds__(256, 8) makes
// all 8 co-resident (1 round). probsmean: ~80 VGPRs rules out 8; (256, 4)
// (VGPR cap 128, no spill) turns rounds (3,3,2) into (4,4).
#define C1F 0.0225421076f  // (1/64)*log2e
#define C2F 0.0541010849f  // (0.3/8)*log2e

// ---------------- pack weights
__global__ void pack_w_kernel(const float* __restrict__ Wq_r, const float* __restrict__ Wq_i,
                              const float* __restrict__ Wk_r, const float* __restrict__ Wk_i,
                              const float* __restrict__ Wv, const float* __restrict__ Wo,
                              unsigned short* __restrict__ WcatT, unsigned short* __restrict__ WoT) {
  int gid = blockIdx.x * 256 + threadIdx.x;
  if (gid < 5120 * 2048) {
    int k = gid & 2047;
    int n = gid >> 11;
    int q = n >> 10, j = n & 1023;
    float v;
    if (k < 1024) {
      const float* src = (q == 0) ? Wq_r : (q == 1) ? Wq_i : (q == 2) ? Wk_r : (q == 3) ? Wk_i : Wv;
      v = src[k * 1024 + j];
    } else {
      int k2 = k - 1024;
      if (q == 0)      v = -Wq_i[k2 * 1024 + j];
      else if (q == 1) v =  Wq_r[k2 * 1024 + j];
      else if (q == 2) v = -Wk_i[k2 * 1024 + j];
      else if (q == 3) v =  Wk_r[k2 * 1024 + j];
      else             v = 0.0f;
    }
    WcatT[gid] = f2b(v);
  } else {
    int g2 = gid - 5120 * 2048;            // n*1024 + k
    int k = g2 & 1023, n = g2 >> 10;
    WoT[g2] = f2b(Wo[k * 1024 + n]);
  }
}

// ---------------- pack X: Xcat[4096][2048] = [z_real | z_imag] (bf16)
__global__ void pack_x_kernel(const float* __restrict__ zr, const float* __restrict__ zi,
                              unsigned short* __restrict__ X) {
  int gid = blockIdx.x * 256 + threadIdx.x;  // 4096*2048
  int k = gid & 2047, m = gid >> 11;
  float v = (k < 1024) ? zr[m * 1024 + k] : zi[m * 1024 + (k - 1024)];
  X[gid] = f2b(v);
}

// ---------------- projection GEMM: epilogue writes fragment-major Q/K and V^T
__global__ __launch_bounds__(256, 2) void gemm_proj_kernel(
    const unsigned short* __restrict__ A, const unsigned short* __restrict__ Bt,
    unsigned short* __restrict__ Qr, unsigned short* __restrict__ Qi,
    unsigned short* __restrict__ Kr, unsigned short* __restrict__ Ki,
    unsigned short* __restrict__ VT) {
  constexpr int K = 2048;
  __shared__ __attribute__((aligned(16))) unsigned short As[128][40];
  __shared__ __attribute__((aligned(16))) unsigned short Bs[128][40];
  const int tid = threadIdx.x;
  const int m0 = blockIdx.x * 128;
  const int n0 = blockIdx.y * 128;
  const int lane = tid & 63, wid = tid >> 6;
  const int l15 = lane & 15, quad = lane >> 4;
  const int wm = (wid & 1) * 64, wn = (wid >> 1) * 64;
  const int lrow = tid >> 1, lseg = (tid & 1) * 16;
  f32x4 acc[4][4] = {};
  const int4* ga = (const int4*)(A + (size_t)(m0 + lrow) * K + lseg);
  const int4* gb = (const int4*)(Bt + (size_t)(n0 + lrow) * K + lseg);
  for (int k0 = 0; k0 < K; k0 += 32) {
    int4 a0 = ga[0], a1 = ga[1];
    int4 b0 = gb[0], b1 = gb[1];
    __syncthreads();
    *(int4*)&As[lrow][lseg] = a0;  *(int4*)&As[lrow][lseg + 8] = a1;
    *(int4*)&Bs[lrow][lseg] = b0;  *(int4*)&Bs[lrow][lseg + 8] = b1;
    __syncthreads();
    short8x af[4], bfr[4];
#pragma unroll
    for (int i = 0; i < 4; i++) af[i]  = *(const short8x*)&As[wm + i * 16 + l15][quad * 8];
#pragma unroll
    for (int i = 0; i < 4; i++) bfr[i] = *(const short8x*)&Bs[wn + i * 16 + l15][quad * 8];
#pragma unroll
    for (int mi = 0; mi < 4; mi++)
#pragma unroll
      for (int ni = 0; ni < 4; ni++)
        acc[mi][ni] = mfma16(af[mi], bfr[ni], acc[mi][ni]);
    ga += 4; gb += 4;
  }
#pragma unroll
  for (int mi = 0; mi < 4; mi++) {
#pragma unroll
    for (int ni = 0; ni < 4; ni++) {
      int gn = n0 + wn + ni * 16 + l15;
      if (gn < 4096) {
        int which = gn >> 10, j = gn & 1023, h = j >> 6, dk = j & 63;
        int ks = dk >> 5, q = (dk >> 3) & 3, e = dk & 7;
        unsigned short* dst = (which == 0) ? Qr : (which == 1) ? Qi : (which == 2) ? Kr : Ki;
#pragma unroll
        for (int r = 0; r < 4; r++) {
          int gm = m0 + wm + mi * 16 + quad * 4 + r;
          int b = gm >> 11, s = gm & 2047;
          int bh = b * HH + h, rb = s >> 4, l = s & 15;
          dst[(size_t)(((bh * 128 + rb) * 2 + ks) * 512 + (q * 16 + l) * 8 + e)] = f2b(acc[mi][ni][r]);
        }
      } else {
        int j = gn - 4096, h = j >> 6, dk = j & 63;
        int rbv = dk >> 4, lv = dk & 15;
#pragma unroll
        for (int r = 0; r < 4; r++) {
          int gm = m0 + wm + mi * 16 + quad * 4 + r;
          int b = gm >> 11, s = gm & 2047;
          int bh = b * HH + h, kc = s >> 5, qv = (s >> 3) & 3, ev = s & 7;
          VT[(size_t)(((bh * 4 + rbv) * 64 + kc) * 512 + (qv * 16 + lv) * 8 + ev)] = f2b(acc[mi][ni][r]);
        }
      }
    }
  }
}

// ---------------- flash attention, fixed-m, K-range split, raw-HW transcendentals
// R9: launch_bounds 6->8. Grid = 2048 blocks = exactly 8/CU; VGPR=40 and LDS=9216B
// both allow 8 resident. At 6 resident the scheduler ran rounds (6,2) -> makespan
// 2x block-time, measured occupancy 47% with MfmaUtil 21 / VALU 40 (nothing
// saturated). 8 resident = one round.
__global__ __launch_bounds__(256, 8) void flash_kernel(
    const unsigned short* __restrict__ Qr, const unsigned short* __restrict__ Qi,
    const unsigned short* __restrict__ Kr, const unsigned short* __restrict__ Ki,
    const unsigned short* __restrict__ VT, const int* __restrict__ mask,
    float* __restrict__ ctxP0, float* __restrict__ ctxP1,
    float* __restrict__ Lp0, float* __restrict__ Lp1) {
  __shared__ __attribute__((aligned(16))) unsigned short Ps[4][16][72];
  const int tid = threadIdx.x;
  const int lane = tid & 63, wid = tid >> 6;
  const int l15 = lane & 15, quad = lane >> 4;
  const int qt = blockIdx.x * 64;
  const int h = blockIdx.y;
  const int b = blockIdx.z >> 1, half = blockIdx.z & 1;
  const int bh = b * HH + h;
  float* __restrict__ cp = half ? ctxP1 : ctxP0;
  float* __restrict__ lp = half ? Lp1 : Lp0;
  const int rb = (qt >> 4) + wid;
  const int qbase = (bh * 128 + rb) * 1024 + lane * 8;
  short8x fqr0 = *(const short8x*)(Qr + qbase);
  short8x fqr1 = *(const short8x*)(Qr + qbase + 512);
  short8x fqi0 = *(const short8x*)(Qi + qbase);
  short8x fqi1 = *(const short8x*)(Qi + qbase + 512);
  f32x4 ctxacc[4] = {};
  float lsum[4] = {0.f, 0.f, 0.f, 0.f};

  const int kt0 = half * 1024;
  for (int kt = kt0; kt < kt0 + 1024; kt += 64) {
#pragma unroll
    for (int nb = 0; nb < 4; nb++) {
      float mkf = (float)mask[b * SS + kt + nb * 16 + l15];
      const int koff = (bh * 128 + (kt >> 4) + nb) * 1024 + lane * 8;
      short8x bkr0 = *(const short8x*)(Kr + koff);
      short8x bkr1 = *(const short8x*)(Kr + koff + 512);
      short8x bki0 = *(const short8x*)(Ki + koff);
      short8x bki1 = *(const short8x*)(Ki + koff + 512);
      f32x4 sr = {0.f, 0.f, 0.f, 0.f};
      sr = mfma16(fqr0, bkr0, sr);  sr = mfma16(fqr1, bkr1, sr);
      sr = mfma16(fqi0, bki0, sr);  sr = mfma16(fqi1, bki1, sr);
      f32x4 sa = {0.f, 0.f, 0.f, 0.f};
      sa = mfma16(fqi0, bkr0, sa);  sa = mfma16(fqi1, bkr1, sa);
      f32x4 sb = {0.f, 0.f, 0.f, 0.f};
      sb = mfma16(fqr0, bki0, sb);  sb = mfma16(fqr1, bki1, sb);
#pragma unroll
      for (int r = 0; r < 4; r++) {
        float a = sr[r];
        float d = sa[r] - sb[r];
        float r2 = __builtin_fmaf(a, a, d * d);
        float inv = __builtin_amdgcn_rsqf(r2);
        float arg = inv * __builtin_fmaf(C1F, r2, C2F * a);
        float p = mkf * __builtin_amdgcn_exp2f(arg);
        lsum[r] += p;
        Ps[wid][quad * 4 + r][nb * 16 + l15] = f2b_fast(p);
      }
    }
    // PV (Ps per-wave; lgkmcnt wait suffices, no barrier)
#pragma unroll
    for (int ks = 0; ks < 2; ks++)
#pragma unroll
      for (int db = 0; db < 4; db++) {
        int voff = ((bh * 4 + db) * 64 + (kt >> 5) + ks) * 512 + lane * 8;
        short8x bv = *(const short8x*)(VT + voff);
        short8x ap = *(const short8x*)&Ps[wid][l15][ks * 32 + quad * 8];
        ctxacc[db] = mfma16(ap, bv, ctxacc[db]);
      }
  }
  // reduce partial l over the 16 column-lanes
#pragma unroll
  for (int r = 0; r < 4; r++) {
#pragma unroll
    for (int off = 1; off < 16; off <<= 1) lsum[r] += __shfl_xor(lsum[r], off, 64);
  }
#pragma unroll
  for (int r = 0; r < 4; r++) {
    int s = qt + wid * 16 + quad * 4 + r;
#pragma unroll
    for (int db = 0; db < 4; db++)
      cp[((size_t)b * SS + s) * DD + h * DKK + db * 16 + l15] = ctxacc[db][r];
    if (l15 == 0) lp[(size_t)bh * SS + s] = lsum[r];
  }
}

// ---------------- combine: ctx_bf16 = (P0+P1) / (L0+L1)
__global__ __launch_bounds__(256) void combine_kernel(
    const float* __restrict__ ctxP0, const float* __restrict__ ctxP1,
    const float* __restrict__ Lp0, const float* __restrict__ Lp1,
    unsigned short* __restrict__ ctx) {
  int idx = blockIdx.x * 256 + threadIdx.x;   // 1048576 threads
  int g = idx * 4;
  int c = g & 1023, s = (g >> 10) & 2047, b = g >> 21;
  int h = c >> 6;
  size_t loff = (size_t)(b * HH + h) * SS + s;
  float linv = 1.0f / (Lp0[loff] + Lp1[loff]);
  float4 p0 = *(const float4*)(ctxP0 + g);
  float4 p1 = *(const float4*)(ctxP1 + g);
  ushort4 o;
  o.x = f2b((p0.x + p1.x) * linv);
  o.y = f2b((p0.y + p1.y) * linv);
  o.z = f2b((p0.z + p1.z) * linv);
  o.w = f2b((p0.w + p1.w) * linv);
  *(ushort4*)(ctx + g) = o;
}

// ---------------- output GEMM: out = ctx @ WoT^T + bias (unchanged)
__global__ __launch_bounds__(256, 2) void gemm_out_kernel(
    const unsigned short* __restrict__ A, const unsigned short* __restrict__ Bt,
    const float* __restrict__ bias, float* __restrict__ out) {
  constexpr int K = 1024;
  __shared__ __attribute__((aligned(16))) unsigned short As[128][40];
  __shared__ __attribute__((aligned(16))) unsigned short Bs[128][40];
  const int tid = threadIdx.x;
  const int m0 = blockIdx.x * 128;
  const int n0 = blockIdx.y * 128;
  const int lane = tid & 63, wid = tid >> 6;
  const int l15 = lane & 15, quad = lane >> 4;
  const int wm = (wid & 1) * 64, wn = (wid >> 1) * 64;
  const int lrow = tid >> 1, lseg = (tid & 1) * 16;
  f32x4 acc[4][4] = {};
  const int4* ga = (const int4*)(A + (size_t)(m0 + lrow) * K + lseg);
  const int4* gb = (const int4*)(Bt + (size_t)(n0 + lrow) * K + lseg);
  for (int k0 = 0; k0 < K; k0 += 32) {
    int4 a0 = ga[0], a1 = ga[1];
    int4 b0 = gb[0], b1 = gb[1];
    __syncthreads();
    *(int4*)&As[lrow][lseg] = a0;  *(int4*)&As[lrow][lseg + 8] = a1;
    *(int4*)&Bs[lrow][lseg] = b0;  *(int4*)&Bs[lrow][lseg + 8] = b1;
    __syncthreads();
    short8x af[4], bfr[4];
#pragma unroll
    for (int i = 0; i < 4; i++) af[i]  = *(const short8x*)&As[wm + i * 16 + l15][quad * 8];
#pragma unroll
    for (int i = 0; i < 4; i++) bfr[i] = *(const short8x*)&Bs[wn + i * 16 + l15][quad * 8];
#pragma unroll
    for (int mi = 0; mi < 4; mi++)
#pragma unroll
      for (int ni = 0; ni < 4; ni++)
        acc[mi][ni] = mfma16(af[mi], bfr[ni], acc[mi][ni]);
    ga += 4; gb += 4;
  }
#pragma unroll
  for (int mi = 0; mi < 4; mi++)
#pragma unroll
    for (int ni = 0; ni < 4; ni++) {
      int gn = n0 + wn + ni * 16 + l15;
      float bv = bias[gn];
#pragma unroll
      for (int r = 0; r < 4; r++) {
        int gm = m0 + wm + mi * 16 + quad * 4 + r;
        out[(size_t)gm * 1024 + gn] = acc[mi][ni][r] + bv;
      }
    }
}

// ---------------- probs_mean: fragment-major, fixed m=0, raw-HW transcendentals
// R9: launch_bounds 3->4. Grid = 2048 blocks = 8/CU; at 3 resident the rounds are
// (3,3,2) -> makespan 3x block-time (~33% occupancy). 4 resident (VGPR cap 128,
// ~80 live regs so no spill) gives exact rounds (4,4) -> makespan 2x. 8 would need
// VGPR<=64 and would spill the h-loop state.
__global__ __launch_bounds__(256, 4) void probsmean_kernel(
    const unsigned short* __restrict__ Qr, const unsigned short* __restrict__ Qi,
    const unsigned short* __restrict__ Kr, const unsigned short* __restrict__ Ki,
    const int* __restrict__ mask, const float* __restrict__ Lp0, const float* __restrict__ Lp1,
    float* __restrict__ out2) {
  const int tid = threadIdx.x, lane = tid & 63, wid = tid >> 6;
  const int l15 = lane & 15, quad = lane >> 4;
  const int qt = blockIdx.x * 64;
  const int kt = blockIdx.y * 64;
  const int b = blockIdx.z;
  const int qrow0 = qt + wid * 16;
  const int qrb = (qt >> 4) + wid;
  const int ktb = kt >> 4;
  float mkf[4];
#pragma unroll
  for (int nb = 0; nb < 4; nb++) mkf[nb] = (float)mask[b * SS + kt + nb * 16 + l15];
  float psum[4][4] = {};  // [nb][r]
  for (int h = 0; h < HH; h++) {
    const int bh = b * HH + h;
    const int qoff = (bh * 128 + qrb) * 1024 + lane * 8;
    short8x fqr0 = *(const short8x*)(Qr + qoff);
    short8x fqr1 = *(const short8x*)(Qr + qoff + 512);
    short8x fqi0 = *(const short8x*)(Qi + qoff);
    short8x fqi1 = *(const short8x*)(Qi + qoff + 512);
    const float4 lv0 = *(const float4*)(Lp0 + (size_t)bh * SS + qrow0 + quad * 4);
    const float4 lv1 = *(const float4*)(Lp1 + (size_t)bh * SS + qrow0 + quad * 4);
    float li[4];
    li[0] = 1.0f / (lv0.x + lv1.x); li[1] = 1.0f / (lv0.y + lv1.y);
    li[2] = 1.0f / (lv0.z + lv1.z); li[3] = 1.0f / (lv0.w + lv1.w);
#pragma unroll
    for (int nb = 0; nb < 4; nb++) {
      const int koff = (bh * 128 + ktb + nb) * 1024 + lane * 8;
      short8x bkr0 = *(const short8x*)(Kr + koff);
      short8x bkr1 = *(const short8x*)(Kr + koff + 512);
      short8x bki0 = *(const short8x*)(Ki + koff);
      short8x bki1 = *(const short8x*)(Ki + koff + 512);
      f32x4 sr = {0.f, 0.f, 0.f, 0.f};
      sr = mfma16(fqr0, bkr0, sr);  sr = mfma16(fqr1, bkr1, sr);
      sr = mfma16(fqi0, bki0, sr);  sr = mfma16(fqi1, bki1, sr);
      f32x4 sa = {0.f, 0.f, 0.f, 0.f};  // Qi.Kr
      sa = mfma16(fqi0, bkr0, sa);  sa = mfma16(fqi1, bkr1, sa);
      f32x4 sb = {0.f, 0.f, 0.f, 0.f};  // Qr.Ki
      sb = mfma16(fqr0, bki0, sb);  sb = mfma16(fqr1, bki1, sb);
#pragma unroll
      for (int r = 0; r < 4; r++) {
        float a = sr[r];
        float d = sa[r] - sb[r];
        float r2 = __builtin_fmaf(a, a, d * d);
        float inv = __builtin_amdgcn_rsqf(r2);
        float arg = inv * __builtin_fmaf(C1F, r2, C2F * a);
        float p = mkf[nb] * __builtin_amdgcn_exp2f(arg) * li[r];
        psum[nb][r] += p;
      }
    }
  }
#pragma unroll
  for (int nb = 0; nb < 4; nb++)
#pragma unroll
    for (int r = 0; r < 4; r++) {
      int qrow = qrow0 + quad * 4 + r;
      out2[((size_t)b * SS + qrow) * SS + kt + nb * 16 + l15] = psum[nb][r] * 0.0625f;
    }
}

extern "C" void kernel_launch(void* const* d_in, const int* in_sizes, int n_in,
                              void* d_out, int out_size, void* d_ws, size_t ws_size,
                              hipStream_t stream) {
  const float* z_real = (const float*)d_in[0];
  const float* z_imag = (const float*)d_in[1];
  const float* Wq_r = (const float*)d_in[2];
  const float* Wq_i = (const float*)d_in[3];
  const float* Wk_r = (const float*)d_in[4];
  const float* Wk_i = (const float*)d_in[5];
  const float* Wv   = (const float*)d_in[6];
  const float* Wo_w = (const float*)d_in[7];
  const float* Wo_b = (const float*)d_in[8];
  const int*   mask = (const int*)d_in[9];
  char* ws = (char*)d_ws;

  // ws layout (bytes). ctxP0/ctxP1 ALIAS WcatT/Xcat: dead after gemm_proj (stream-serial).
  constexpr size_t QKV_BYTES = 8388608;  // B*H*S*DK*2
  unsigned short* Qr   = (unsigned short*)(ws + 0);
  unsigned short* Qi   = (unsigned short*)(ws + QKV_BYTES);
  unsigned short* Kr   = (unsigned short*)(ws + 2 * QKV_BYTES);
  unsigned short* Ki   = (unsigned short*)(ws + 3 * QKV_BYTES);
  unsigned short* VT   = (unsigned short*)(ws + 4 * QKV_BYTES);
  unsigned short* ctx  = (unsigned short*)(ws + 5 * QKV_BYTES);              // 8 MB bf16
  unsigned short* WcatT= (unsigned short*)(ws + 50331648);                   // 20 MB
  unsigned short* WoT  = (unsigned short*)(ws + 71303168);                   // 2 MB
  unsigned short* Xcat = (unsigned short*)(ws + 73400320);                   // 16 MB
  float* ctxP0 = (float*)(ws + 50331648);                                    // aliases WcatT (16 MB)
  float* ctxP1 = (float*)(ws + 73400320);                                    // aliases Xcat (16 MB)
  float* Lp0   = (float*)(ws + 90177536);                                    // 256 KB
  float* Lp1   = (float*)(ws + 90439680);                                    // 256 KB

  float* out  = (float*)d_out;
  float* out2 = out + (size_t)BB * SS * DD;

  pack_w_kernel<<<dim3(45056), dim3(256), 0, stream>>>(Wq_r, Wq_i, Wk_r, Wk_i, Wv, Wo_w, WcatT, WoT);
  pack_x_kernel<<<dim3(32768), dim3(256), 0, stream>>>(z_real, z_imag, Xcat);
  gemm_proj_kernel<<<dim3(32, 40), dim3(256), 0, stream>>>(Xcat, WcatT, Qr, Qi, Kr, Ki, VT);
  flash_kernel<<<dim3(32, 16, 4), dim3(256), 0, stream>>>(Qr, Qi, Kr, Ki, VT, mask, ctxP0, ctxP1, Lp0, Lp1);
  combine_kernel<<<dim3(4096), dim3(256), 0, stream>>>(ctxP0, ctxP1, Lp0, Lp1, ctx);
  gemm_out_kernel<<<dim3(32, 8), dim3(256), 0, stream>>>(ctx, WoT, Wo_b, out);
  probsmean_kernel<<<dim3(32, 32, 2), dim3(256), 0, stream>>>(Qr, Qi, Kr, Ki, mask, Lp0, Lp1, out2);
}

// Round 3
// 588.995 us; speedup vs baseline: 1.2413x; 1.2413x over previous
//
#include <hip/hip_runtime.h>
#include <cstdint>
#include <cstddef>

#define BB 2
#define SS 2048
#define DD 1024
#define HH 16
#define DKK 64

typedef __attribute__((ext_vector_type(8))) short short8x;
typedef __attribute__((ext_vector_type(4))) float f32x4;

__device__ __forceinline__ unsigned short f2b(float f) {
  union { float f; unsigned u; } v; v.f = f;
  unsigned r = (v.u + 0x7fffu + ((v.u >> 16) & 1u)) >> 16;  // RNE
  return (unsigned short)r;
}

// hot-path bf16: round-half-up, 2 VALU (vs ~5 for RNE). Used only for Ps probabilities.
__device__ __forceinline__ unsigned short f2b_fast(float f) {
  union { float f; unsigned u; } v; v.f = f;
  return (unsigned short)((v.u + 0x8000u) >> 16);
}

__device__ __forceinline__ f32x4 mfma16(short8x a, short8x b, f32x4 c) {
  return __builtin_amdgcn_mfma_f32_16x16x32_bf16(a, b, c, 0, 0, 0);
}

// Fragment-major Q/K layout (R5): frag (bh,rb,ks) at ((bh*128+rb)*2+ks)*512 + lane*8.
// V^T frag (bh,rbv,kc) at ((bh*4+rbv)*64+kc)*512 + lane*8.
// R6: fixed m=0. R7: K-split across 2 blocks + combine. R8: raw-HW transcendentals.
// R9 FAILED: __launch_bounds__(256,8) on flash forced arch VGPR 40->32 -> scratch
// spill (FETCH 114->474 MB, WRITE 39->677 MB, dur 165->330us). 8 waves/EU needs
// total (arch+acc) <= 64 regs; flash needs ~56-64 and the allocator falls off the
// cliff. 7/EU gives rounds (7,1) = same 2-round makespan as (6,2): no bounds-only
// fix exists. REVERTED to (256,6).
// R10 (this round): XCD-aware block swizzle (T1). All hot grids are %8==0; remap
// lin -> (lin&7)*(nwg/8) + (lin>>3) so each XCD's round-robin slots receive a
// CONTIGUOUS chunk of work sharing K/V (flash: 8 heads x 384KB = 3MB < 4MB L2/XCD;
// probsmean: 8 kt-tiles x 256KB = 2MB; gemm_proj: B-panel resident). SALU-only.
#define C1F 0.0225421076f  // (1/64)*log2e
#define C2F 0.0541010849f  // (0.3/8)*log2e

// ---------------- pack weights
__global__ void pack_w_kernel(const float* __restrict__ Wq_r, const float* __restrict__ Wq_i,
                              const float* __restrict__ Wk_r, const float* __restrict__ Wk_i,
                              const float* __restrict__ Wv, const float* __restrict__ Wo,
                              unsigned short* __restrict__ WcatT, unsigned short* __restrict__ WoT) {
  int gid = blockIdx.x * 256 + threadIdx.x;
  if (gid < 5120 * 2048) {
    int k = gid & 2047;
    int n = gid >> 11;
    int q = n >> 10, j = n & 1023;
    float v;
    if (k < 1024) {
      const float* src = (q == 0) ? Wq_r : (q == 1) ? Wq_i : (q == 2) ? Wk_r : (q == 3) ? Wk_i : Wv;
      v = src[k * 1024 + j];
    } else {
      int k2 = k - 1024;
      if (q == 0)      v = -Wq_i[k2 * 1024 + j];
      else if (q == 1) v =  Wq_r[k2 * 1024 + j];
      else if (q == 2) v = -Wk_i[k2 * 1024 + j];
      else if (q == 3) v =  Wk_r[k2 * 1024 + j];
      else             v = 0.0f;
    }
    WcatT[gid] = f2b(v);
  } else {
    int g2 = gid - 5120 * 2048;            // n*1024 + k
    int k = g2 & 1023, n = g2 >> 10;
    WoT[g2] = f2b(Wo[k * 1024 + n]);
  }
}

// ---------------- pack X: Xcat[4096][2048] = [z_real | z_imag] (bf16)
__global__ void pack_x_kernel(const float* __restrict__ zr, const float* __restrict__ zi,
                              unsigned short* __restrict__ X) {
  int gid = blockIdx.x * 256 + threadIdx.x;  // 4096*2048
  int k = gid & 2047, m = gid >> 11;
  float v = (k < 1024) ? zr[m * 1024 + k] : zi[m * 1024 + (k - 1024)];
  X[gid] = f2b(v);
}

// ---------------- projection GEMM: epilogue writes fragment-major Q/K and V^T
__global__ __launch_bounds__(256, 2) void gemm_proj_kernel(
    const unsigned short* __restrict__ A, const unsigned short* __restrict__ Bt,
    unsigned short* __restrict__ Qr, unsigned short* __restrict__ Qi,
    unsigned short* __restrict__ Kr, unsigned short* __restrict__ Ki,
    unsigned short* __restrict__ VT) {
  constexpr int K = 2048;
  __shared__ __attribute__((aligned(16))) unsigned short As[128][40];
  __shared__ __attribute__((aligned(16))) unsigned short Bs[128][40];
  const int tid = threadIdx.x;
  // R10: XCD swizzle, nwg=1280 (%8==0), cpx=160
  int lin = blockIdx.x + 32 * blockIdx.y;
  lin = (lin & 7) * 160 + (lin >> 3);
  const int m0 = (lin & 31) * 128;
  const int n0 = (lin >> 5) * 128;
  const int lane = tid & 63, wid = tid >> 6;
  const int l15 = lane & 15, quad = lane >> 4;
  const int wm = (wid & 1) * 64, wn = (wid >> 1) * 64;
  const int lrow = tid >> 1, lseg = (tid & 1) * 16;
  f32x4 acc[4][4] = {};
  const int4* ga = (const int4*)(A + (size_t)(m0 + lrow) * K + lseg);
  const int4* gb = (const int4*)(Bt + (size_t)(n0 + lrow) * K + lseg);
  for (int k0 = 0; k0 < K; k0 += 32) {
    int4 a0 = ga[0], a1 = ga[1];
    int4 b0 = gb[0], b1 = gb[1];
    __syncthreads();
    *(int4*)&As[lrow][lseg] = a0;  *(int4*)&As[lrow][lseg + 8] = a1;
    *(int4*)&Bs[lrow][lseg] = b0;  *(int4*)&Bs[lrow][lseg + 8] = b1;
    __syncthreads();
    short8x af[4], bfr[4];
#pragma unroll
    for (int i = 0; i < 4; i++) af[i]  = *(const short8x*)&As[wm + i * 16 + l15][quad * 8];
#pragma unroll
    for (int i = 0; i < 4; i++) bfr[i] = *(const short8x*)&Bs[wn + i * 16 + l15][quad * 8];
#pragma unroll
    for (int mi = 0; mi < 4; mi++)
#pragma unroll
      for (int ni = 0; ni < 4; ni++)
        acc[mi][ni] = mfma16(af[mi], bfr[ni], acc[mi][ni]);
    ga += 4; gb += 4;
  }
#pragma unroll
  for (int mi = 0; mi < 4; mi++) {
#pragma unroll
    for (int ni = 0; ni < 4; ni++) {
      int gn = n0 + wn + ni * 16 + l15;
      if (gn < 4096) {
        int which = gn >> 10, j = gn & 1023, h = j >> 6, dk = j & 63;
        int ks = dk >> 5, q = (dk >> 3) & 3, e = dk & 7;
        unsigned short* dst = (which == 0) ? Qr : (which == 1) ? Qi : (which == 2) ? Kr : Ki;
#pragma unroll
        for (int r = 0; r < 4; r++) {
          int gm = m0 + wm + mi * 16 + quad * 4 + r;
          int b = gm >> 11, s = gm & 2047;
          int bh = b * HH + h, rb = s >> 4, l = s & 15;
          dst[(size_t)(((bh * 128 + rb) * 2 + ks) * 512 + (q * 16 + l) * 8 + e)] = f2b(acc[mi][ni][r]);
        }
      } else {
        int j = gn - 4096, h = j >> 6, dk = j & 63;
        int rbv = dk >> 4, lv = dk & 15;
#pragma unroll
        for (int r = 0; r < 4; r++) {
          int gm = m0 + wm + mi * 16 + quad * 4 + r;
          int b = gm >> 11, s = gm & 2047;
          int bh = b * HH + h, kc = s >> 5, qv = (s >> 3) & 3, ev = s & 7;
          VT[(size_t)(((bh * 4 + rbv) * 64 + kc) * 512 + (qv * 16 + lv) * 8 + ev)] = f2b(acc[mi][ni][r]);
        }
      }
    }
  }
}

// ---------------- flash attention, fixed-m, K-range split, raw-HW transcendentals
// R10: reverted to (256,6) (R9's 8 spilled to scratch, see header). XCD swizzle:
// nwg=2048, cpx=256 -> each XCD handles 8 contiguous heads of one (b,half):
// K/V working set 8 x 384KB = 3MB, L2/XCD-resident.
__global__ __launch_bounds__(256, 6) void flash_kernel(
    const unsigned short* __restrict__ Qr, const unsigned short* __restrict__ Qi,
    const unsigned short* __restrict__ Kr, const unsigned short* __restrict__ Ki,
    const unsigned short* __restrict__ VT, const int* __restrict__ mask,
    float* __restrict__ ctxP0, float* __restrict__ ctxP1,
    float* __restrict__ Lp0, float* __restrict__ Lp1) {
  __shared__ __attribute__((aligned(16))) unsigned short Ps[4][16][72];
  const int tid = threadIdx.x;
  const int lane = tid & 63, wid = tid >> 6;
  const int l15 = lane & 15, quad = lane >> 4;
  // R10: XCD swizzle (bijective, 2048 % 8 == 0)
  int lin = blockIdx.x + 32 * (blockIdx.y + 16 * blockIdx.z);
  lin = ((lin & 7) << 8) | (lin >> 3);
  const int qt = (lin & 31) * 64;
  const int h = (lin >> 5) & 15;
  const int z = lin >> 9;
  const int b = z >> 1, half = z & 1;
  const int bh = b * HH + h;
  float* __restrict__ cp = half ? ctxP1 : ctxP0;
  float* __restrict__ lp = half ? Lp1 : Lp0;
  const int rb = (qt >> 4) + wid;
  const int qbase = (bh * 128 + rb) * 1024 + lane * 8;
  short8x fqr0 = *(const short8x*)(Qr + qbase);
  short8x fqr1 = *(const short8x*)(Qr + qbase + 512);
  short8x fqi0 = *(const short8x*)(Qi + qbase);
  short8x fqi1 = *(const short8x*)(Qi + qbase + 512);
  f32x4 ctxacc[4] = {};
  float lsum[4] = {0.f, 0.f, 0.f, 0.f};

  const int kt0 = half * 1024;
  for (int kt = kt0; kt < kt0 + 1024; kt += 64) {
#pragma unroll
    for (int nb = 0; nb < 4; nb++) {
      float mkf = (float)mask[b * SS + kt + nb * 16 + l15];
      const int koff = (bh * 128 + (kt >> 4) + nb) * 1024 + lane * 8;
      short8x bkr0 = *(const short8x*)(Kr + koff);
      short8x bkr1 = *(const short8x*)(Kr + koff + 512);
      short8x bki0 = *(const short8x*)(Ki + koff);
      short8x bki1 = *(const short8x*)(Ki + koff + 512);
      f32x4 sr = {0.f, 0.f, 0.f, 0.f};
      sr = mfma16(fqr0, bkr0, sr);  sr = mfma16(fqr1, bkr1, sr);
      sr = mfma16(fqi0, bki0, sr);  sr = mfma16(fqi1, bki1, sr);
      f32x4 sa = {0.f, 0.f, 0.f, 0.f};
      sa = mfma16(fqi0, bkr0, sa);  sa = mfma16(fqi1, bkr1, sa);
      f32x4 sb = {0.f, 0.f, 0.f, 0.f};
      sb = mfma16(fqr0, bki0, sb);  sb = mfma16(fqr1, bki1, sb);
#pragma unroll
      for (int r = 0; r < 4; r++) {
        float a = sr[r];
        float d = sa[r] - sb[r];
        float r2 = __builtin_fmaf(a, a, d * d);
        float inv = __builtin_amdgcn_rsqf(r2);
        float arg = inv * __builtin_fmaf(C1F, r2, C2F * a);
        float p = mkf * __builtin_amdgcn_exp2f(arg);
        lsum[r] += p;
        Ps[wid][quad * 4 + r][nb * 16 + l15] = f2b_fast(p);
      }
    }
    // PV (Ps per-wave; lgkmcnt wait suffices, no barrier)
#pragma unroll
    for (int ks = 0; ks < 2; ks++)
#pragma unroll
      for (int db = 0; db < 4; db++) {
        int voff = ((bh * 4 + db) * 64 + (kt >> 5) + ks) * 512 + lane * 8;
        short8x bv = *(const short8x*)(VT + voff);
        short8x ap = *(const short8x*)&Ps[wid][l15][ks * 32 + quad * 8];
        ctxacc[db] = mfma16(ap, bv, ctxacc[db]);
      }
  }
  // reduce partial l over the 16 column-lanes
#pragma unroll
  for (int r = 0; r < 4; r++) {
#pragma unroll
    for (int off = 1; off < 16; off <<= 1) lsum[r] += __shfl_xor(lsum[r], off, 64);
  }
#pragma unroll
  for (int r = 0; r < 4; r++) {
    int s = qt + wid * 16 + quad * 4 + r;
#pragma unroll
    for (int db = 0; db < 4; db++)
      cp[((size_t)b * SS + s) * DD + h * DKK + db * 16 + l15] = ctxacc[db][r];
    if (l15 == 0) lp[(size_t)bh * SS + s] = lsum[r];
  }
}

// ---------------- combine: ctx_bf16 = (P0+P1) / (L0+L1)
__global__ __launch_bounds__(256) void combine_kernel(
    const float* __restrict__ ctxP0, const float* __restrict__ ctxP1,
    const float* __restrict__ Lp0, const float* __restrict__ Lp1,
    unsigned short* __restrict__ ctx) {
  int idx = blockIdx.x * 256 + threadIdx.x;   // 1048576 threads
  int g = idx * 4;
  int c = g & 1023, s = (g >> 10) & 2047, b = g >> 21;
  int h = c >> 6;
  size_t loff = (size_t)(b * HH + h) * SS + s;
  float linv = 1.0f / (Lp0[loff] + Lp1[loff]);
  float4 p0 = *(const float4*)(ctxP0 + g);
  float4 p1 = *(const float4*)(ctxP1 + g);
  ushort4 o;
  o.x = f2b((p0.x + p1.x) * linv);
  o.y = f2b((p0.y + p1.y) * linv);
  o.z = f2b((p0.z + p1.z) * linv);
  o.w = f2b((p0.w + p1.w) * linv);
  *(ushort4*)(ctx + g) = o;
}

// ---------------- output GEMM: out = ctx @ WoT^T + bias
__global__ __launch_bounds__(256, 2) void gemm_out_kernel(
    const unsigned short* __restrict__ A, const unsigned short* __restrict__ Bt,
    const float* __restrict__ bias, float* __restrict__ out) {
  constexpr int K = 1024;
  __shared__ __attribute__((aligned(16))) unsigned short As[128][40];
  __shared__ __attribute__((aligned(16))) unsigned short Bs[128][40];
  const int tid = threadIdx.x;
  // R10: XCD swizzle, nwg=256 (%8==0), cpx=32
  int lin = blockIdx.x + 32 * blockIdx.y;
  lin = (lin & 7) * 32 + (lin >> 3);
  const int m0 = (lin & 31) * 128;
  const int n0 = (lin >> 5) * 128;
  const int lane = tid & 63, wid = tid >> 6;
  const int l15 = lane & 15, quad = lane >> 4;
  const int wm = (wid & 1) * 64, wn = (wid >> 1) * 64;
  const int lrow = tid >> 1, lseg = (tid & 1) * 16;
  f32x4 acc[4][4] = {};
  const int4* ga = (const int4*)(A + (size_t)(m0 + lrow) * K + lseg);
  const int4* gb = (const int4*)(Bt + (size_t)(n0 + lrow) * K + lseg);
  for (int k0 = 0; k0 < K; k0 += 32) {
    int4 a0 = ga[0], a1 = ga[1];
    int4 b0 = gb[0], b1 = gb[1];
    __syncthreads();
    *(int4*)&As[lrow][lseg] = a0;  *(int4*)&As[lrow][lseg + 8] = a1;
    *(int4*)&Bs[lrow][lseg] = b0;  *(int4*)&Bs[lrow][lseg + 8] = b1;
    __syncthreads();
    short8x af[4], bfr[4];
#pragma unroll
    for (int i = 0; i < 4; i++) af[i]  = *(const short8x*)&As[wm + i * 16 + l15][quad * 8];
#pragma unroll
    for (int i = 0; i < 4; i++) bfr[i] = *(const short8x*)&Bs[wn + i * 16 + l15][quad * 8];
#pragma unroll
    for (int mi = 0; mi < 4; mi++)
#pragma unroll
      for (int ni = 0; ni < 4; ni++)
        acc[mi][ni] = mfma16(af[mi], bfr[ni], acc[mi][ni]);
    ga += 4; gb += 4;
  }
#pragma unroll
  for (int mi = 0; mi < 4; mi++)
#pragma unroll
    for (int ni = 0; ni < 4; ni++) {
      int gn = n0 + wn + ni * 16 + l15;
      float bv = bias[gn];
#pragma unroll
      for (int r = 0; r < 4; r++) {
        int gm = m0 + wm + mi * 16 + quad * 4 + r;
        out[(size_t)gm * 1024 + gn] = acc[mi][ni][r] + bv;
      }
    }
}

// ---------------- probs_mean: fragment-major, fixed m=0, raw-HW transcendentals
// R9 kept: (256,4) -> rounds (4,4) instead of (3,3,2); non-flash delta in R2 was
// -7us, so this is neutral-to-positive. R10: XCD swizzle, cpx=256 -> each XCD gets
// 8 contiguous kt-tiles of one b: K working set 2MB, L2-resident.
__global__ __launch_bounds__(256, 4) void probsmean_kernel(
    const unsigned short* __restrict__ Qr, const unsigned short* __restrict__ Qi,
    const unsigned short* __restrict__ Kr, const unsigned short* __restrict__ Ki,
    const int* __restrict__ mask, const float* __restrict__ Lp0, const float* __restrict__ Lp1,
    float* __restrict__ out2) {
  const int tid = threadIdx.x, lane = tid & 63, wid = tid >> 6;
  const int l15 = lane & 15, quad = lane >> 4;
  // R10: XCD swizzle (bijective, 2048 % 8 == 0)
  int lin = blockIdx.x + 32 * (blockIdx.y + 32 * blockIdx.z);
  lin = ((lin & 7) << 8) | (lin >> 3);
  const int qt = (lin & 31) * 64;
  const int kt = ((lin >> 5) & 31) * 64;
  const int b = lin >> 10;
  const int qrow0 = qt + wid * 16;
  const int qrb = (qt >> 4) + wid;
  const int ktb = kt >> 4;
  float mkf[4];
#pragma unroll
  for (int nb = 0; nb < 4; nb++) mkf[nb] = (float)mask[b * SS + kt + nb * 16 + l15];
  float psum[4][4] = {};  // [nb][r]
  for (int h = 0; h < HH; h++) {
    const int bh = b * HH + h;
    const int qoff = (bh * 128 + qrb) * 1024 + lane * 8;
    short8x fqr0 = *(const short8x*)(Qr + qoff);
    short8x fqr1 = *(const short8x*)(Qr + qoff + 512);
    short8x fqi0 = *(const short8x*)(Qi + qoff);
    short8x fqi1 = *(const short8x*)(Qi + qoff + 512);
    const float4 lv0 = *(const float4*)(Lp0 + (size_t)bh * SS + qrow0 + quad * 4);
    const float4 lv1 = *(const float4*)(Lp1 + (size_t)bh * SS + qrow0 + quad * 4);
    float li[4];
    li[0] = 1.0f / (lv0.x + lv1.x); li[1] = 1.0f / (lv0.y + lv1.y);
    li[2] = 1.0f / (lv0.z + lv1.z); li[3] = 1.0f / (lv0.w + lv1.w);
#pragma unroll
    for (int nb = 0; nb < 4; nb++) {
      const int koff = (bh * 128 + ktb + nb) * 1024 + lane * 8;
      short8x bkr0 = *(const short8x*)(Kr + koff);
      short8x bkr1 = *(const short8x*)(Kr + koff + 512);
      short8x bki0 = *(const short8x*)(Ki + koff);
      short8x bki1 = *(const short8x*)(Ki + koff + 512);
      f32x4 sr = {0.f, 0.f, 0.f, 0.f};
      sr = mfma16(fqr0, bkr0, sr);  sr = mfma16(fqr1, bkr1, sr);
      sr = mfma16(fqi0, bki0, sr);  sr = mfma16(fqi1, bki1, sr);
      f32x4 sa = {0.f, 0.f, 0.f, 0.f};  // Qi.Kr
      sa = mfma16(fqi0, bkr0, sa);  sa = mfma16(fqi1, bkr1, sa);
      f32x4 sb = {0.f, 0.f, 0.f, 0.f};  // Qr.Ki
      sb = mfma16(fqr0, bki0, sb);  sb = mfma16(fqr1, bki1, sb);
#pragma unroll
      for (int r = 0; r < 4; r++) {
        float a = sr[r];
        float d = sa[r] - sb[r];
        float r2 = __builtin_fmaf(a, a, d * d);
        float inv = __builtin_amdgcn_rsqf(r2);
        float arg = inv * __builtin_fmaf(C1F, r2, C2F * a);
        float p = mkf[nb] * __builtin_amdgcn_exp2f(arg) * li[r];
        psum[nb][r] += p;
      }
    }
  }
#pragma unroll
  for (int nb = 0; nb < 4; nb++)
#pragma unroll
    for (int r = 0; r < 4; r++) {
      int qrow = qrow0 + quad * 4 + r;
      out2[((size_t)b * SS + qrow) * SS + kt + nb * 16 + l15] = psum[nb][r] * 0.0625f;
    }
}

extern "C" void kernel_launch(void* const* d_in, const int* in_sizes, int n_in,
                              void* d_out, int out_size, void* d_ws, size_t ws_size,
                              hipStream_t stream) {
  const float* z_real = (const float*)d_in[0];
  const float* z_imag = (const float*)d_in[1];
  const float* Wq_r = (const float*)d_in[2];
  const float* Wq_i = (const float*)d_in[3];
  const float* Wk_r = (const float*)d_in[4];
  const float* Wk_i = (const float*)d_in[5];
  const float* Wv   = (const float*)d_in[6];
  const float* Wo_w = (const float*)d_in[7];
  const float* Wo_b = (const float*)d_in[8];
  const int*   mask = (const int*)d_in[9];
  char* ws = (char*)d_ws;

  // ws layout (bytes). ctxP0/ctxP1 ALIAS WcatT/Xcat: dead after gemm_proj (stream-serial).
  constexpr size_t QKV_BYTES = 8388608;  // B*H*S*DK*2
  unsigned short* Qr   = (unsigned short*)(ws + 0);
  unsigned short* Qi   = (unsigned short*)(ws + QKV_BYTES);
  unsigned short* Kr   = (unsigned short*)(ws + 2 * QKV_BYTES);
  unsigned short* Ki   = (unsigned short*)(ws + 3 * QKV_BYTES);
  unsigned short* VT   = (unsigned short*)(ws + 4 * QKV_BYTES);
  unsigned short* ctx  = (unsigned short*)(ws + 5 * QKV_BYTES);              // 8 MB bf16
  unsigned short* WcatT= (unsigned short*)(ws + 50331648);                   // 20 MB
  unsigned short* WoT  = (unsigned short*)(ws + 71303168);                   // 2 MB
  unsigned short* Xcat = (unsigned short*)(ws + 73400320);                   // 16 MB
  float* ctxP0 = (float*)(ws + 50331648);                                    // aliases WcatT (16 MB)
  float* ctxP1 = (float*)(ws + 73400320);                                    // aliases Xcat (16 MB)
  float* Lp0   = (float*)(ws + 90177536);                                    // 256 KB
  float* Lp1   = (float*)(ws + 90439680);                                    // 256 KB

  float* out  = (float*)d_out;
  float* out2 = out + (size_t)BB * SS * DD;

  pack_w_kernel<<<dim3(45056), dim3(256), 0, stream>>>(Wq_r, Wq_i, Wk_r, Wk_i, Wv, Wo_w, WcatT, WoT);
  pack_x_kernel<<<dim3(32768), dim3(256), 0, stream>>>(z_real, z_imag, Xcat);
  gemm_proj_kernel<<<dim3(32, 40), dim3(256), 0, stream>>>(Xcat, WcatT, Qr, Qi, Kr, Ki, VT);
  flash_kernel<<<dim3(32, 16, 4), dim3(256), 0, stream>>>(Qr, Qi, Kr, Ki, VT, mask, ctxP0, ctxP1, Lp0, Lp1);
  combine_kernel<<<dim3(4096), dim3(256), 0, stream>>>(ctxP0, ctxP1, Lp0, Lp1, ctx);
  gemm_out_kernel<<<dim3(32, 8), dim3(256), 0, stream>>>(ctx, WoT, Wo_b, out);
  probsmean_kernel<<<dim3(32, 32, 2), dim3(256), 0, stream>>>(Qr, Qi, Kr, Ki, mask, Lp0, Lp1, out2);
}

// Round 4
// 570.731 us; speedup vs baseline: 1.2810x; 1.0320x over previous
//
#include <hip/hip_runtime.h>
#include <cstdint>
#include <cstddef>

#define BB 2
#define SS 2048
#define DD 1024
#define HH 16
#define DKK 64

typedef __attribute__((ext_vector_type(8))) short short8x;
typedef __attribute__((ext_vector_type(4))) float f32x4;

__device__ __forceinline__ unsigned short f2b(float f) {
  union { float f; unsigned u; } v; v.f = f;
  unsigned r = (v.u + 0x7fffu + ((v.u >> 16) & 1u)) >> 16;  // RNE
  return (unsigned short)r;
}

// hot-path bf16: round-half-up, 2 VALU (vs ~5 for RNE). Used only for Ps probabilities.
__device__ __forceinline__ unsigned short f2b_fast(float f) {
  union { float f; unsigned u; } v; v.f = f;
  return (unsigned short)((v.u + 0x8000u) >> 16);
}

__device__ __forceinline__ f32x4 mfma16(short8x a, short8x b, f32x4 c) {
  return __builtin_amdgcn_mfma_f32_16x16x32_bf16(a, b, c, 0, 0, 0);
}

// Fragment-major Q/K layout (R5): frag (bh,rb,ks) at ((bh*128+rb)*2+ks)*512 + lane*8.
// V^T frag (bh,rbv,kc) at ((bh*4+rbv)*64+kc)*512 + lane*8.
// R6: fixed m=0. R7: K-split across 2 blocks + combine. R8: raw-HW transcendentals.
// R9 FAILED: launch_bounds(256,8) on flash -> scratch spill. Reverted.
// R10: XCD swizzle on 4 kernels. flash WON (-10us, FETCH 114->32MB: K/V L2-resident).
//   gemm_proj/gemm_out/probsmean LOST (+25us total): their NATURAL round-robin
//   partition (fast grid dim mod 8) already gave each XCD a small resident working
//   set (probsmean: 4 qt-tiles = 1.25MB; gemm_proj: 4 m-tiles A = 2MB); the chunked
//   swizzle replaced it with an 8-16MB streamed set. REVERTED on those three.
// R11 (this round): gemm_proj launch_bounds (256,2)->(256,3). 1280 blocks = 5/CU;
//   at 2-resident rounds are (2,2,1) = ~2.5-3x block-time makespan. 3-resident
//   (VGPR cap 168 vs ~130 needed, no spill expected) -> rounds (3,2) = 2x.
#define C1F 0.0225421076f  // (1/64)*log2e
#define C2F 0.0541010849f  // (0.3/8)*log2e

// ---------------- pack weights
__global__ void pack_w_kernel(const float* __restrict__ Wq_r, const float* __restrict__ Wq_i,
                              const float* __restrict__ Wk_r, const float* __restrict__ Wk_i,
                              const float* __restrict__ Wv, const float* __restrict__ Wo,
                              unsigned short* __restrict__ WcatT, unsigned short* __restrict__ WoT) {
  int gid = blockIdx.x * 256 + threadIdx.x;
  if (gid < 5120 * 2048) {
    int k = gid & 2047;
    int n = gid >> 11;
    int q = n >> 10, j = n & 1023;
    float v;
    if (k < 1024) {
      const float* src = (q == 0) ? Wq_r : (q == 1) ? Wq_i : (q == 2) ? Wk_r : (q == 3) ? Wk_i : Wv;
      v = src[k * 1024 + j];
    } else {
      int k2 = k - 1024;
      if (q == 0)      v = -Wq_i[k2 * 1024 + j];
      else if (q == 1) v =  Wq_r[k2 * 1024 + j];
      else if (q == 2) v = -Wk_i[k2 * 1024 + j];
      else if (q == 3) v =  Wk_r[k2 * 1024 + j];
      else             v = 0.0f;
    }
    WcatT[gid] = f2b(v);
  } else {
    int g2 = gid - 5120 * 2048;            // n*1024 + k
    int k = g2 & 1023, n = g2 >> 10;
    WoT[g2] = f2b(Wo[k * 1024 + n]);
  }
}

// ---------------- pack X: Xcat[4096][2048] = [z_real | z_imag] (bf16)
__global__ void pack_x_kernel(const float* __restrict__ zr, const float* __restrict__ zi,
                              unsigned short* __restrict__ X) {
  int gid = blockIdx.x * 256 + threadIdx.x;  // 4096*2048
  int k = gid & 2047, m = gid >> 11;
  float v = (k < 1024) ? zr[m * 1024 + k] : zi[m * 1024 + (k - 1024)];
  X[gid] = f2b(v);
}

// ---------------- projection GEMM: epilogue writes fragment-major Q/K and V^T
// R11: (256,3) — see header. Swizzle reverted (natural round-robin = A-resident).
__global__ __launch_bounds__(256, 3) void gemm_proj_kernel(
    const unsigned short* __restrict__ A, const unsigned short* __restrict__ Bt,
    unsigned short* __restrict__ Qr, unsigned short* __restrict__ Qi,
    unsigned short* __restrict__ Kr, unsigned short* __restrict__ Ki,
    unsigned short* __restrict__ VT) {
  constexpr int K = 2048;
  __shared__ __attribute__((aligned(16))) unsigned short As[128][40];
  __shared__ __attribute__((aligned(16))) unsigned short Bs[128][40];
  const int tid = threadIdx.x;
  const int m0 = blockIdx.x * 128;
  const int n0 = blockIdx.y * 128;
  const int lane = tid & 63, wid = tid >> 6;
  const int l15 = lane & 15, quad = lane >> 4;
  const int wm = (wid & 1) * 64, wn = (wid >> 1) * 64;
  const int lrow = tid >> 1, lseg = (tid & 1) * 16;
  f32x4 acc[4][4] = {};
  const int4* ga = (const int4*)(A + (size_t)(m0 + lrow) * K + lseg);
  const int4* gb = (const int4*)(Bt + (size_t)(n0 + lrow) * K + lseg);
  for (int k0 = 0; k0 < K; k0 += 32) {
    int4 a0 = ga[0], a1 = ga[1];
    int4 b0 = gb[0], b1 = gb[1];
    __syncthreads();
    *(int4*)&As[lrow][lseg] = a0;  *(int4*)&As[lrow][lseg + 8] = a1;
    *(int4*)&Bs[lrow][lseg] = b0;  *(int4*)&Bs[lrow][lseg + 8] = b1;
    __syncthreads();
    short8x af[4], bfr[4];
#pragma unroll
    for (int i = 0; i < 4; i++) af[i]  = *(const short8x*)&As[wm + i * 16 + l15][quad * 8];
#pragma unroll
    for (int i = 0; i < 4; i++) bfr[i] = *(const short8x*)&Bs[wn + i * 16 + l15][quad * 8];
#pragma unroll
    for (int mi = 0; mi < 4; mi++)
#pragma unroll
      for (int ni = 0; ni < 4; ni++)
        acc[mi][ni] = mfma16(af[mi], bfr[ni], acc[mi][ni]);
    ga += 4; gb += 4;
  }
#pragma unroll
  for (int mi = 0; mi < 4; mi++) {
#pragma unroll
    for (int ni = 0; ni < 4; ni++) {
      int gn = n0 + wn + ni * 16 + l15;
      if (gn < 4096) {
        int which = gn >> 10, j = gn & 1023, h = j >> 6, dk = j & 63;
        int ks = dk >> 5, q = (dk >> 3) & 3, e = dk & 7;
        unsigned short* dst = (which == 0) ? Qr : (which == 1) ? Qi : (which == 2) ? Kr : Ki;
#pragma unroll
        for (int r = 0; r < 4; r++) {
          int gm = m0 + wm + mi * 16 + quad * 4 + r;
          int b = gm >> 11, s = gm & 2047;
          int bh = b * HH + h, rb = s >> 4, l = s & 15;
          dst[(size_t)(((bh * 128 + rb) * 2 + ks) * 512 + (q * 16 + l) * 8 + e)] = f2b(acc[mi][ni][r]);
        }
      } else {
        int j = gn - 4096, h = j >> 6, dk = j & 63;
        int rbv = dk >> 4, lv = dk & 15;
#pragma unroll
        for (int r = 0; r < 4; r++) {
          int gm = m0 + wm + mi * 16 + quad * 4 + r;
          int b = gm >> 11, s = gm & 2047;
          int bh = b * HH + h, kc = s >> 5, qv = (s >> 3) & 3, ev = s & 7;
          VT[(size_t)(((bh * 4 + rbv) * 64 + kc) * 512 + (qv * 16 + lv) * 8 + ev)] = f2b(acc[mi][ni][r]);
        }
      }
    }
  }
}

// ---------------- flash attention, fixed-m, K-range split, raw-HW transcendentals
// R10 (kept): XCD swizzle: nwg=2048, cpx=256 -> each XCD handles 8 contiguous heads
// of one (b,half): K/V working set 8 x 384KB = 3MB, L2/XCD-resident.
// Measured: FETCH 114->32MB, dur 165->155.5us.
__global__ __launch_bounds__(256, 6) void flash_kernel(
    const unsigned short* __restrict__ Qr, const unsigned short* __restrict__ Qi,
    const unsigned short* __restrict__ Kr, const unsigned short* __restrict__ Ki,
    const unsigned short* __restrict__ VT, const int* __restrict__ mask,
    float* __restrict__ ctxP0, float* __restrict__ ctxP1,
    float* __restrict__ Lp0, float* __restrict__ Lp1) {
  __shared__ __attribute__((aligned(16))) unsigned short Ps[4][16][72];
  const int tid = threadIdx.x;
  const int lane = tid & 63, wid = tid >> 6;
  const int l15 = lane & 15, quad = lane >> 4;
  // XCD swizzle (bijective, 2048 % 8 == 0)
  int lin = blockIdx.x + 32 * (blockIdx.y + 16 * blockIdx.z);
  lin = ((lin & 7) << 8) | (lin >> 3);
  const int qt = (lin & 31) * 64;
  const int h = (lin >> 5) & 15;
  const int z = lin >> 9;
  const int b = z >> 1, half = z & 1;
  const int bh = b * HH + h;
  float* __restrict__ cp = half ? ctxP1 : ctxP0;
  float* __restrict__ lp = half ? Lp1 : Lp0;
  const int rb = (qt >> 4) + wid;
  const int qbase = (bh * 128 + rb) * 1024 + lane * 8;
  short8x fqr0 = *(const short8x*)(Qr + qbase);
  short8x fqr1 = *(const short8x*)(Qr + qbase + 512);
  short8x fqi0 = *(const short8x*)(Qi + qbase);
  short8x fqi1 = *(const short8x*)(Qi + qbase + 512);
  f32x4 ctxacc[4] = {};
  float lsum[4] = {0.f, 0.f, 0.f, 0.f};

  const int kt0 = half * 1024;
  for (int kt = kt0; kt < kt0 + 1024; kt += 64) {
#pragma unroll
    for (int nb = 0; nb < 4; nb++) {
      float mkf = (float)mask[b * SS + kt + nb * 16 + l15];
      const int koff = (bh * 128 + (kt >> 4) + nb) * 1024 + lane * 8;
      short8x bkr0 = *(const short8x*)(Kr + koff);
      short8x bkr1 = *(const short8x*)(Kr + koff + 512);
      short8x bki0 = *(const short8x*)(Ki + koff);
      short8x bki1 = *(const short8x*)(Ki + koff + 512);
      f32x4 sr = {0.f, 0.f, 0.f, 0.f};
      sr = mfma16(fqr0, bkr0, sr);  sr = mfma16(fqr1, bkr1, sr);
      sr = mfma16(fqi0, bki0, sr);  sr = mfma16(fqi1, bki1, sr);
      f32x4 sa = {0.f, 0.f, 0.f, 0.f};
      sa = mfma16(fqi0, bkr0, sa);  sa = mfma16(fqi1, bkr1, sa);
      f32x4 sb = {0.f, 0.f, 0.f, 0.f};
      sb = mfma16(fqr0, bki0, sb);  sb = mfma16(fqr1, bki1, sb);
#pragma unroll
      for (int r = 0; r < 4; r++) {
        float a = sr[r];
        float d = sa[r] - sb[r];
        float r2 = __builtin_fmaf(a, a, d * d);
        float inv = __builtin_amdgcn_rsqf(r2);
        float arg = inv * __builtin_fmaf(C1F, r2, C2F * a);
        float p = mkf * __builtin_amdgcn_exp2f(arg);
        lsum[r] += p;
        Ps[wid][quad * 4 + r][nb * 16 + l15] = f2b_fast(p);
      }
    }
    // PV (Ps per-wave; lgkmcnt wait suffices, no barrier)
#pragma unroll
    for (int ks = 0; ks < 2; ks++)
#pragma unroll
      for (int db = 0; db < 4; db++) {
        int voff = ((bh * 4 + db) * 64 + (kt >> 5) + ks) * 512 + lane * 8;
        short8x bv = *(const short8x*)(VT + voff);
        short8x ap = *(const short8x*)&Ps[wid][l15][ks * 32 + quad * 8];
        ctxacc[db] = mfma16(ap, bv, ctxacc[db]);
      }
  }
  // reduce partial l over the 16 column-lanes
#pragma unroll
  for (int r = 0; r < 4; r++) {
#pragma unroll
    for (int off = 1; off < 16; off <<= 1) lsum[r] += __shfl_xor(lsum[r], off, 64);
  }
#pragma unroll
  for (int r = 0; r < 4; r++) {
    int s = qt + wid * 16 + quad * 4 + r;
#pragma unroll
    for (int db = 0; db < 4; db++)
      cp[((size_t)b * SS + s) * DD + h * DKK + db * 16 + l15] = ctxacc[db][r];
    if (l15 == 0) lp[(size_t)bh * SS + s] = lsum[r];
  }
}

// ---------------- combine: ctx_bf16 = (P0+P1) / (L0+L1)
__global__ __launch_bounds__(256) void combine_kernel(
    const float* __restrict__ ctxP0, const float* __restrict__ ctxP1,
    const float* __restrict__ Lp0, const float* __restrict__ Lp1,
    unsigned short* __restrict__ ctx) {
  int idx = blockIdx.x * 256 + threadIdx.x;   // 1048576 threads
  int g = idx * 4;
  int c = g & 1023, s = (g >> 10) & 2047, b = g >> 21;
  int h = c >> 6;
  size_t loff = (size_t)(b * HH + h) * SS + s;
  float linv = 1.0f / (Lp0[loff] + Lp1[loff]);
  float4 p0 = *(const float4*)(ctxP0 + g);
  float4 p1 = *(const float4*)(ctxP1 + g);
  ushort4 o;
  o.x = f2b((p0.x + p1.x) * linv);
  o.y = f2b((p0.y + p1.y) * linv);
  o.z = f2b((p0.z + p1.z) * linv);
  o.w = f2b((p0.w + p1.w) * linv);
  *(ushort4*)(ctx + g) = o;
}

// ---------------- output GEMM: out = ctx @ WoT^T + bias (swizzle reverted)
__global__ __launch_bounds__(256, 2) void gemm_out_kernel(
    const unsigned short* __restrict__ A, const unsigned short* __restrict__ Bt,
    const float* __restrict__ bias, float* __restrict__ out) {
  constexpr int K = 1024;
  __shared__ __attribute__((aligned(16))) unsigned short As[128][40];
  __shared__ __attribute__((aligned(16))) unsigned short Bs[128][40];
  const int tid = threadIdx.x;
  const int m0 = blockIdx.x * 128;
  const int n0 = blockIdx.y * 128;
  const int lane = tid & 63, wid = tid >> 6;
  const int l15 = lane & 15, quad = lane >> 4;
  const int wm = (wid & 1) * 64, wn = (wid >> 1) * 64;
  const int lrow = tid >> 1, lseg = (tid & 1) * 16;
  f32x4 acc[4][4] = {};
  const int4* ga = (const int4*)(A + (size_t)(m0 + lrow) * K + lseg);
  const int4* gb = (const int4*)(Bt + (size_t)(n0 + lrow) * K + lseg);
  for (int k0 = 0; k0 < K; k0 += 32) {
    int4 a0 = ga[0], a1 = ga[1];
    int4 b0 = gb[0], b1 = gb[1];
    __syncthreads();
    *(int4*)&As[lrow][lseg] = a0;  *(int4*)&As[lrow][lseg + 8] = a1;
    *(int4*)&Bs[lrow][lseg] = b0;  *(int4*)&Bs[lrow][lseg + 8] = b1;
    __syncthreads();
    short8x af[4], bfr[4];
#pragma unroll
    for (int i = 0; i < 4; i++) af[i]  = *(const short8x*)&As[wm + i * 16 + l15][quad * 8];
#pragma unroll
    for (int i = 0; i < 4; i++) bfr[i] = *(const short8x*)&Bs[wn + i * 16 + l15][quad * 8];
#pragma unroll
    for (int mi = 0; mi < 4; mi++)
#pragma unroll
      for (int ni = 0; ni < 4; ni++)
        acc[mi][ni] = mfma16(af[mi], bfr[ni], acc[mi][ni]);
    ga += 4; gb += 4;
  }
#pragma unroll
  for (int mi = 0; mi < 4; mi++)
#pragma unroll
    for (int ni = 0; ni < 4; ni++) {
      int gn = n0 + wn + ni * 16 + l15;
      float bv = bias[gn];
#pragma unroll
      for (int r = 0; r < 4; r++) {
        int gm = m0 + wm + mi * 16 + quad * 4 + r;
        out[(size_t)gm * 1024 + gn] = acc[mi][ni][r] + bv;
      }
    }
}

// ---------------- probs_mean: fragment-major, fixed m=0, raw-HW transcendentals
// R9 kept: (256,4) -> rounds (4,4). R10 swizzle REVERTED: natural round-robin gives
// each XCD qt = x mod 8 (4 qt-tiles, 1.25MB resident) — better than chunked.
__global__ __launch_bounds__(256, 4) void probsmean_kernel(
    const unsigned short* __restrict__ Qr, const unsigned short* __restrict__ Qi,
    const unsigned short* __restrict__ Kr, const unsigned short* __restrict__ Ki,
    const int* __restrict__ mask, const float* __restrict__ Lp0, const float* __restrict__ Lp1,
    float* __restrict__ out2) {
  const int tid = threadIdx.x, lane = tid & 63, wid = tid >> 6;
  const int l15 = lane & 15, quad = lane >> 4;
  const int qt = blockIdx.x * 64;
  const int kt = blockIdx.y * 64;
  const int b = blockIdx.z;
  const int qrow0 = qt + wid * 16;
  const int qrb = (qt >> 4) + wid;
  const int ktb = kt >> 4;
  float mkf[4];
#pragma unroll
  for (int nb = 0; nb < 4; nb++) mkf[nb] = (float)mask[b * SS + kt + nb * 16 + l15];
  float psum[4][4] = {};  // [nb][r]
  for (int h = 0; h < HH; h++) {
    const int bh = b * HH + h;
    const int qoff = (bh * 128 + qrb) * 1024 + lane * 8;
    short8x fqr0 = *(const short8x*)(Qr + qoff);
    short8x fqr1 = *(const short8x*)(Qr + qoff + 512);
    short8x fqi0 = *(const short8x*)(Qi + qoff);
    short8x fqi1 = *(const short8x*)(Qi + qoff + 512);
    const float4 lv0 = *(const float4*)(Lp0 + (size_t)bh * SS + qrow0 + quad * 4);
    const float4 lv1 = *(const float4*)(Lp1 + (size_t)bh * SS + qrow0 + quad * 4);
    float li[4];
    li[0] = 1.0f / (lv0.x + lv1.x); li[1] = 1.0f / (lv0.y + lv1.y);
    li[2] = 1.0f / (lv0.z + lv1.z); li[3] = 1.0f / (lv0.w + lv1.w);
#pragma unroll
    for (int nb = 0; nb < 4; nb++) {
      const int koff = (bh * 128 + ktb + nb) * 1024 + lane * 8;
      short8x bkr0 = *(const short8x*)(Kr + koff);
      short8x bkr1 = *(const short8x*)(Kr + koff + 512);
      short8x bki0 = *(const short8x*)(Ki + koff);
      short8x bki1 = *(const short8x*)(Ki + koff + 512);
      f32x4 sr = {0.f, 0.f, 0.f, 0.f};
      sr = mfma16(fqr0, bkr0, sr);  sr = mfma16(fqr1, bkr1, sr);
      sr = mfma16(fqi0, bki0, sr);  sr = mfma16(fqi1, bki1, sr);
      f32x4 sa = {0.f, 0.f, 0.f, 0.f};  // Qi.Kr
      sa = mfma16(fqi0, bkr0, sa);  sa = mfma16(fqi1, bkr1, sa);
      f32x4 sb = {0.f, 0.f, 0.f, 0.f};  // Qr.Ki
      sb = mfma16(fqr0, bki0, sb);  sb = mfma16(fqr1, bki1, sb);
#pragma unroll
      for (int r = 0; r < 4; r++) {
        float a = sr[r];
        float d = sa[r] - sb[r];
        float r2 = __builtin_fmaf(a, a, d * d);
        float inv = __builtin_amdgcn_rsqf(r2);
        float arg = inv * __builtin_fmaf(C1F, r2, C2F * a);
        float p = mkf[nb] * __builtin_amdgcn_exp2f(arg) * li[r];
        psum[nb][r] += p;
      }
    }
  }
#pragma unroll
  for (int nb = 0; nb < 4; nb++)
#pragma unroll
    for (int r = 0; r < 4; r++) {
      int qrow = qrow0 + quad * 4 + r;
      out2[((size_t)b * SS + qrow) * SS + kt + nb * 16 + l15] = psum[nb][r] * 0.0625f;
    }
}

extern "C" void kernel_launch(void* const* d_in, const int* in_sizes, int n_in,
                              void* d_out, int out_size, void* d_ws, size_t ws_size,
                              hipStream_t stream) {
  const float* z_real = (const float*)d_in[0];
  const float* z_imag = (const float*)d_in[1];
  const float* Wq_r = (const float*)d_in[2];
  const float* Wq_i = (const float*)d_in[3];
  const float* Wk_r = (const float*)d_in[4];
  const float* Wk_i = (const float*)d_in[5];
  const float* Wv   = (const float*)d_in[6];
  const float* Wo_w = (const float*)d_in[7];
  const float* Wo_b = (const float*)d_in[8];
  const int*   mask = (const int*)d_in[9];
  char* ws = (char*)d_ws;

  // ws layout (bytes). ctxP0/ctxP1 ALIAS WcatT/Xcat: dead after gemm_proj (stream-serial).
  constexpr size_t QKV_BYTES = 8388608;  // B*H*S*DK*2
  unsigned short* Qr   = (unsigned short*)(ws + 0);
  unsigned short* Qi   = (unsigned short*)(ws + QKV_BYTES);
  unsigned short* Kr   = (unsigned short*)(ws + 2 * QKV_BYTES);
  unsigned short* Ki   = (unsigned short*)(ws + 3 * QKV_BYTES);
  unsigned short* VT   = (unsigned short*)(ws + 4 * QKV_BYTES);
  unsigned short* ctx  = (unsigned short*)(ws + 5 * QKV_BYTES);              // 8 MB bf16
  unsigned short* WcatT= (unsigned short*)(ws + 50331648);                   // 20 MB
  unsigned short* WoT  = (unsigned short*)(ws + 71303168);                   // 2 MB
  unsigned short* Xcat = (unsigned short*)(ws + 73400320);                   // 16 MB
  float* ctxP0 = (float*)(ws + 50331648);                                    // aliases WcatT (16 MB)
  float* ctxP1 = (float*)(ws + 73400320);                                    // aliases Xcat (16 MB)
  float* Lp0   = (float*)(ws + 90177536);                                    // 256 KB
  float* Lp1   = (float*)(ws + 90439680);                                    // 256 KB

  float* out  = (float*)d_out;
  float* out2 = out + (size_t)BB * SS * DD;

  pack_w_kernel<<<dim3(45056), dim3(256), 0, stream>>>(Wq_r, Wq_i, Wk_r, Wk_i, Wv, Wo_w, WcatT, WoT);
  pack_x_kernel<<<dim3(32768), dim3(256), 0, stream>>>(z_real, z_imag, Xcat);
  gemm_proj_kernel<<<dim3(32, 40), dim3(256), 0, stream>>>(Xcat, WcatT, Qr, Qi, Kr, Ki, VT);
  flash_kernel<<<dim3(32, 16, 4), dim3(256), 0, stream>>>(Qr, Qi, Kr, Ki, VT, mask, ctxP0, ctxP1, Lp0, Lp1);
  combine_kernel<<<dim3(4096), dim3(256), 0, stream>>>(ctxP0, ctxP1, Lp0, Lp1, ctx);
  gemm_out_kernel<<<dim3(32, 8), dim3(256), 0, stream>>>(ctx, WoT, Wo_b, out);
  probsmean_kernel<<<dim3(32, 32, 2), dim3(256), 0, stream>>>(Qr, Qi, Kr, Ki, mask, Lp0, Lp1, out2);
}

// Round 5
// 492.373 us; speedup vs baseline: 1.4848x; 1.1591x over previous
//
#include <hip/hip_runtime.h>
#include <cstdint>
#include <cstddef>

#define BB 2
#define SS 2048
#define DD 1024
#define HH 16
#define DKK 64

typedef __attribute__((ext_vector_type(8))) short short8x;
typedef __attribute__((ext_vector_type(4))) float f32x4;

__device__ __forceinline__ unsigned short f2b(float f) {
  union { float f; unsigned u; } v; v.f = f;
  unsigned r = (v.u + 0x7fffu + ((v.u >> 16) & 1u)) >> 16;  // RNE
  return (unsigned short)r;
}

// hot-path bf16: round-half-up, 2 VALU (vs ~5 for RNE). Used only for Ps probabilities.
__device__ __forceinline__ unsigned short f2b_fast(float f) {
  union { float f; unsigned u; } v; v.f = f;
  return (unsigned short)((v.u + 0x8000u) >> 16);
}

__device__ __forceinline__ f32x4 mfma16(short8x a, short8x b, f32x4 c) {
  return __builtin_amdgcn_mfma_f32_16x16x32_bf16(a, b, c, 0, 0, 0);
}

// Fragment-major Q/K layout (R5): frag (bh,rb,ks) at ((bh*128+rb)*2+ks)*512 + lane*8.
// V^T frag (bh,rbv,kc) at ((bh*4+rbv)*64+kc)*512 + lane*8.
// R6: fixed m=0. R7: K-split across 2 blocks + combine. R8: raw-HW transcendentals.
// R9 FAILED: launch_bounds(256,8) flash spill. R10: XCD swizzle kept on flash only
// (FETCH 114->32MB, -10us); others reverted. R11: gemm_proj (256,3).
// R12 (this round): K-COMPACTION. mask is Bernoulli(0.5) per (b,k); masked columns
// are EXACT zeros in softmax and probs-mean. flash+probsmean (~275us, issue-bound)
// spend half their MFMA+transcendental work on them. Compact K/V per (b,half) to
// unmasked columns: mask_scan builds pos/idx/cnt tables (stored in d_out scratch --
// dead until gemm_out, probsmean reordered before combine). gemm_proj epilogue
// writes K/V to compacted slots; VT pre-zeroed (pad rows 0 so PV stays NaN-free);
// K pad garbage neutralized by SELECT (valid ? exp2 : 0), never multiply.
// out2 pre-zeroed (= reference value for masked cols); probsmean scatters valid
// columns via idx. Removed terms are exact zeros => bitwise-identical lsum; ctxacc
// MFMA regrouping shifts rounding ~1e-7 (margin 3.3x).
#define C1F 0.0225421076f  // (1/64)*log2e
#define C2F 0.0541010849f  // (0.3/8)*log2e

// ---------------- pack weights
__global__ void pack_w_kernel(const float* __restrict__ Wq_r, const float* __restrict__ Wq_i,
                              const float* __restrict__ Wk_r, const float* __restrict__ Wk_i,
                              const float* __restrict__ Wv, const float* __restrict__ Wo,
                              unsigned short* __restrict__ WcatT, unsigned short* __restrict__ WoT) {
  int gid = blockIdx.x * 256 + threadIdx.x;
  if (gid < 5120 * 2048) {
    int k = gid & 2047;
    int n = gid >> 11;
    int q = n >> 10, j = n & 1023;
    float v;
    if (k < 1024) {
      const float* src = (q == 0) ? Wq_r : (q == 1) ? Wq_i : (q == 2) ? Wk_r : (q == 3) ? Wk_i : Wv;
      v = src[k * 1024 + j];
    } else {
      int k2 = k - 1024;
      if (q == 0)      v = -Wq_i[k2 * 1024 + j];
      else if (q == 1) v =  Wq_r[k2 * 1024 + j];
      else if (q == 2) v = -Wk_i[k2 * 1024 + j];
      else if (q == 3) v =  Wk_r[k2 * 1024 + j];
      else             v = 0.0f;
    }
    WcatT[gid] = f2b(v);
  } else {
    int g2 = gid - 5120 * 2048;            // n*1024 + k
    int k = g2 & 1023, n = g2 >> 10;
    WoT[g2] = f2b(Wo[k * 1024 + n]);
  }
}

// ---------------- pack X: Xcat[4096][2048] = [z_real | z_imag] (bf16)
__global__ void pack_x_kernel(const float* __restrict__ zr, const float* __restrict__ zi,
                              unsigned short* __restrict__ X) {
  int gid = blockIdx.x * 256 + threadIdx.x;  // 4096*2048
  int k = gid & 2047, m = gid >> 11;
  float v = (k < 1024) ? zr[m * 1024 + k] : zi[m * 1024 + (k - 1024)];
  X[gid] = f2b(v);
}

// ---------------- generic zero (float4 granularity)
__global__ void zero_kernel(float4* __restrict__ p) {
  p[(size_t)blockIdx.x * 256 + threadIdx.x] = float4{0.f, 0.f, 0.f, 0.f};
}

// ---------------- mask scan: per (b,half) compaction tables
// pos[b*2048+s] = compacted slot within half (0xFFFF if masked out)
// idx[(b*2+half)*1024+j] = original global k for compacted j
// cnt[b*2+half] = number of unmasked keys in half
__global__ void mask_scan_kernel(const int* __restrict__ mask,
                                 unsigned short* __restrict__ pos,
                                 unsigned short* __restrict__ idx,
                                 int* __restrict__ cnt) {
  const int b = blockIdx.x >> 1, half = blockIdx.x & 1;
  __shared__ int sums[256];
  const int t = threadIdx.x;
  const int s0 = half * 1024 + t * 4;
  int m[4];
  int loc = 0;
#pragma unroll
  for (int i = 0; i < 4; i++) { m[i] = mask[b * 2048 + s0 + i]; loc += m[i]; }
  sums[t] = loc;
  __syncthreads();
  for (int off = 1; off < 256; off <<= 1) {
    int v = (t >= off) ? sums[t - off] : 0;
    __syncthreads();
    sums[t] += v;
    __syncthreads();
  }
  int excl = sums[t] - loc;
#pragma unroll
  for (int i = 0; i < 4; i++) {
    int sg = s0 + i;
    if (m[i]) {
      pos[b * 2048 + sg] = (unsigned short)excl;
      idx[(b * 2 + half) * 1024 + excl] = (unsigned short)sg;
      excl++;
    } else {
      pos[b * 2048 + sg] = 0xFFFFu;
    }
  }
  if (t == 255) cnt[b * 2 + half] = sums[255];
}

// ---------------- projection GEMM: epilogue writes fragment-major Q (uncompacted)
// and COMPACTED K / V^T via pos lookup. Masked rows dropped (K pad slots stale ->
// handled by select in consumers; V pad slots are pre-zeroed).
__global__ __launch_bounds__(256, 3) void gemm_proj_kernel(
    const unsigned short* __restrict__ A, const unsigned short* __restrict__ Bt,
    const unsigned short* __restrict__ pos,
    unsigned short* __restrict__ Qr, unsigned short* __restrict__ Qi,
    unsigned short* __restrict__ Kr, unsigned short* __restrict__ Ki,
    unsigned short* __restrict__ VT) {
  constexpr int K = 2048;
  __shared__ __attribute__((aligned(16))) unsigned short As[128][40];
  __shared__ __attribute__((aligned(16))) unsigned short Bs[128][40];
  const int tid = threadIdx.x;
  const int m0 = blockIdx.x * 128;
  const int n0 = blockIdx.y * 128;
  const int lane = tid & 63, wid = tid >> 6;
  const int l15 = lane & 15, quad = lane >> 4;
  const int wm = (wid & 1) * 64, wn = (wid >> 1) * 64;
  const int lrow = tid >> 1, lseg = (tid & 1) * 16;
  f32x4 acc[4][4] = {};
  const int4* ga = (const int4*)(A + (size_t)(m0 + lrow) * K + lseg);
  const int4* gb = (const int4*)(Bt + (size_t)(n0 + lrow) * K + lseg);
  for (int k0 = 0; k0 < K; k0 += 32) {
    int4 a0 = ga[0], a1 = ga[1];
    int4 b0 = gb[0], b1 = gb[1];
    __syncthreads();
    *(int4*)&As[lrow][lseg] = a0;  *(int4*)&As[lrow][lseg + 8] = a1;
    *(int4*)&Bs[lrow][lseg] = b0;  *(int4*)&Bs[lrow][lseg + 8] = b1;
    __syncthreads();
    short8x af[4], bfr[4];
#pragma unroll
    for (int i = 0; i < 4; i++) af[i]  = *(const short8x*)&As[wm + i * 16 + l15][quad * 8];
#pragma unroll
    for (int i = 0; i < 4; i++) bfr[i] = *(const short8x*)&Bs[wn + i * 16 + l15][quad * 8];
#pragma unroll
    for (int mi = 0; mi < 4; mi++)
#pragma unroll
      for (int ni = 0; ni < 4; ni++)
        acc[mi][ni] = mfma16(af[mi], bfr[ni], acc[mi][ni]);
    ga += 4; gb += 4;
  }
#pragma unroll
  for (int mi = 0; mi < 4; mi++) {
#pragma unroll
    for (int ni = 0; ni < 4; ni++) {
      int gn = n0 + wn + ni * 16 + l15;
      if (gn < 2048) {
        // Q: uncompacted
        int which = gn >> 10, j = gn & 1023, h = j >> 6, dk = j & 63;
        int ks = dk >> 5, q = (dk >> 3) & 3, e = dk & 7;
        unsigned short* dst = which ? Qi : Qr;
#pragma unroll
        for (int r = 0; r < 4; r++) {
          int gm = m0 + wm + mi * 16 + quad * 4 + r;
          int b = gm >> 11, s = gm & 2047;
          int bh = b * HH + h, rb = s >> 4, l = s & 15;
          dst[(size_t)(((bh * 128 + rb) * 2 + ks) * 512 + (q * 16 + l) * 8 + e)] = f2b(acc[mi][ni][r]);
        }
      } else if (gn < 4096) {
        // K: compacted per (b, half)
        int which = gn >> 10, j = gn & 1023, h = j >> 6, dk = j & 63;
        int ks = dk >> 5, q = (dk >> 3) & 3, e = dk & 7;
        unsigned short* dst = (which == 2) ? Kr : Ki;
#pragma unroll
        for (int r = 0; r < 4; r++) {
          int gm = m0 + wm + mi * 16 + quad * 4 + r;
          int b = gm >> 11, s = gm & 2047;
          unsigned short pp = pos[b * 2048 + s];
          if (pp != 0xFFFFu) {
            int hf = s >> 10;
            int bh = b * HH + h, rb = hf * 64 + (pp >> 4), l = pp & 15;
            dst[(size_t)(((bh * 128 + rb) * 2 + ks) * 512 + (q * 16 + l) * 8 + e)] = f2b(acc[mi][ni][r]);
          }
        }
      } else {
        // V^T: compacted per (b, half)
        int j = gn - 4096, h = j >> 6, dk = j & 63;
        int rbv = dk >> 4, lv = dk & 15;
#pragma unroll
        for (int r = 0; r < 4; r++) {
          int gm = m0 + wm + mi * 16 + quad * 4 + r;
          int b = gm >> 11, s = gm & 2047;
          unsigned short pp = pos[b * 2048 + s];
          if (pp != 0xFFFFu) {
            int hf = s >> 10;
            int bh = b * HH + h, kc = hf * 32 + (pp >> 5), qv = (pp >> 3) & 3, ev = pp & 7;
            VT[(size_t)(((bh * 4 + rbv) * 64 + kc) * 512 + (qv * 16 + lv) * 8 + ev)] = f2b(acc[mi][ni][r]);
          }
        }
      }
    }
  }
}

// ---------------- flash attention over COMPACTED keys, fixed-m, K-range split
// R10 XCD swizzle kept. kt-loop trip = ceil(cnt/64) (~8-9 vs 16). No mask loads:
// validity is j < cnt, applied as SELECT so stale K pad slots (possible NaN) are
// discarded, never multiplied.
__global__ __launch_bounds__(256, 6) void flash_kernel(
    const unsigned short* __restrict__ Qr, const unsigned short* __restrict__ Qi,
    const unsigned short* __restrict__ Kr, const unsigned short* __restrict__ Ki,
    const unsigned short* __restrict__ VT, const int* __restrict__ cnt,
    float* __restrict__ ctxP0, float* __restrict__ ctxP1,
    float* __restrict__ Lp0, float* __restrict__ Lp1) {
  __shared__ __attribute__((aligned(16))) unsigned short Ps[4][16][72];
  const int tid = threadIdx.x;
  const int lane = tid & 63, wid = tid >> 6;
  const int l15 = lane & 15, quad = lane >> 4;
  // XCD swizzle (bijective, 2048 % 8 == 0)
  int lin = blockIdx.x + 32 * (blockIdx.y + 16 * blockIdx.z);
  lin = ((lin & 7) << 8) | (lin >> 3);
  const int qt = (lin & 31) * 64;
  const int h = (lin >> 5) & 15;
  const int z = lin >> 9;
  const int b = z >> 1, half = z & 1;
  const int bh = b * HH + h;
  float* __restrict__ cp = half ? ctxP1 : ctxP0;
  float* __restrict__ lp = half ? Lp1 : Lp0;
  const int rb = (qt >> 4) + wid;
  const int qbase = (bh * 128 + rb) * 1024 + lane * 8;
  short8x fqr0 = *(const short8x*)(Qr + qbase);
  short8x fqr1 = *(const short8x*)(Qr + qbase + 512);
  short8x fqi0 = *(const short8x*)(Qi + qbase);
  short8x fqi1 = *(const short8x*)(Qi + qbase + 512);
  f32x4 ctxacc[4] = {};
  float lsum[4] = {0.f, 0.f, 0.f, 0.f};

  const int cntbh = cnt[b * 2 + half];
  const int kend = ((cntbh + 63) >> 6) << 6;
  const int kt0 = half * 1024;
  for (int ktl = 0; ktl < kend; ktl += 64) {
    const int kt = kt0 + ktl;
#pragma unroll
    for (int nb = 0; nb < 4; nb++) {
      const int j = ktl + nb * 16 + l15;           // compacted-local index
      const int koff = (bh * 128 + (kt >> 4) + nb) * 1024 + lane * 8;
      short8x bkr0 = *(const short8x*)(Kr + koff);
      short8x bkr1 = *(const short8x*)(Kr + koff + 512);
      short8x bki0 = *(const short8x*)(Ki + koff);
      short8x bki1 = *(const short8x*)(Ki + koff + 512);
      f32x4 sr = {0.f, 0.f, 0.f, 0.f};
      sr = mfma16(fqr0, bkr0, sr);  sr = mfma16(fqr1, bkr1, sr);
      sr = mfma16(fqi0, bki0, sr);  sr = mfma16(fqi1, bki1, sr);
      f32x4 sa = {0.f, 0.f, 0.f, 0.f};
      sa = mfma16(fqi0, bkr0, sa);  sa = mfma16(fqi1, bkr1, sa);
      f32x4 sb = {0.f, 0.f, 0.f, 0.f};
      sb = mfma16(fqr0, bki0, sb);  sb = mfma16(fqr1, bki1, sb);
#pragma unroll
      for (int r = 0; r < 4; r++) {
        float a = sr[r];
        float d = sa[r] - sb[r];
        float r2 = __builtin_fmaf(a, a, d * d);
        float inv = __builtin_amdgcn_rsqf(r2);
        float arg = inv * __builtin_fmaf(C1F, r2, C2F * a);
        float p = (j < cntbh) ? __builtin_amdgcn_exp2f(arg) : 0.0f;  // select, not mul
        lsum[r] += p;
        Ps[wid][quad * 4 + r][nb * 16 + l15] = f2b_fast(p);
      }
    }
    // PV (Ps per-wave; lgkmcnt wait suffices, no barrier). V pad rows pre-zeroed.
#pragma unroll
    for (int ks = 0; ks < 2; ks++)
#pragma unroll
      for (int db = 0; db < 4; db++) {
        int voff = ((bh * 4 + db) * 64 + (kt >> 5) + ks) * 512 + lane * 8;
        short8x bv = *(const short8x*)(VT + voff);
        short8x ap = *(const short8x*)&Ps[wid][l15][ks * 32 + quad * 8];
        ctxacc[db] = mfma16(ap, bv, ctxacc[db]);
      }
  }
  // reduce partial l over the 16 column-lanes
#pragma unroll
  for (int r = 0; r < 4; r++) {
#pragma unroll
    for (int off = 1; off < 16; off <<= 1) lsum[r] += __shfl_xor(lsum[r], off, 64);
  }
#pragma unroll
  for (int r = 0; r < 4; r++) {
    int s = qt + wid * 16 + quad * 4 + r;
#pragma unroll
    for (int db = 0; db < 4; db++)
      cp[((size_t)b * SS + s) * DD + h * DKK + db * 16 + l15] = ctxacc[db][r];
    if (l15 == 0) lp[(size_t)bh * SS + s] = lsum[r];
  }
}

// ---------------- combine: ctx_bf16 = (P0+P1) / (L0+L1)
__global__ __launch_bounds__(256) void combine_kernel(
    const float* __restrict__ ctxP0, const float* __restrict__ ctxP1,
    const float* __restrict__ Lp0, const float* __restrict__ Lp1,
    unsigned short* __restrict__ ctx) {
  int idx = blockIdx.x * 256 + threadIdx.x;   // 1048576 threads
  int g = idx * 4;
  int c = g & 1023, s = (g >> 10) & 2047, b = g >> 21;
  int h = c >> 6;
  size_t loff = (size_t)(b * HH + h) * SS + s;
  float linv = 1.0f / (Lp0[loff] + Lp1[loff]);
  float4 p0 = *(const float4*)(ctxP0 + g);
  float4 p1 = *(const float4*)(ctxP1 + g);
  ushort4 o;
  o.x = f2b((p0.x + p1.x) * linv);
  o.y = f2b((p0.y + p1.y) * linv);
  o.z = f2b((p0.z + p1.z) * linv);
  o.w = f2b((p0.w + p1.w) * linv);
  *(ushort4*)(ctx + g) = o;
}

// ---------------- output GEMM: out = ctx @ WoT^T + bias
__global__ __launch_bounds__(256, 2) void gemm_out_kernel(
    const unsigned short* __restrict__ A, const unsigned short* __restrict__ Bt,
    const float* __restrict__ bias, float* __restrict__ out) {
  constexpr int K = 1024;
  __shared__ __attribute__((aligned(16))) unsigned short As[128][40];
  __shared__ __attribute__((aligned(16))) unsigned short Bs[128][40];
  const int tid = threadIdx.x;
  const int m0 = blockIdx.x * 128;
  const int n0 = blockIdx.y * 128;
  const int lane = tid & 63, wid = tid >> 6;
  const int l15 = lane & 15, quad = lane >> 4;
  const int wm = (wid & 1) * 64, wn = (wid >> 1) * 64;
  const int lrow = tid >> 1, lseg = (tid & 1) * 16;
  f32x4 acc[4][4] = {};
  const int4* ga = (const int4*)(A + (size_t)(m0 + lrow) * K + lseg);
  const int4* gb = (const int4*)(Bt + (size_t)(n0 + lrow) * K + lseg);
  for (int k0 = 0; k0 < K; k0 += 32) {
    int4 a0 = ga[0], a1 = ga[1];
    int4 b0 = gb[0], b1 = gb[1];
    __syncthreads();
    *(int4*)&As[lrow][lseg] = a0;  *(int4*)&As[lrow][lseg + 8] = a1;
    *(int4*)&Bs[lrow][lseg] = b0;  *(int4*)&Bs[lrow][lseg + 8] = b1;
    __syncthreads();
    short8x af[4], bfr[4];
#pragma unroll
    for (int i = 0; i < 4; i++) af[i]  = *(const short8x*)&As[wm + i * 16 + l15][quad * 8];
#pragma unroll
    for (int i = 0; i < 4; i++) bfr[i] = *(const short8x*)&Bs[wn + i * 16 + l15][quad * 8];
#pragma unroll
    for (int mi = 0; mi < 4; mi++)
#pragma unroll
      for (int ni = 0; ni < 4; ni++)
        acc[mi][ni] = mfma16(af[mi], bfr[ni], acc[mi][ni]);
    ga += 4; gb += 4;
  }
#pragma unroll
  for (int mi = 0; mi < 4; mi++)
#pragma unroll
    for (int ni = 0; ni < 4; ni++) {
      int gn = n0 + wn + ni * 16 + l15;
      float bv = bias[gn];
#pragma unroll
      for (int r = 0; r < 4; r++) {
        int gm = m0 + wm + mi * 16 + quad * 4 + r;
        out[(size_t)gm * 1024 + gn] = acc[mi][ni][r] + bv;
      }
    }
}

// ---------------- probs_mean over COMPACTED keys; out2 pre-zeroed, valid columns
// scattered via idx. Grid kt-slots map onto the two halves' compacted tiles;
// surplus blocks exit immediately.
__global__ __launch_bounds__(256, 4) void probsmean_kernel(
    const unsigned short* __restrict__ Qr, const unsigned short* __restrict__ Qi,
    const unsigned short* __restrict__ Kr, const unsigned short* __restrict__ Ki,
    const int* __restrict__ cnt, const unsigned short* __restrict__ idxT,
    const float* __restrict__ Lp0, const float* __restrict__ Lp1,
    float* __restrict__ out2) {
  const int tid = threadIdx.x, lane = tid & 63, wid = tid >> 6;
  const int l15 = lane & 15, quad = lane >> 4;
  const int qt = blockIdx.x * 64;
  const int b = blockIdx.z;
  const int c0 = cnt[b * 2], c1 = cnt[b * 2 + 1];
  const int t0n = (c0 + 63) >> 6;
  const int t1n = (c1 + 63) >> 6;
  const int t = blockIdx.y;
  int half, jl0, cnth;
  if (t < t0n)            { half = 0; jl0 = t * 64;         cnth = c0; }
  else if (t < t0n + t1n) { half = 1; jl0 = (t - t0n) * 64; cnth = c1; }
  else return;  // out2 pre-zeroed
  const int qrow0 = qt + wid * 16;
  const int qrb = (qt >> 4) + wid;
  const int ktb = half * 64 + (jl0 >> 4);
  int korig[4]; bool vld[4];
#pragma unroll
  for (int nb = 0; nb < 4; nb++) {
    int j = jl0 + nb * 16 + l15;
    vld[nb] = j < cnth;
    korig[nb] = idxT[(b * 2 + half) * 1024 + j];
  }
  float psum[4][4] = {};  // [nb][r]
  for (int h = 0; h < HH; h++) {
    const int bh = b * HH + h;
    const int qoff = (bh * 128 + qrb) * 1024 + lane * 8;
    short8x fqr0 = *(const short8x*)(Qr + qoff);
    short8x fqr1 = *(const short8x*)(Qr + qoff + 512);
    short8x fqi0 = *(const short8x*)(Qi + qoff);
    short8x fqi1 = *(const short8x*)(Qi + qoff + 512);
    const float4 lv0 = *(const float4*)(Lp0 + (size_t)bh * SS + qrow0 + quad * 4);
    const float4 lv1 = *(const float4*)(Lp1 + (size_t)bh * SS + qrow0 + quad * 4);
    float li[4];
    li[0] = 1.0f / (lv0.x + lv1.x); li[1] = 1.0f / (lv0.y + lv1.y);
    li[2] = 1.0f / (lv0.z + lv1.z); li[3] = 1.0f / (lv0.w + lv1.w);
#pragma unroll
    for (int nb = 0; nb < 4; nb++) {
      const int koff = (bh * 128 + ktb + nb) * 1024 + lane * 8;
      short8x bkr0 = *(const short8x*)(Kr + koff);
      short8x bkr1 = *(const short8x*)(Kr + koff + 512);
      short8x bki0 = *(const short8x*)(Ki + koff);
      short8x bki1 = *(const short8x*)(Ki + koff + 512);
      f32x4 sr = {0.f, 0.f, 0.f, 0.f};
      sr = mfma16(fqr0, bkr0, sr);  sr = mfma16(fqr1, bkr1, sr);
      sr = mfma16(fqi0, bki0, sr);  sr = mfma16(fqi1, bki1, sr);
      f32x4 sa = {0.f, 0.f, 0.f, 0.f};  // Qi.Kr
      sa = mfma16(fqi0, bkr0, sa);  sa = mfma16(fqi1, bkr1, sa);
      f32x4 sb = {0.f, 0.f, 0.f, 0.f};  // Qr.Ki
      sb = mfma16(fqr0, bki0, sb);  sb = mfma16(fqr1, bki1, sb);
#pragma unroll
      for (int r = 0; r < 4; r++) {
        float a = sr[r];
        float d = sa[r] - sb[r];
        float r2 = __builtin_fmaf(a, a, d * d);
        float inv = __builtin_amdgcn_rsqf(r2);
        float arg = inv * __builtin_fmaf(C1F, r2, C2F * a);
        float p = vld[nb] ? __builtin_amdgcn_exp2f(arg) * li[r] : 0.0f;  // select
        psum[nb][r] += p;
      }
    }
  }
#pragma unroll
  for (int nb = 0; nb < 4; nb++)
#pragma unroll
    for (int r = 0; r < 4; r++) {
      if (vld[nb]) {
        int qrow = qrow0 + quad * 4 + r;
        out2[((size_t)b * SS + qrow) * SS + korig[nb]] = psum[nb][r] * 0.0625f;
      }
    }
}

extern "C" void kernel_launch(void* const* d_in, const int* in_sizes, int n_in,
                              void* d_out, int out_size, void* d_ws, size_t ws_size,
                              hipStream_t stream) {
  const float* z_real = (const float*)d_in[0];
  const float* z_imag = (const float*)d_in[1];
  const float* Wq_r = (const float*)d_in[2];
  const float* Wq_i = (const float*)d_in[3];
  const float* Wk_r = (const float*)d_in[4];
  const float* Wk_i = (const float*)d_in[5];
  const float* Wv   = (const float*)d_in[6];
  const float* Wo_w = (const float*)d_in[7];
  const float* Wo_b = (const float*)d_in[8];
  const int*   mask = (const int*)d_in[9];
  char* ws = (char*)d_ws;

  // ws layout (bytes). ctxP0/ctxP1 ALIAS WcatT/Xcat: dead after gemm_proj (stream-serial).
  constexpr size_t QKV_BYTES = 8388608;  // B*H*S*DK*2
  unsigned short* Qr   = (unsigned short*)(ws + 0);
  unsigned short* Qi   = (unsigned short*)(ws + QKV_BYTES);
  unsigned short* Kr   = (unsigned short*)(ws + 2 * QKV_BYTES);
  unsigned short* Ki   = (unsigned short*)(ws + 3 * QKV_BYTES);
  unsigned short* VT   = (unsigned short*)(ws + 4 * QKV_BYTES);
  unsigned short* ctx  = (unsigned short*)(ws + 5 * QKV_BYTES);              // 8 MB bf16
  unsigned short* WcatT= (unsigned short*)(ws + 50331648);                   // 20 MB
  unsigned short* WoT  = (unsigned short*)(ws + 71303168);                   // 2 MB
  unsigned short* Xcat = (unsigned short*)(ws + 73400320);                   // 16 MB
  float* ctxP0 = (float*)(ws + 50331648);                                    // aliases WcatT (16 MB)
  float* ctxP1 = (float*)(ws + 73400320);                                    // aliases Xcat (16 MB)
  float* Lp0   = (float*)(ws + 90177536);                                    // 256 KB
  float* Lp1   = (float*)(ws + 90439680);                                    // 256 KB

  float* out  = (float*)d_out;
  float* out2 = out + (size_t)BB * SS * DD;

  // Compaction tables live in d_out scratch (`out` region): dead until gemm_out,
  // which runs last. probsmean (reads idx) ordered before combine/gemm_out.
  unsigned short* posT = (unsigned short*)out;       // [2][2048] = 8 KB
  unsigned short* idxT = posT + 4096;                // [2][2][1024] = 8 KB
  int* cntT = (int*)(idxT + 4096);                   // [2][2]

  pack_w_kernel<<<dim3(45056), dim3(256), 0, stream>>>(Wq_r, Wq_i, Wk_r, Wk_i, Wv, Wo_w, WcatT, WoT);
  pack_x_kernel<<<dim3(32768), dim3(256), 0, stream>>>(z_real, z_imag, Xcat);
  zero_kernel<<<dim3(2048), dim3(256), 0, stream>>>((float4*)VT);            // 8 MB: V pad rows = 0
  zero_kernel<<<dim3(8192), dim3(256), 0, stream>>>((float4*)out2);          // 32 MB: masked cols = 0
  mask_scan_kernel<<<dim3(4), dim3(256), 0, stream>>>(mask, posT, idxT, cntT);
  gemm_proj_kernel<<<dim3(32, 40), dim3(256), 0, stream>>>(Xcat, WcatT, posT, Qr, Qi, Kr, Ki, VT);
  flash_kernel<<<dim3(32, 16, 4), dim3(256), 0, stream>>>(Qr, Qi, Kr, Ki, VT, cntT, ctxP0, ctxP1, Lp0, Lp1);
  probsmean_kernel<<<dim3(32, 32, 2), dim3(256), 0, stream>>>(Qr, Qi, Kr, Ki, cntT, idxT, Lp0, Lp1, out2);
  combine_kernel<<<dim3(4096), dim3(256), 0, stream>>>(ctxP0, ctxP1, Lp0, Lp1, ctx);
  gemm_out_kernel<<<dim3(32, 8), dim3(256), 0, stream>>>(ctx, WoT, Wo_b, out);
}

// Round 6
// 474.795 us; speedup vs baseline: 1.5398x; 1.0370x over previous
//
#include <hip/hip_runtime.h>
#include <cstdint>
#include <cstddef>

#define BB 2
#define SS 2048
#define DD 1024
#define HH 16
#define DKK 64

typedef __attribute__((ext_vector_type(8))) short short8x;
typedef __attribute__((ext_vector_type(4))) float f32x4;

__device__ __forceinline__ unsigned short f2b(float f) {
  union { float f; unsigned u; } v; v.f = f;
  unsigned r = (v.u + 0x7fffu + ((v.u >> 16) & 1u)) >> 16;  // RNE
  return (unsigned short)r;
}

// hot-path bf16: round-half-up, 2 VALU (vs ~5 for RNE). Used only for Ps probabilities.
__device__ __forceinline__ unsigned short f2b_fast(float f) {
  union { float f; unsigned u; } v; v.f = f;
  return (unsigned short)((v.u + 0x8000u) >> 16);
}

__device__ __forceinline__ f32x4 mfma16(short8x a, short8x b, f32x4 c) {
  return __builtin_amdgcn_mfma_f32_16x16x32_bf16(a, b, c, 0, 0, 0);
}

// async global->LDS, 16B per lane. LDS dest = wave-uniform base + lane*16.
__device__ __forceinline__ void gload16(const unsigned short* g, unsigned short* l) {
  __builtin_amdgcn_global_load_lds(
      (__attribute__((address_space(1))) unsigned int*)g,
      (__attribute__((address_space(3))) unsigned int*)l,
      16, 0, 0);
}

// Fragment-major Q/K layout (R5): frag (bh,rb,ks) at ((bh*128+rb)*2+ks)*512 + lane*8.
// V^T frag (bh,rbv,kc) at ((bh*4+rbv)*64+kc)*512 + lane*8.
// R6: fixed m=0. R7: K-split across 2 blocks + combine. R8: raw-HW transcendentals.
// R9 FAILED: launch_bounds(256,8) flash spill. R10: XCD swizzle kept on flash only.
// R11: gemm_proj (256,3). R12: K-compaction (mask Bernoulli(0.5) -> masked columns
// are exact zeros; compact K/V per (b,half), flash/probsmean loop over cnt only).
// R13 (this round): gemm_proj/gemm_out staging via __builtin_amdgcn_global_load_lds
// width-16 (m151: reg-staging 646 TF vs gload_lds 874 TF at this exact 128^2
// 2-barrier structure; our gemm_proj measured ~590 TF = the reg-staging regime).
// Requires LINEAR LDS [128][32] (no pad): wave w lane l writes row w*16+l/4,
// colseg (l&3)*8 = row-major linear, matching fragment ds_reads.
#define C1F 0.0225421076f  // (1/64)*log2e
#define C2F 0.0541010849f  // (0.3/8)*log2e

// ---------------- pack weights
__global__ void pack_w_kernel(const float* __restrict__ Wq_r, const float* __restrict__ Wq_i,
                              const float* __restrict__ Wk_r, const float* __restrict__ Wk_i,
                              const float* __restrict__ Wv, const float* __restrict__ Wo,
                              unsigned short* __restrict__ WcatT, unsigned short* __restrict__ WoT) {
  int gid = blockIdx.x * 256 + threadIdx.x;
  if (gid < 5120 * 2048) {
    int k = gid & 2047;
    int n = gid >> 11;
    int q = n >> 10, j = n & 1023;
    float v;
    if (k < 1024) {
      const float* src = (q == 0) ? Wq_r : (q == 1) ? Wq_i : (q == 2) ? Wk_r : (q == 3) ? Wk_i : Wv;
      v = src[k * 1024 + j];
    } else {
      int k2 = k - 1024;
      if (q == 0)      v = -Wq_i[k2 * 1024 + j];
      else if (q == 1) v =  Wq_r[k2 * 1024 + j];
      else if (q == 2) v = -Wk_i[k2 * 1024 + j];
      else if (q == 3) v =  Wk_r[k2 * 1024 + j];
      else             v = 0.0f;
    }
    WcatT[gid] = f2b(v);
  } else {
    int g2 = gid - 5120 * 2048;            // n*1024 + k
    int k = g2 & 1023, n = g2 >> 10;
    WoT[g2] = f2b(Wo[k * 1024 + n]);
  }
}

// ---------------- pack X: Xcat[4096][2048] = [z_real | z_imag] (bf16)
__global__ void pack_x_kernel(const float* __restrict__ zr, const float* __restrict__ zi,
                              unsigned short* __restrict__ X) {
  int gid = blockIdx.x * 256 + threadIdx.x;  // 4096*2048
  int k = gid & 2047, m = gid >> 11;
  float v = (k < 1024) ? zr[m * 1024 + k] : zi[m * 1024 + (k - 1024)];
  X[gid] = f2b(v);
}

// ---------------- generic zero (float4 granularity)
__global__ void zero_kernel(float4* __restrict__ p) {
  p[(size_t)blockIdx.x * 256 + threadIdx.x] = float4{0.f, 0.f, 0.f, 0.f};
}

// ---------------- mask scan: per (b,half) compaction tables
__global__ void mask_scan_kernel(const int* __restrict__ mask,
                                 unsigned short* __restrict__ pos,
                                 unsigned short* __restrict__ idx,
                                 int* __restrict__ cnt) {
  const int b = blockIdx.x >> 1, half = blockIdx.x & 1;
  __shared__ int sums[256];
  const int t = threadIdx.x;
  const int s0 = half * 1024 + t * 4;
  int m[4];
  int loc = 0;
#pragma unroll
  for (int i = 0; i < 4; i++) { m[i] = mask[b * 2048 + s0 + i]; loc += m[i]; }
  sums[t] = loc;
  __syncthreads();
  for (int off = 1; off < 256; off <<= 1) {
    int v = (t >= off) ? sums[t - off] : 0;
    __syncthreads();
    sums[t] += v;
    __syncthreads();
  }
  int excl = sums[t] - loc;
#pragma unroll
  for (int i = 0; i < 4; i++) {
    int sg = s0 + i;
    if (m[i]) {
      pos[b * 2048 + sg] = (unsigned short)excl;
      idx[(b * 2 + half) * 1024 + excl] = (unsigned short)sg;
      excl++;
    } else {
      pos[b * 2048 + sg] = 0xFFFFu;
    }
  }
  if (t == 255) cnt[b * 2 + half] = sums[255];
}

// ---------------- projection GEMM: gload_lds staging (R13); epilogue writes
// fragment-major Q (uncompacted) and COMPACTED K / V^T via pos lookup.
__global__ __launch_bounds__(256, 3) void gemm_proj_kernel(
    const unsigned short* __restrict__ A, const unsigned short* __restrict__ Bt,
    const unsigned short* __restrict__ pos,
    unsigned short* __restrict__ Qr, unsigned short* __restrict__ Qi,
    unsigned short* __restrict__ Kr, unsigned short* __restrict__ Ki,
    unsigned short* __restrict__ VT) {
  constexpr int K = 2048;
  __shared__ __attribute__((aligned(16))) unsigned short As[128][32];
  __shared__ __attribute__((aligned(16))) unsigned short Bs[128][32];
  const int tid = threadIdx.x;
  const int m0 = blockIdx.x * 128;
  const int n0 = blockIdx.y * 128;
  const int lane = tid & 63, wid = tid >> 6;
  const int l15 = lane & 15, quad = lane >> 4;
  const int wm = (wid & 1) * 64, wn = (wid >> 1) * 64;
  const int r4 = lane >> 2, c8 = (lane & 3) * 8;
  f32x4 acc[4][4] = {};
  const unsigned short* pa0 = A + (size_t)(m0 + wid * 16 + r4) * K + c8;
  const unsigned short* pa1 = pa0 + (size_t)64 * K;
  const unsigned short* pb0 = Bt + (size_t)(n0 + wid * 16 + r4) * K + c8;
  const unsigned short* pb1 = pb0 + (size_t)64 * K;
  unsigned short* la0 = &As[wid * 16][0];
  unsigned short* la1 = &As[64 + wid * 16][0];
  unsigned short* lb0 = &Bs[wid * 16][0];
  unsigned short* lb1 = &Bs[64 + wid * 16][0];
  for (int k0 = 0; k0 < K; k0 += 32) {
    __syncthreads();
    gload16(pa0, la0);  gload16(pa1, la1);
    gload16(pb0, lb0);  gload16(pb1, lb1);
    pa0 += 32; pa1 += 32; pb0 += 32; pb1 += 32;
    __syncthreads();
    short8x af[4], bfr[4];
#pragma unroll
    for (int i = 0; i < 4; i++) af[i]  = *(const short8x*)&As[wm + i * 16 + l15][quad * 8];
#pragma unroll
    for (int i = 0; i < 4; i++) bfr[i] = *(const short8x*)&Bs[wn + i * 16 + l15][quad * 8];
#pragma unroll
    for (int mi = 0; mi < 4; mi++)
#pragma unroll
      for (int ni = 0; ni < 4; ni++)
        acc[mi][ni] = mfma16(af[mi], bfr[ni], acc[mi][ni]);
  }
#pragma unroll
  for (int mi = 0; mi < 4; mi++) {
#pragma unroll
    for (int ni = 0; ni < 4; ni++) {
      int gn = n0 + wn + ni * 16 + l15;
      if (gn < 2048) {
        // Q: uncompacted
        int which = gn >> 10, j = gn & 1023, h = j >> 6, dk = j & 63;
        int ks = dk >> 5, q = (dk >> 3) & 3, e = dk & 7;
        unsigned short* dst = which ? Qi : Qr;
#pragma unroll
        for (int r = 0; r < 4; r++) {
          int gm = m0 + wm + mi * 16 + quad * 4 + r;
          int b = gm >> 11, s = gm & 2047;
          int bh = b * HH + h, rb = s >> 4, l = s & 15;
          dst[(size_t)(((bh * 128 + rb) * 2 + ks) * 512 + (q * 16 + l) * 8 + e)] = f2b(acc[mi][ni][r]);
        }
      } else if (gn < 4096) {
        // K: compacted per (b, half)
        int which = gn >> 10, j = gn & 1023, h = j >> 6, dk = j & 63;
        int ks = dk >> 5, q = (dk >> 3) & 3, e = dk & 7;
        unsigned short* dst = (which == 2) ? Kr : Ki;
#pragma unroll
        for (int r = 0; r < 4; r++) {
          int gm = m0 + wm + mi * 16 + quad * 4 + r;
          int b = gm >> 11, s = gm & 2047;
          unsigned short pp = pos[b * 2048 + s];
          if (pp != 0xFFFFu) {
            int hf = s >> 10;
            int bh = b * HH + h, rb = hf * 64 + (pp >> 4), l = pp & 15;
            dst[(size_t)(((bh * 128 + rb) * 2 + ks) * 512 + (q * 16 + l) * 8 + e)] = f2b(acc[mi][ni][r]);
          }
        }
      } else {
        // V^T: compacted per (b, half)
        int j = gn - 4096, h = j >> 6, dk = j & 63;
        int rbv = dk >> 4, lv = dk & 15;
#pragma unroll
        for (int r = 0; r < 4; r++) {
          int gm = m0 + wm + mi * 16 + quad * 4 + r;
          int b = gm >> 11, s = gm & 2047;
          unsigned short pp = pos[b * 2048 + s];
          if (pp != 0xFFFFu) {
            int hf = s >> 10;
            int bh = b * HH + h, kc = hf * 32 + (pp >> 5), qv = (pp >> 3) & 3, ev = pp & 7;
            VT[(size_t)(((bh * 4 + rbv) * 64 + kc) * 512 + (qv * 16 + lv) * 8 + ev)] = f2b(acc[mi][ni][r]);
          }
        }
      }
    }
  }
}

// ---------------- flash attention over COMPACTED keys, fixed-m, K-range split
__global__ __launch_bounds__(256, 6) void flash_kernel(
    const unsigned short* __restrict__ Qr, const unsigned short* __restrict__ Qi,
    const unsigned short* __restrict__ Kr, const unsigned short* __restrict__ Ki,
    const unsigned short* __restrict__ VT, const int* __restrict__ cnt,
    float* __restrict__ ctxP0, float* __restrict__ ctxP1,
    float* __restrict__ Lp0, float* __restrict__ Lp1) {
  __shared__ __attribute__((aligned(16))) unsigned short Ps[4][16][72];
  const int tid = threadIdx.x;
  const int lane = tid & 63, wid = tid >> 6;
  const int l15 = lane & 15, quad = lane >> 4;
  // XCD swizzle (bijective, 2048 % 8 == 0)
  int lin = blockIdx.x + 32 * (blockIdx.y + 16 * blockIdx.z);
  lin = ((lin & 7) << 8) | (lin >> 3);
  const int qt = (lin & 31) * 64;
  const int h = (lin >> 5) & 15;
  const int z = lin >> 9;
  const int b = z >> 1, half = z & 1;
  const int bh = b * HH + h;
  float* __restrict__ cp = half ? ctxP1 : ctxP0;
  float* __restrict__ lp = half ? Lp1 : Lp0;
  const int rb = (qt >> 4) + wid;
  const int qbase = (bh * 128 + rb) * 1024 + lane * 8;
  short8x fqr0 = *(const short8x*)(Qr + qbase);
  short8x fqr1 = *(const short8x*)(Qr + qbase + 512);
  short8x fqi0 = *(const short8x*)(Qi + qbase);
  short8x fqi1 = *(const short8x*)(Qi + qbase + 512);
  f32x4 ctxacc[4] = {};
  float lsum[4] = {0.f, 0.f, 0.f, 0.f};

  const int cntbh = cnt[b * 2 + half];
  const int kend = ((cntbh + 63) >> 6) << 6;
  const int kt0 = half * 1024;
  for (int ktl = 0; ktl < kend; ktl += 64) {
    const int kt = kt0 + ktl;
#pragma unroll
    for (int nb = 0; nb < 4; nb++) {
      const int j = ktl + nb * 16 + l15;           // compacted-local index
      const int koff = (bh * 128 + (kt >> 4) + nb) * 1024 + lane * 8;
      short8x bkr0 = *(const short8x*)(Kr + koff);
      short8x bkr1 = *(const short8x*)(Kr + koff + 512);
      short8x bki0 = *(const short8x*)(Ki + koff);
      short8x bki1 = *(const short8x*)(Ki + koff + 512);
      f32x4 sr = {0.f, 0.f, 0.f, 0.f};
      sr = mfma16(fqr0, bkr0, sr);  sr = mfma16(fqr1, bkr1, sr);
      sr = mfma16(fqi0, bki0, sr);  sr = mfma16(fqi1, bki1, sr);
      f32x4 sa = {0.f, 0.f, 0.f, 0.f};
      sa = mfma16(fqi0, bkr0, sa);  sa = mfma16(fqi1, bkr1, sa);
      f32x4 sb = {0.f, 0.f, 0.f, 0.f};
      sb = mfma16(fqr0, bki0, sb);  sb = mfma16(fqr1, bki1, sb);
#pragma unroll
      for (int r = 0; r < 4; r++) {
        float a = sr[r];
        float d = sa[r] - sb[r];
        float r2 = __builtin_fmaf(a, a, d * d);
        float inv = __builtin_amdgcn_rsqf(r2);
        float arg = inv * __builtin_fmaf(C1F, r2, C2F * a);
        float p = (j < cntbh) ? __builtin_amdgcn_exp2f(arg) : 0.0f;  // select, not mul
        lsum[r] += p;
        Ps[wid][quad * 4 + r][nb * 16 + l15] = f2b_fast(p);
      }
    }
    // PV (Ps per-wave; lgkmcnt wait suffices, no barrier). V pad rows pre-zeroed.
#pragma unroll
    for (int ks = 0; ks < 2; ks++)
#pragma unroll
      for (int db = 0; db < 4; db++) {
        int voff = ((bh * 4 + db) * 64 + (kt >> 5) + ks) * 512 + lane * 8;
        short8x bv = *(const short8x*)(VT + voff);
        short8x ap = *(const short8x*)&Ps[wid][l15][ks * 32 + quad * 8];
        ctxacc[db] = mfma16(ap, bv, ctxacc[db]);
      }
  }
  // reduce partial l over the 16 column-lanes
#pragma unroll
  for (int r = 0; r < 4; r++) {
#pragma unroll
    for (int off = 1; off < 16; off <<= 1) lsum[r] += __shfl_xor(lsum[r], off, 64);
  }
#pragma unroll
  for (int r = 0; r < 4; r++) {
    int s = qt + wid * 16 + quad * 4 + r;
#pragma unroll
    for (int db = 0; db < 4; db++)
      cp[((size_t)b * SS + s) * DD + h * DKK + db * 16 + l15] = ctxacc[db][r];
    if (l15 == 0) lp[(size_t)bh * SS + s] = lsum[r];
  }
}

// ---------------- combine: ctx_bf16 = (P0+P1) / (L0+L1)
__global__ __launch_bounds__(256) void combine_kernel(
    const float* __restrict__ ctxP0, const float* __restrict__ ctxP1,
    const float* __restrict__ Lp0, const float* __restrict__ Lp1,
    unsigned short* __restrict__ ctx) {
  int idx = blockIdx.x * 256 + threadIdx.x;   // 1048576 threads
  int g = idx * 4;
  int c = g & 1023, s = (g >> 10) & 2047, b = g >> 21;
  int h = c >> 6;
  size_t loff = (size_t)(b * HH + h) * SS + s;
  float linv = 1.0f / (Lp0[loff] + Lp1[loff]);
  float4 p0 = *(const float4*)(ctxP0 + g);
  float4 p1 = *(const float4*)(ctxP1 + g);
  ushort4 o;
  o.x = f2b((p0.x + p1.x) * linv);
  o.y = f2b((p0.y + p1.y) * linv);
  o.z = f2b((p0.z + p1.z) * linv);
  o.w = f2b((p0.w + p1.w) * linv);
  *(ushort4*)(ctx + g) = o;
}

// ---------------- output GEMM: out = ctx @ WoT^T + bias (R13: gload_lds staging)
__global__ __launch_bounds__(256, 2) void gemm_out_kernel(
    const unsigned short* __restrict__ A, const unsigned short* __restrict__ Bt,
    const float* __restrict__ bias, float* __restrict__ out) {
  constexpr int K = 1024;
  __shared__ __attribute__((aligned(16))) unsigned short As[128][32];
  __shared__ __attribute__((aligned(16))) unsigned short Bs[128][32];
  const int tid = threadIdx.x;
  const int m0 = blockIdx.x * 128;
  const int n0 = blockIdx.y * 128;
  const int lane = tid & 63, wid = tid >> 6;
  const int l15 = lane & 15, quad = lane >> 4;
  const int wm = (wid & 1) * 64, wn = (wid >> 1) * 64;
  const int r4 = lane >> 2, c8 = (lane & 3) * 8;
  f32x4 acc[4][4] = {};
  const unsigned short* pa0 = A + (size_t)(m0 + wid * 16 + r4) * K + c8;
  const unsigned short* pa1 = pa0 + (size_t)64 * K;
  const unsigned short* pb0 = Bt + (size_t)(n0 + wid * 16 + r4) * K + c8;
  const unsigned short* pb1 = pb0 + (size_t)64 * K;
  unsigned short* la0 = &As[wid * 16][0];
  unsigned short* la1 = &As[64 + wid * 16][0];
  unsigned short* lb0 = &Bs[wid * 16][0];
  unsigned short* lb1 = &Bs[64 + wid * 16][0];
  for (int k0 = 0; k0 < K; k0 += 32) {
    __syncthreads();
    gload16(pa0, la0);  gload16(pa1, la1);
    gload16(pb0, lb0);  gload16(pb1, lb1);
    pa0 += 32; pa1 += 32; pb0 += 32; pb1 += 32;
    __syncthreads();
    short8x af[4], bfr[4];
#pragma unroll
    for (int i = 0; i < 4; i++) af[i]  = *(const short8x*)&As[wm + i * 16 + l15][quad * 8];
#pragma unroll
    for (int i = 0; i < 4; i++) bfr[i] = *(const short8x*)&Bs[wn + i * 16 + l15][quad * 8];
#pragma unroll
    for (int mi = 0; mi < 4; mi++)
#pragma unroll
      for (int ni = 0; ni < 4; ni++)
        acc[mi][ni] = mfma16(af[mi], bfr[ni], acc[mi][ni]);
  }
#pragma unroll
  for (int mi = 0; mi < 4; mi++)
#pragma unroll
    for (int ni = 0; ni < 4; ni++) {
      int gn = n0 + wn + ni * 16 + l15;
      float bv = bias[gn];
#pragma unroll
      for (int r = 0; r < 4; r++) {
        int gm = m0 + wm + mi * 16 + quad * 4 + r;
        out[(size_t)gm * 1024 + gn] = acc[mi][ni][r] + bv;
      }
    }
}

// ---------------- probs_mean over COMPACTED keys; out2 pre-zeroed, valid columns
// scattered via idx.
__global__ __launch_bounds__(256, 4) void probsmean_kernel(
    const unsigned short* __restrict__ Qr, const unsigned short* __restrict__ Qi,
    const unsigned short* __restrict__ Kr, const unsigned short* __restrict__ Ki,
    const int* __restrict__ cnt, const unsigned short* __restrict__ idxT,
    const float* __restrict__ Lp0, const float* __restrict__ Lp1,
    float* __restrict__ out2) {
  const int tid = threadIdx.x, lane = tid & 63, wid = tid >> 6;
  const int l15 = lane & 15, quad = lane >> 4;
  const int qt = blockIdx.x * 64;
  const int b = blockIdx.z;
  const int c0 = cnt[b * 2], c1 = cnt[b * 2 + 1];
  const int t0n = (c0 + 63) >> 6;
  const int t1n = (c1 + 63) >> 6;
  const int t = blockIdx.y;
  int half, jl0, cnth;
  if (t < t0n)            { half = 0; jl0 = t * 64;         cnth = c0; }
  else if (t < t0n + t1n) { half = 1; jl0 = (t - t0n) * 64; cnth = c1; }
  else return;  // out2 pre-zeroed
  const int qrow0 = qt + wid * 16;
  const int qrb = (qt >> 4) + wid;
  const int ktb = half * 64 + (jl0 >> 4);
  int korig[4]; bool vld[4];
#pragma unroll
  for (int nb = 0; nb < 4; nb++) {
    int j = jl0 + nb * 16 + l15;
    vld[nb] = j < cnth;
    korig[nb] = idxT[(b * 2 + half) * 1024 + j];
  }
  float psum[4][4] = {};  // [nb][r]
  for (int h = 0; h < HH; h++) {
    const int bh = b * HH + h;
    const int qoff = (bh * 128 + qrb) * 1024 + lane * 8;
    short8x fqr0 = *(const short8x*)(Qr + qoff);
    short8x fqr1 = *(const short8x*)(Qr + qoff + 512);
    short8x fqi0 = *(const short8x*)(Qi + qoff);
    short8x fqi1 = *(const short8x*)(Qi + qoff + 512);
    const float4 lv0 = *(const float4*)(Lp0 + (size_t)bh * SS + qrow0 + quad * 4);
    const float4 lv1 = *(const float4*)(Lp1 + (size_t)bh * SS + qrow0 + quad * 4);
    float li[4];
    li[0] = 1.0f / (lv0.x + lv1.x); li[1] = 1.0f / (lv0.y + lv1.y);
    li[2] = 1.0f / (lv0.z + lv1.z); li[3] = 1.0f / (lv0.w + lv1.w);
#pragma unroll
    for (int nb = 0; nb < 4; nb++) {
      const int koff = (bh * 128 + ktb + nb) * 1024 + lane * 8;
      short8x bkr0 = *(const short8x*)(Kr + koff);
      short8x bkr1 = *(const short8x*)(Kr + koff + 512);
      short8x bki0 = *(const short8x*)(Ki + koff);
      short8x bki1 = *(const short8x*)(Ki + koff + 512);
      f32x4 sr = {0.f, 0.f, 0.f, 0.f};
      sr = mfma16(fqr0, bkr0, sr);  sr = mfma16(fqr1, bkr1, sr);
      sr = mfma16(fqi0, bki0, sr);  sr = mfma16(fqi1, bki1, sr);
      f32x4 sa = {0.f, 0.f, 0.f, 0.f};  // Qi.Kr
      sa = mfma16(fqi0, bkr0, sa);  sa = mfma16(fqi1, bkr1, sa);
      f32x4 sb = {0.f, 0.f, 0.f, 0.f};  // Qr.Ki
      sb = mfma16(fqr0, bki0, sb);  sb = mfma16(fqr1, bki1, sb);
#pragma unroll
      for (int r = 0; r < 4; r++) {
        float a = sr[r];
        float d = sa[r] - sb[r];
        float r2 = __builtin_fmaf(a, a, d * d);
        float inv = __builtin_amdgcn_rsqf(r2);
        float arg = inv * __builtin_fmaf(C1F, r2, C2F * a);
        float p = vld[nb] ? __builtin_amdgcn_exp2f(arg) * li[r] : 0.0f;  // select
        psum[nb][r] += p;
      }
    }
  }
#pragma unroll
  for (int nb = 0; nb < 4; nb++)
#pragma unroll
    for (int r = 0; r < 4; r++) {
      if (vld[nb]) {
        int qrow = qrow0 + quad * 4 + r;
        out2[((size_t)b * SS + qrow) * SS + korig[nb]] = psum[nb][r] * 0.0625f;
      }
    }
}

extern "C" void kernel_launch(void* const* d_in, const int* in_sizes, int n_in,
                              void* d_out, int out_size, void* d_ws, size_t ws_size,
                              hipStream_t stream) {
  const float* z_real = (const float*)d_in[0];
  const float* z_imag = (const float*)d_in[1];
  const float* Wq_r = (const float*)d_in[2];
  const float* Wq_i = (const float*)d_in[3];
  const float* Wk_r = (const float*)d_in[4];
  const float* Wk_i = (const float*)d_in[5];
  const float* Wv   = (const float*)d_in[6];
  const float* Wo_w = (const float*)d_in[7];
  const float* Wo_b = (const float*)d_in[8];
  const int*   mask = (const int*)d_in[9];
  char* ws = (char*)d_ws;

  // ws layout (bytes). ctxP0/ctxP1 ALIAS WcatT/Xcat: dead after gemm_proj (stream-serial).
  constexpr size_t QKV_BYTES = 8388608;  // B*H*S*DK*2
  unsigned short* Qr   = (unsigned short*)(ws + 0);
  unsigned short* Qi   = (unsigned short*)(ws + QKV_BYTES);
  unsigned short* Kr   = (unsigned short*)(ws + 2 * QKV_BYTES);
  unsigned short* Ki   = (unsigned short*)(ws + 3 * QKV_BYTES);
  unsigned short* VT   = (unsigned short*)(ws + 4 * QKV_BYTES);
  unsigned short* ctx  = (unsigned short*)(ws + 5 * QKV_BYTES);              // 8 MB bf16
  unsigned short* WcatT= (unsigned short*)(ws + 50331648);                   // 20 MB
  unsigned short* WoT  = (unsigned short*)(ws + 71303168);                   // 2 MB
  unsigned short* Xcat = (unsigned short*)(ws + 73400320);                   // 16 MB
  float* ctxP0 = (float*)(ws + 50331648);                                    // aliases WcatT (16 MB)
  float* ctxP1 = (float*)(ws + 73400320);                                    // aliases Xcat (16 MB)
  float* Lp0   = (float*)(ws + 90177536);                                    // 256 KB
  float* Lp1   = (float*)(ws + 90439680);                                    // 256 KB

  float* out  = (float*)d_out;
  float* out2 = out + (size_t)BB * SS * DD;

  // Compaction tables live in d_out scratch (`out` region): dead until gemm_out,
  // which runs last. probsmean (reads idx) ordered before combine/gemm_out.
  unsigned short* posT = (unsigned short*)out;       // [2][2048] = 8 KB
  unsigned short* idxT = posT + 4096;                // [2][2][1024] = 8 KB
  int* cntT = (int*)(idxT + 4096);                   // [2][2]

  pack_w_kernel<<<dim3(45056), dim3(256), 0, stream>>>(Wq_r, Wq_i, Wk_r, Wk_i, Wv, Wo_w, WcatT, WoT);
  pack_x_kernel<<<dim3(32768), dim3(256), 0, stream>>>(z_real, z_imag, Xcat);
  zero_kernel<<<dim3(2048), dim3(256), 0, stream>>>((float4*)VT);            // 8 MB: V pad rows = 0
  zero_kernel<<<dim3(8192), dim3(256), 0, stream>>>((float4*)out2);          // 32 MB: masked cols = 0
  mask_scan_kernel<<<dim3(4), dim3(256), 0, stream>>>(mask, posT, idxT, cntT);
  gemm_proj_kernel<<<dim3(32, 40), dim3(256), 0, stream>>>(Xcat, WcatT, posT, Qr, Qi, Kr, Ki, VT);
  flash_kernel<<<dim3(32, 16, 4), dim3(256), 0, stream>>>(Qr, Qi, Kr, Ki, VT, cntT, ctxP0, ctxP1, Lp0, Lp1);
  probsmean_kernel<<<dim3(32, 32, 2), dim3(256), 0, stream>>>(Qr, Qi, Kr, Ki, cntT, idxT, Lp0, Lp1, out2);
  combine_kernel<<<dim3(4096), dim3(256), 0, stream>>>(ctxP0, ctxP1, Lp0, Lp1, ctx);
  gemm_out_kernel<<<dim3(32, 8), dim3(256), 0, stream>>>(ctx, WoT, Wo_b, out);
}

// Round 7
// 455.975 us; speedup vs baseline: 1.6034x; 1.0413x over previous
//
#include <hip/hip_runtime.h>
#include <cstdint>
#include <cstddef>

#define BB 2
#define SS 2048
#define DD 1024
#define HH 16
#define DKK 64

typedef __attribute__((ext_vector_type(8))) short short8x;
typedef __attribute__((ext_vector_type(4))) float f32x4;

__device__ __forceinline__ unsigned short f2b(float f) {
  union { float f; unsigned u; } v; v.f = f;
  unsigned r = (v.u + 0x7fffu + ((v.u >> 16) & 1u)) >> 16;  // RNE
  return (unsigned short)r;
}

// hot-path bf16: round-half-up, 2 VALU (vs ~5 for RNE). Used only for Ps probabilities.
__device__ __forceinline__ unsigned short f2b_fast(float f) {
  union { float f; unsigned u; } v; v.f = f;
  return (unsigned short)((v.u + 0x8000u) >> 16);
}

__device__ __forceinline__ f32x4 mfma16(short8x a, short8x b, f32x4 c) {
  return __builtin_amdgcn_mfma_f32_16x16x32_bf16(a, b, c, 0, 0, 0);
}

// async global->LDS, 16B per lane. LDS dest = wave-uniform base + lane*16.
__device__ __forceinline__ void gload16(const unsigned short* g, unsigned short* l) {
  __builtin_amdgcn_global_load_lds(
      (__attribute__((address_space(1))) unsigned int*)g,
      (__attribute__((address_space(3))) unsigned int*)l,
      16, 0, 0);
}

// Fragment-major Q/K layout (R5): frag (bh,rb,ks) at ((bh*128+rb)*2+ks)*512 + lane*8.
// V^T frag (bh,rbv,kc) at ((bh*4+rbv)*64+kc)*512 + lane*8.
// R6: fixed m=0. R7: K-split across 2 blocks + combine. R8: raw-HW transcendentals.
// R9 FAILED: launch_bounds(256,8) flash spill. R10: XCD swizzle kept on flash only.
// R11: gemm_proj (256,3). R12: K-compaction. R13: gload_lds staging on both GEMMs
// (146->131us, bank-conflicts halved).
// R14 (this round): gemm_proj residency quantization + V-K1024.
//  (a) (256,3)->(256,5): grid 1280 = exactly 5/CU; at 3-resident rounds were (3,2)
//      (measured occ 33%). 5-resident = ONE round. Cliff check: VGPR cap 102 vs
//      measured 56 (1.8x margin, unlike R9's 64-vs-70); LDS 5x16KB=80KB OK.
//  (b) V n-tiles (n0>=4096) stop at K=1024: WcatT V-rows are 0 for k>=1024 by
//      construction -> skipping is bitwise identical. Every CU sheds the same 0.5
//      block-units (block c+1024 on CU c is always the V-tile) -> no imbalance.
#define C1F 0.0225421076f  // (1/64)*log2e
#define C2F 0.0541010849f  // (0.3/8)*log2e

// ---------------- pack weights
__global__ void pack_w_kernel(const float* __restrict__ Wq_r, const float* __restrict__ Wq_i,
                              const float* __restrict__ Wk_r, const float* __restrict__ Wk_i,
                              const float* __restrict__ Wv, const float* __restrict__ Wo,
                              unsigned short* __restrict__ WcatT, unsigned short* __restrict__ WoT) {
  int gid = blockIdx.x * 256 + threadIdx.x;
  if (gid < 5120 * 2048) {
    int k = gid & 2047;
    int n = gid >> 11;
    int q = n >> 10, j = n & 1023;
    float v;
    if (k < 1024) {
      const float* src = (q == 0) ? Wq_r : (q == 1) ? Wq_i : (q == 2) ? Wk_r : (q == 3) ? Wk_i : Wv;
      v = src[k * 1024 + j];
    } else {
      int k2 = k - 1024;
      if (q == 0)      v = -Wq_i[k2 * 1024 + j];
      else if (q == 1) v =  Wq_r[k2 * 1024 + j];
      else if (q == 2) v = -Wk_i[k2 * 1024 + j];
      else if (q == 3) v =  Wk_r[k2 * 1024 + j];
      else             v = 0.0f;
    }
    WcatT[gid] = f2b(v);
  } else {
    int g2 = gid - 5120 * 2048;            // n*1024 + k
    int k = g2 & 1023, n = g2 >> 10;
    WoT[g2] = f2b(Wo[k * 1024 + n]);
  }
}

// ---------------- pack X: Xcat[4096][2048] = [z_real | z_imag] (bf16)
__global__ void pack_x_kernel(const float* __restrict__ zr, const float* __restrict__ zi,
                              unsigned short* __restrict__ X) {
  int gid = blockIdx.x * 256 + threadIdx.x;  // 4096*2048
  int k = gid & 2047, m = gid >> 11;
  float v = (k < 1024) ? zr[m * 1024 + k] : zi[m * 1024 + (k - 1024)];
  X[gid] = f2b(v);
}

// ---------------- generic zero (float4 granularity)
__global__ void zero_kernel(float4* __restrict__ p) {
  p[(size_t)blockIdx.x * 256 + threadIdx.x] = float4{0.f, 0.f, 0.f, 0.f};
}

// ---------------- mask scan: per (b,half) compaction tables
__global__ void mask_scan_kernel(const int* __restrict__ mask,
                                 unsigned short* __restrict__ pos,
                                 unsigned short* __restrict__ idx,
                                 int* __restrict__ cnt) {
  const int b = blockIdx.x >> 1, half = blockIdx.x & 1;
  __shared__ int sums[256];
  const int t = threadIdx.x;
  const int s0 = half * 1024 + t * 4;
  int m[4];
  int loc = 0;
#pragma unroll
  for (int i = 0; i < 4; i++) { m[i] = mask[b * 2048 + s0 + i]; loc += m[i]; }
  sums[t] = loc;
  __syncthreads();
  for (int off = 1; off < 256; off <<= 1) {
    int v = (t >= off) ? sums[t - off] : 0;
    __syncthreads();
    sums[t] += v;
    __syncthreads();
  }
  int excl = sums[t] - loc;
#pragma unroll
  for (int i = 0; i < 4; i++) {
    int sg = s0 + i;
    if (m[i]) {
      pos[b * 2048 + sg] = (unsigned short)excl;
      idx[(b * 2 + half) * 1024 + excl] = (unsigned short)sg;
      excl++;
    } else {
      pos[b * 2048 + sg] = 0xFFFFu;
    }
  }
  if (t == 255) cnt[b * 2 + half] = sums[255];
}

// ---------------- projection GEMM: gload_lds staging; epilogue writes fragment-major
// Q (uncompacted) and COMPACTED K / V^T via pos lookup.
__global__ __launch_bounds__(256, 5) void gemm_proj_kernel(
    const unsigned short* __restrict__ A, const unsigned short* __restrict__ Bt,
    const unsigned short* __restrict__ pos,
    unsigned short* __restrict__ Qr, unsigned short* __restrict__ Qi,
    unsigned short* __restrict__ Kr, unsigned short* __restrict__ Ki,
    unsigned short* __restrict__ VT) {
  constexpr int K = 2048;
  __shared__ __attribute__((aligned(16))) unsigned short As[128][32];
  __shared__ __attribute__((aligned(16))) unsigned short Bs[128][32];
  const int tid = threadIdx.x;
  const int m0 = blockIdx.x * 128;
  const int n0 = blockIdx.y * 128;
  const int lane = tid & 63, wid = tid >> 6;
  const int l15 = lane & 15, quad = lane >> 4;
  const int wm = (wid & 1) * 64, wn = (wid >> 1) * 64;
  const int r4 = lane >> 2, c8 = (lane & 3) * 8;
  // V columns (n >= 4096) have zero weights for k >= 1024: skip exactly.
  const int kmax = (n0 >= 4096) ? 1024 : K;
  f32x4 acc[4][4] = {};
  const unsigned short* pa0 = A + (size_t)(m0 + wid * 16 + r4) * K + c8;
  const unsigned short* pa1 = pa0 + (size_t)64 * K;
  const unsigned short* pb0 = Bt + (size_t)(n0 + wid * 16 + r4) * K + c8;
  const unsigned short* pb1 = pb0 + (size_t)64 * K;
  unsigned short* la0 = &As[wid * 16][0];
  unsigned short* la1 = &As[64 + wid * 16][0];
  unsigned short* lb0 = &Bs[wid * 16][0];
  unsigned short* lb1 = &Bs[64 + wid * 16][0];
  for (int k0 = 0; k0 < kmax; k0 += 32) {
    __syncthreads();
    gload16(pa0, la0);  gload16(pa1, la1);
    gload16(pb0, lb0);  gload16(pb1, lb1);
    pa0 += 32; pa1 += 32; pb0 += 32; pb1 += 32;
    __syncthreads();
    short8x af[4], bfr[4];
#pragma unroll
    for (int i = 0; i < 4; i++) af[i]  = *(const short8x*)&As[wm + i * 16 + l15][quad * 8];
#pragma unroll
    for (int i = 0; i < 4; i++) bfr[i] = *(const short8x*)&Bs[wn + i * 16 + l15][quad * 8];
#pragma unroll
    for (int mi = 0; mi < 4; mi++)
#pragma unroll
      for (int ni = 0; ni < 4; ni++)
        acc[mi][ni] = mfma16(af[mi], bfr[ni], acc[mi][ni]);
  }
#pragma unroll
  for (int mi = 0; mi < 4; mi++) {
#pragma unroll
    for (int ni = 0; ni < 4; ni++) {
      int gn = n0 + wn + ni * 16 + l15;
      if (gn < 2048) {
        // Q: uncompacted
        int which = gn >> 10, j = gn & 1023, h = j >> 6, dk = j & 63;
        int ks = dk >> 5, q = (dk >> 3) & 3, e = dk & 7;
        unsigned short* dst = which ? Qi : Qr;
#pragma unroll
        for (int r = 0; r < 4; r++) {
          int gm = m0 + wm + mi * 16 + quad * 4 + r;
          int b = gm >> 11, s = gm & 2047;
          int bh = b * HH + h, rb = s >> 4, l = s & 15;
          dst[(size_t)(((bh * 128 + rb) * 2 + ks) * 512 + (q * 16 + l) * 8 + e)] = f2b(acc[mi][ni][r]);
        }
      } else if (gn < 4096) {
        // K: compacted per (b, half)
        int which = gn >> 10, j = gn & 1023, h = j >> 6, dk = j & 63;
        int ks = dk >> 5, q = (dk >> 3) & 3, e = dk & 7;
        unsigned short* dst = (which == 2) ? Kr : Ki;
#pragma unroll
        for (int r = 0; r < 4; r++) {
          int gm = m0 + wm + mi * 16 + quad * 4 + r;
          int b = gm >> 11, s = gm & 2047;
          unsigned short pp = pos[b * 2048 + s];
          if (pp != 0xFFFFu) {
            int hf = s >> 10;
            int bh = b * HH + h, rb = hf * 64 + (pp >> 4), l = pp & 15;
            dst[(size_t)(((bh * 128 + rb) * 2 + ks) * 512 + (q * 16 + l) * 8 + e)] = f2b(acc[mi][ni][r]);
          }
        }
      } else {
        // V^T: compacted per (b, half)
        int j = gn - 4096, h = j >> 6, dk = j & 63;
        int rbv = dk >> 4, lv = dk & 15;
#pragma unroll
        for (int r = 0; r < 4; r++) {
          int gm = m0 + wm + mi * 16 + quad * 4 + r;
          int b = gm >> 11, s = gm & 2047;
          unsigned short pp = pos[b * 2048 + s];
          if (pp != 0xFFFFu) {
            int hf = s >> 10;
            int bh = b * HH + h, kc = hf * 32 + (pp >> 5), qv = (pp >> 3) & 3, ev = pp & 7;
            VT[(size_t)(((bh * 4 + rbv) * 64 + kc) * 512 + (qv * 16 + lv) * 8 + ev)] = f2b(acc[mi][ni][r]);
          }
        }
      }
    }
  }
}

// ---------------- flash attention over COMPACTED keys, fixed-m, K-range split
__global__ __launch_bounds__(256, 6) void flash_kernel(
    const unsigned short* __restrict__ Qr, const unsigned short* __restrict__ Qi,
    const unsigned short* __restrict__ Kr, const unsigned short* __restrict__ Ki,
    const unsigned short* __restrict__ VT, const int* __restrict__ cnt,
    float* __restrict__ ctxP0, float* __restrict__ ctxP1,
    float* __restrict__ Lp0, float* __restrict__ Lp1) {
  __shared__ __attribute__((aligned(16))) unsigned short Ps[4][16][72];
  const int tid = threadIdx.x;
  const int lane = tid & 63, wid = tid >> 6;
  const int l15 = lane & 15, quad = lane >> 4;
  // XCD swizzle (bijective, 2048 % 8 == 0)
  int lin = blockIdx.x + 32 * (blockIdx.y + 16 * blockIdx.z);
  lin = ((lin & 7) << 8) | (lin >> 3);
  const int qt = (lin & 31) * 64;
  const int h = (lin >> 5) & 15;
  const int z = lin >> 9;
  const int b = z >> 1, half = z & 1;
  const int bh = b * HH + h;
  float* __restrict__ cp = half ? ctxP1 : ctxP0;
  float* __restrict__ lp = half ? Lp1 : Lp0;
  const int rb = (qt >> 4) + wid;
  const int qbase = (bh * 128 + rb) * 1024 + lane * 8;
  short8x fqr0 = *(const short8x*)(Qr + qbase);
  short8x fqr1 = *(const short8x*)(Qr + qbase + 512);
  short8x fqi0 = *(const short8x*)(Qi + qbase);
  short8x fqi1 = *(const short8x*)(Qi + qbase + 512);
  f32x4 ctxacc[4] = {};
  float lsum[4] = {0.f, 0.f, 0.f, 0.f};

  const int cntbh = cnt[b * 2 + half];
  const int kend = ((cntbh + 63) >> 6) << 6;
  const int kt0 = half * 1024;
  for (int ktl = 0; ktl < kend; ktl += 64) {
    const int kt = kt0 + ktl;
#pragma unroll
    for (int nb = 0; nb < 4; nb++) {
      const int j = ktl + nb * 16 + l15;           // compacted-local index
      const int koff = (bh * 128 + (kt >> 4) + nb) * 1024 + lane * 8;
      short8x bkr0 = *(const short8x*)(Kr + koff);
      short8x bkr1 = *(const short8x*)(Kr + koff + 512);
      short8x bki0 = *(const short8x*)(Ki + koff);
      short8x bki1 = *(const short8x*)(Ki + koff + 512);
      f32x4 sr = {0.f, 0.f, 0.f, 0.f};
      sr = mfma16(fqr0, bkr0, sr);  sr = mfma16(fqr1, bkr1, sr);
      sr = mfma16(fqi0, bki0, sr);  sr = mfma16(fqi1, bki1, sr);
      f32x4 sa = {0.f, 0.f, 0.f, 0.f};
      sa = mfma16(fqi0, bkr0, sa);  sa = mfma16(fqi1, bkr1, sa);
      f32x4 sb = {0.f, 0.f, 0.f, 0.f};
      sb = mfma16(fqr0, bki0, sb);  sb = mfma16(fqr1, bki1, sb);
#pragma unroll
      for (int r = 0; r < 4; r++) {
        float a = sr[r];
        float d = sa[r] - sb[r];
        float r2 = __builtin_fmaf(a, a, d * d);
        float inv = __builtin_amdgcn_rsqf(r2);
        float arg = inv * __builtin_fmaf(C1F, r2, C2F * a);
        float p = (j < cntbh) ? __builtin_amdgcn_exp2f(arg) : 0.0f;  // select, not mul
        lsum[r] += p;
        Ps[wid][quad * 4 + r][nb * 16 + l15] = f2b_fast(p);
      }
    }
    // PV (Ps per-wave; lgkmcnt wait suffices, no barrier). V pad rows pre-zeroed.
#pragma unroll
    for (int ks = 0; ks < 2; ks++)
#pragma unroll
      for (int db = 0; db < 4; db++) {
        int voff = ((bh * 4 + db) * 64 + (kt >> 5) + ks) * 512 + lane * 8;
        short8x bv = *(const short8x*)(VT + voff);
        short8x ap = *(const short8x*)&Ps[wid][l15][ks * 32 + quad * 8];
        ctxacc[db] = mfma16(ap, bv, ctxacc[db]);
      }
  }
  // reduce partial l over the 16 column-lanes
#pragma unroll
  for (int r = 0; r < 4; r++) {
#pragma unroll
    for (int off = 1; off < 16; off <<= 1) lsum[r] += __shfl_xor(lsum[r], off, 64);
  }
#pragma unroll
  for (int r = 0; r < 4; r++) {
    int s = qt + wid * 16 + quad * 4 + r;
#pragma unroll
    for (int db = 0; db < 4; db++)
      cp[((size_t)b * SS + s) * DD + h * DKK + db * 16 + l15] = ctxacc[db][r];
    if (l15 == 0) lp[(size_t)bh * SS + s] = lsum[r];
  }
}

// ---------------- combine: ctx_bf16 = (P0+P1) / (L0+L1)
__global__ __launch_bounds__(256) void combine_kernel(
    const float* __restrict__ ctxP0, const float* __restrict__ ctxP1,
    const float* __restrict__ Lp0, const float* __restrict__ Lp1,
    unsigned short* __restrict__ ctx) {
  int idx = blockIdx.x * 256 + threadIdx.x;   // 1048576 threads
  int g = idx * 4;
  int c = g & 1023, s = (g >> 10) & 2047, b = g >> 21;
  int h = c >> 6;
  size_t loff = (size_t)(b * HH + h) * SS + s;
  float linv = 1.0f / (Lp0[loff] + Lp1[loff]);
  float4 p0 = *(const float4*)(ctxP0 + g);
  float4 p1 = *(const float4*)(ctxP1 + g);
  ushort4 o;
  o.x = f2b((p0.x + p1.x) * linv);
  o.y = f2b((p0.y + p1.y) * linv);
  o.z = f2b((p0.z + p1.z) * linv);
  o.w = f2b((p0.w + p1.w) * linv);
  *(ushort4*)(ctx + g) = o;
}

// ---------------- output GEMM: out = ctx @ WoT^T + bias (gload_lds staging)
__global__ __launch_bounds__(256, 2) void gemm_out_kernel(
    const unsigned short* __restrict__ A, const unsigned short* __restrict__ Bt,
    const float* __restrict__ bias, float* __restrict__ out) {
  constexpr int K = 1024;
  __shared__ __attribute__((aligned(16))) unsigned short As[128][32];
  __shared__ __attribute__((aligned(16))) unsigned short Bs[128][32];
  const int tid = threadIdx.x;
  const int m0 = blockIdx.x * 128;
  const int n0 = blockIdx.y * 128;
  const int lane = tid & 63, wid = tid >> 6;
  const int l15 = lane & 15, quad = lane >> 4;
  const int wm = (wid & 1) * 64, wn = (wid >> 1) * 64;
  const int r4 = lane >> 2, c8 = (lane & 3) * 8;
  f32x4 acc[4][4] = {};
  const unsigned short* pa0 = A + (size_t)(m0 + wid * 16 + r4) * K + c8;
  const unsigned short* pa1 = pa0 + (size_t)64 * K;
  const unsigned short* pb0 = Bt + (size_t)(n0 + wid * 16 + r4) * K + c8;
  const unsigned short* pb1 = pb0 + (size_t)64 * K;
  unsigned short* la0 = &As[wid * 16][0];
  unsigned short* la1 = &As[64 + wid * 16][0];
  unsigned short* lb0 = &Bs[wid * 16][0];
  unsigned short* lb1 = &Bs[64 + wid * 16][0];
  for (int k0 = 0; k0 < K; k0 += 32) {
    __syncthreads();
    gload16(pa0, la0);  gload16(pa1, la1);
    gload16(pb0, lb0);  gload16(pb1, lb1);
    pa0 += 32; pa1 += 32; pb0 += 32; pb1 += 32;
    __syncthreads();
    short8x af[4], bfr[4];
#pragma unroll
    for (int i = 0; i < 4; i++) af[i]  = *(const short8x*)&As[wm + i * 16 + l15][quad * 8];
#pragma unroll
    for (int i = 0; i < 4; i++) bfr[i] = *(const short8x*)&Bs[wn + i * 16 + l15][quad * 8];
#pragma unroll
    for (int mi = 0; mi < 4; mi++)
#pragma unroll
      for (int ni = 0; ni < 4; ni++)
        acc[mi][ni] = mfma16(af[mi], bfr[ni], acc[mi][ni]);
  }
#pragma unroll
  for (int mi = 0; mi < 4; mi++)
#pragma unroll
    for (int ni = 0; ni < 4; ni++) {
      int gn = n0 + wn + ni * 16 + l15;
      float bv = bias[gn];
#pragma unroll
      for (int r = 0; r < 4; r++) {
        int gm = m0 + wm + mi * 16 + quad * 4 + r;
        out[(size_t)gm * 1024 + gn] = acc[mi][ni][r] + bv;
      }
    }
}

// ---------------- probs_mean over COMPACTED keys; out2 pre-zeroed, valid columns
// scattered via idx.
__global__ __launch_bounds__(256, 4) void probsmean_kernel(
    const unsigned short* __restrict__ Qr, const unsigned short* __restrict__ Qi,
    const unsigned short* __restrict__ Kr, const unsigned short* __restrict__ Ki,
    const int* __restrict__ cnt, const unsigned short* __restrict__ idxT,
    const float* __restrict__ Lp0, const float* __restrict__ Lp1,
    float* __restrict__ out2) {
  const int tid = threadIdx.x, lane = tid & 63, wid = tid >> 6;
  const int l15 = lane & 15, quad = lane >> 4;
  const int qt = blockIdx.x * 64;
  const int b = blockIdx.z;
  const int c0 = cnt[b * 2], c1 = cnt[b * 2 + 1];
  const int t0n = (c0 + 63) >> 6;
  const int t1n = (c1 + 63) >> 6;
  const int t = blockIdx.y;
  int half, jl0, cnth;
  if (t < t0n)            { half = 0; jl0 = t * 64;         cnth = c0; }
  else if (t < t0n + t1n) { half = 1; jl0 = (t - t0n) * 64; cnth = c1; }
  else return;  // out2 pre-zeroed
  const int qrow0 = qt + wid * 16;
  const int qrb = (qt >> 4) + wid;
  const int ktb = half * 64 + (jl0 >> 4);
  int korig[4]; bool vld[4];
#pragma unroll
  for (int nb = 0; nb < 4; nb++) {
    int j = jl0 + nb * 16 + l15;
    vld[nb] = j < cnth;
    korig[nb] = idxT[(b * 2 + half) * 1024 + j];
  }
  float psum[4][4] = {};  // [nb][r]
  for (int h = 0; h < HH; h++) {
    const int bh = b * HH + h;
    const int qoff = (bh * 128 + qrb) * 1024 + lane * 8;
    short8x fqr0 = *(const short8x*)(Qr + qoff);
    short8x fqr1 = *(const short8x*)(Qr + qoff + 512);
    short8x fqi0 = *(const short8x*)(Qi + qoff);
    short8x fqi1 = *(const short8x*)(Qi + qoff + 512);
    const float4 lv0 = *(const float4*)(Lp0 + (size_t)bh * SS + qrow0 + quad * 4);
    const float4 lv1 = *(const float4*)(Lp1 + (size_t)bh * SS + qrow0 + quad * 4);
    float li[4];
    li[0] = 1.0f / (lv0.x + lv1.x); li[1] = 1.0f / (lv0.y + lv1.y);
    li[2] = 1.0f / (lv0.z + lv1.z); li[3] = 1.0f / (lv0.w + lv1.w);
#pragma unroll
    for (int nb = 0; nb < 4; nb++) {
      const int koff = (bh * 128 + ktb + nb) * 1024 + lane * 8;
      short8x bkr0 = *(const short8x*)(Kr + koff);
      short8x bkr1 = *(const short8x*)(Kr + koff + 512);
      short8x bki0 = *(const short8x*)(Ki + koff);
      short8x bki1 = *(const short8x*)(Ki + koff + 512);
      f32x4 sr = {0.f, 0.f, 0.f, 0.f};
      sr = mfma16(fqr0, bkr0, sr);  sr = mfma16(fqr1, bkr1, sr);
      sr = mfma16(fqi0, bki0, sr);  sr = mfma16(fqi1, bki1, sr);
      f32x4 sa = {0.f, 0.f, 0.f, 0.f};  // Qi.Kr
      sa = mfma16(fqi0, bkr0, sa);  sa = mfma16(fqi1, bkr1, sa);
      f32x4 sb = {0.f, 0.f, 0.f, 0.f};  // Qr.Ki
      sb = mfma16(fqr0, bki0, sb);  sb = mfma16(fqr1, bki1, sb);
#pragma unroll
      for (int r = 0; r < 4; r++) {
        float a = sr[r];
        float d = sa[r] - sb[r];
        float r2 = __builtin_fmaf(a, a, d * d);
        float inv = __builtin_amdgcn_rsqf(r2);
        float arg = inv * __builtin_fmaf(C1F, r2, C2F * a);
        float p = vld[nb] ? __builtin_amdgcn_exp2f(arg) * li[r] : 0.0f;  // select
        psum[nb][r] += p;
      }
    }
  }
#pragma unroll
  for (int nb = 0; nb < 4; nb++)
#pragma unroll
    for (int r = 0; r < 4; r++) {
      if (vld[nb]) {
        int qrow = qrow0 + quad * 4 + r;
        out2[((size_t)b * SS + qrow) * SS + korig[nb]] = psum[nb][r] * 0.0625f;
      }
    }
}

extern "C" void kernel_launch(void* const* d_in, const int* in_sizes, int n_in,
                              void* d_out, int out_size, void* d_ws, size_t ws_size,
                              hipStream_t stream) {
  const float* z_real = (const float*)d_in[0];
  const float* z_imag = (const float*)d_in[1];
  const float* Wq_r = (const float*)d_in[2];
  const float* Wq_i = (const float*)d_in[3];
  const float* Wk_r = (const float*)d_in[4];
  const float* Wk_i = (const float*)d_in[5];
  const float* Wv   = (const float*)d_in[6];
  const float* Wo_w = (const float*)d_in[7];
  const float* Wo_b = (const float*)d_in[8];
  const int*   mask = (const int*)d_in[9];
  char* ws = (char*)d_ws;

  // ws layout (bytes). ctxP0/ctxP1 ALIAS WcatT/Xcat: dead after gemm_proj (stream-serial).
  constexpr size_t QKV_BYTES = 8388608;  // B*H*S*DK*2
  unsigned short* Qr   = (unsigned short*)(ws + 0);
  unsigned short* Qi   = (unsigned short*)(ws + QKV_BYTES);
  unsigned short* Kr   = (unsigned short*)(ws + 2 * QKV_BYTES);
  unsigned short* Ki   = (unsigned short*)(ws + 3 * QKV_BYTES);
  unsigned short* VT   = (unsigned short*)(ws + 4 * QKV_BYTES);
  unsigned short* ctx  = (unsigned short*)(ws + 5 * QKV_BYTES);              // 8 MB bf16
  unsigned short* WcatT= (unsigned short*)(ws + 50331648);                   // 20 MB
  unsigned short* WoT  = (unsigned short*)(ws + 71303168);                   // 2 MB
  unsigned short* Xcat = (unsigned short*)(ws + 73400320);                   // 16 MB
  float* ctxP0 = (float*)(ws + 50331648);                                    // aliases WcatT (16 MB)
  float* ctxP1 = (float*)(ws + 73400320);                                    // aliases Xcat (16 MB)
  float* Lp0   = (float*)(ws + 90177536);                                    // 256 KB
  float* Lp1   = (float*)(ws + 90439680);                                    // 256 KB

  float* out  = (float*)d_out;
  float* out2 = out + (size_t)BB * SS * DD;

  // Compaction tables live in d_out scratch (`out` region): dead until gemm_out,
  // which runs last. probsmean (reads idx) ordered before combine/gemm_out.
  unsigned short* posT = (unsigned short*)out;       // [2][2048] = 8 KB
  unsigned short* idxT = posT + 4096;                // [2][2][1024] = 8 KB
  int* cntT = (int*)(idxT + 4096);                   // [2][2]

  pack_w_kernel<<<dim3(45056), dim3(256), 0, stream>>>(Wq_r, Wq_i, Wk_r, Wk_i, Wv, Wo_w, WcatT, WoT);
  pack_x_kernel<<<dim3(32768), dim3(256), 0, stream>>>(z_real, z_imag, Xcat);
  zero_kernel<<<dim3(2048), dim3(256), 0, stream>>>((float4*)VT);            // 8 MB: V pad rows = 0
  zero_kernel<<<dim3(8192), dim3(256), 0, stream>>>((float4*)out2);          // 32 MB: masked cols = 0
  mask_scan_kernel<<<dim3(4), dim3(256), 0, stream>>>(mask, posT, idxT, cntT);
  gemm_proj_kernel<<<dim3(32, 40), dim3(256), 0, stream>>>(Xcat, WcatT, posT, Qr, Qi, Kr, Ki, VT);
  flash_kernel<<<dim3(32, 16, 4), dim3(256), 0, stream>>>(Qr, Qi, Kr, Ki, VT, cntT, ctxP0, ctxP1, Lp0, Lp1);
  probsmean_kernel<<<dim3(32, 32, 2), dim3(256), 0, stream>>>(Qr, Qi, Kr, Ki, cntT, idxT, Lp0, Lp1, out2);
  combine_kernel<<<dim3(4096), dim3(256), 0, stream>>>(ctxP0, ctxP1, Lp0, Lp1, ctx);
  gemm_out_kernel<<<dim3(32, 8), dim3(256), 0, stream>>>(ctx, WoT, Wo_b, out);
}

// Round 8
// 424.278 us; speedup vs baseline: 1.7231x; 1.0747x over previous
//
#include <hip/hip_runtime.h>
#include <cstdint>
#include <cstddef>

#define BB 2
#define SS 2048
#define DD 1024
#define HH 16
#define DKK 64

typedef __attribute__((ext_vector_type(8))) short short8x;
typedef __attribute__((ext_vector_type(4))) float f32x4;

__device__ __forceinline__ unsigned short f2b(float f) {
  union { float f; unsigned u; } v; v.f = f;
  unsigned r = (v.u + 0x7fffu + ((v.u >> 16) & 1u)) >> 16;  // RNE
  return (unsigned short)r;
}

// hot-path bf16: round-half-up, 2 VALU (vs ~5 for RNE). Used only for Ps probabilities.
__device__ __forceinline__ unsigned short f2b_fast(float f) {
  union { float f; unsigned u; } v; v.f = f;
  return (unsigned short)((v.u + 0x8000u) >> 16);
}

__device__ __forceinline__ f32x4 mfma16(short8x a, short8x b, f32x4 c) {
  return __builtin_amdgcn_mfma_f32_16x16x32_bf16(a, b, c, 0, 0, 0);
}

// async global->LDS, 16B per lane. LDS dest = wave-uniform base + lane*16.
__device__ __forceinline__ void gload16(const unsigned short* g, unsigned short* l) {
  __builtin_amdgcn_global_load_lds(
      (__attribute__((address_space(1))) unsigned int*)g,
      (__attribute__((address_space(3))) unsigned int*)l,
      16, 0, 0);
}

// Fragment-major Q/K layout (R5). R6: fixed m=0. R7: K-split + combine. R8: raw-HW
// transcendentals. R9 FAILED (flash spill at 8/EU). R10: XCD swizzle on flash.
// R11: gemm_proj (256,3). R12: K-compaction. R13: gload_lds staging (131us).
// R14: gemm_proj (256,5) single-round + V-K1024 (114.5us, occ 46, no spill).
// R15 (this round):
//  (a) pack_w TILED TRANSPOSE: old version read src[(k)*1024+j] with lane->k =
//      64 lines x 4B used per wave (~16x fetch amplification); suspected ~40-80us
//      (unaccounted gap in the frame budget). New: 64x64 tile via LDS [64][65]
//      (pad -> conflict-free transposed read), coalesced loads AND stores. Same
//      f2b -> bitwise identical.
//  (b) flash 128-row Q-tiles: grid 2048->1024 = 4/CU at 6-resident = SINGLE round
//      (was rounds (6,2); round 2 ran at 2-block issue rate). #pragma unroll 1
//      s2-loop keeps VGPR at 40 (Q frags reloaded per subtile; R9 lesson).
#define C1F 0.0225421076f  // (1/64)*log2e
#define C2F 0.0541010849f  // (0.3/8)*log2e

// ---------------- pack weights: tiled transpose, coalesced both sides
// WcatT[n][k]: q=n>>10, j=n&1023; k<1024 -> {Wqr,Wqi,Wkr,Wki,Wv}[q][k][j]
//              k>=1024 -> {-Wqi, Wqr, -Wki, Wkr, 0}[q][k-1024][j]
// WoT[n][k] = Wo[k][n].
__global__ __launch_bounds__(256) void pack_w_kernel(
    const float* __restrict__ Wq_r, const float* __restrict__ Wq_i,
    const float* __restrict__ Wk_r, const float* __restrict__ Wk_i,
    const float* __restrict__ Wv, const float* __restrict__ Wo,
    unsigned short* __restrict__ WcatT, unsigned short* __restrict__ WoT) {
  __shared__ float tile[64][65];
  const int tid = threadIdx.x;
  int bid = blockIdx.x;
  if (bid < 2560) {
    // WcatT part: 80 n-tiles x 32 k-tiles
    const int kt = bid & 31, nt = bid >> 5;
    const int k0 = kt * 64, n0 = nt * 64;
    const int q = n0 >> 10, j0 = n0 & 1023;
    const float* src;
    float sgn = 1.0f;
    bool zero = false;
    if (k0 < 1024) {
      src = (q == 0) ? Wq_r : (q == 1) ? Wq_i : (q == 2) ? Wk_r : (q == 3) ? Wk_i : Wv;
    } else {
      if (q == 0)      { src = Wq_i; sgn = -1.0f; }
      else if (q == 1) { src = Wq_r; }
      else if (q == 2) { src = Wk_i; sgn = -1.0f; }
      else if (q == 3) { src = Wk_r; }
      else             { src = Wv; zero = true; }
    }
    const int ks0 = k0 & 1023;
    if (!zero) {
#pragma unroll
      for (int i = 0; i < 16; i++) {
        int idx = i * 256 + tid;
        int r = idx >> 6, c = idx & 63;        // r: k-local, c: j-local
        tile[r][c] = src[(size_t)(ks0 + r) * 1024 + j0 + c];
      }
      __syncthreads();
#pragma unroll
      for (int i = 0; i < 16; i++) {
        int idx = i * 256 + tid;
        int nr = idx >> 6, kc = idx & 63;      // nr: j-local (output row), kc: k-local
        WcatT[(size_t)(n0 + nr) * 2048 + k0 + kc] = f2b(sgn * tile[kc][nr]);
      }
    } else {
#pragma unroll
      for (int i = 0; i < 16; i++) {
        int idx = i * 256 + tid;
        int nr = idx >> 6, kc = idx & 63;
        WcatT[(size_t)(n0 + nr) * 2048 + k0 + kc] = 0;
      }
    }
  } else {
    // WoT part: 16 x 16 tiles of 1024x1024 transpose
    bid -= 2560;
    const int kt = bid & 15, nt = bid >> 4;
    const int k0 = kt * 64, n0 = nt * 64;
#pragma unroll
    for (int i = 0; i < 16; i++) {
      int idx = i * 256 + tid;
      int r = idx >> 6, c = idx & 63;
      tile[r][c] = Wo[(size_t)(k0 + r) * 1024 + n0 + c];
    }
    __syncthreads();
#pragma unroll
    for (int i = 0; i < 16; i++) {
      int idx = i * 256 + tid;
      int nr = idx >> 6, kc = idx & 63;
      WoT[(size_t)(n0 + nr) * 1024 + k0 + kc] = f2b(tile[kc][nr]);
    }
  }
}

// ---------------- pack X: Xcat[4096][2048] = [z_real | z_imag] (bf16)
__global__ void pack_x_kernel(const float* __restrict__ zr, const float* __restrict__ zi,
                              unsigned short* __restrict__ X) {
  int gid = blockIdx.x * 256 + threadIdx.x;  // 4096*2048
  int k = gid & 2047, m = gid >> 11;
  float v = (k < 1024) ? zr[m * 1024 + k] : zi[m * 1024 + (k - 1024)];
  X[gid] = f2b(v);
}

// ---------------- generic zero (float4 granularity)
__global__ void zero_kernel(float4* __restrict__ p) {
  p[(size_t)blockIdx.x * 256 + threadIdx.x] = float4{0.f, 0.f, 0.f, 0.f};
}

// ---------------- mask scan: per (b,half) compaction tables
__global__ void mask_scan_kernel(const int* __restrict__ mask,
                                 unsigned short* __restrict__ pos,
                                 unsigned short* __restrict__ idx,
                                 int* __restrict__ cnt) {
  const int b = blockIdx.x >> 1, half = blockIdx.x & 1;
  __shared__ int sums[256];
  const int t = threadIdx.x;
  const int s0 = half * 1024 + t * 4;
  int m[4];
  int loc = 0;
#pragma unroll
  for (int i = 0; i < 4; i++) { m[i] = mask[b * 2048 + s0 + i]; loc += m[i]; }
  sums[t] = loc;
  __syncthreads();
  for (int off = 1; off < 256; off <<= 1) {
    int v = (t >= off) ? sums[t - off] : 0;
    __syncthreads();
    sums[t] += v;
    __syncthreads();
  }
  int excl = sums[t] - loc;
#pragma unroll
  for (int i = 0; i < 4; i++) {
    int sg = s0 + i;
    if (m[i]) {
      pos[b * 2048 + sg] = (unsigned short)excl;
      idx[(b * 2 + half) * 1024 + excl] = (unsigned short)sg;
      excl++;
    } else {
      pos[b * 2048 + sg] = 0xFFFFu;
    }
  }
  if (t == 255) cnt[b * 2 + half] = sums[255];
}

// ---------------- projection GEMM: gload_lds staging; epilogue writes fragment-major
// Q (uncompacted) and COMPACTED K / V^T via pos lookup.
__global__ __launch_bounds__(256, 5) void gemm_proj_kernel(
    const unsigned short* __restrict__ A, const unsigned short* __restrict__ Bt,
    const unsigned short* __restrict__ pos,
    unsigned short* __restrict__ Qr, unsigned short* __restrict__ Qi,
    unsigned short* __restrict__ Kr, unsigned short* __restrict__ Ki,
    unsigned short* __restrict__ VT) {
  constexpr int K = 2048;
  __shared__ __attribute__((aligned(16))) unsigned short As[128][32];
  __shared__ __attribute__((aligned(16))) unsigned short Bs[128][32];
  const int tid = threadIdx.x;
  const int m0 = blockIdx.x * 128;
  const int n0 = blockIdx.y * 128;
  const int lane = tid & 63, wid = tid >> 6;
  const int l15 = lane & 15, quad = lane >> 4;
  const int wm = (wid & 1) * 64, wn = (wid >> 1) * 64;
  const int r4 = lane >> 2, c8 = (lane & 3) * 8;
  // V columns (n >= 4096) have zero weights for k >= 1024: skip exactly.
  const int kmax = (n0 >= 4096) ? 1024 : K;
  f32x4 acc[4][4] = {};
  const unsigned short* pa0 = A + (size_t)(m0 + wid * 16 + r4) * K + c8;
  const unsigned short* pa1 = pa0 + (size_t)64 * K;
  const unsigned short* pb0 = Bt + (size_t)(n0 + wid * 16 + r4) * K + c8;
  const unsigned short* pb1 = pb0 + (size_t)64 * K;
  unsigned short* la0 = &As[wid * 16][0];
  unsigned short* la1 = &As[64 + wid * 16][0];
  unsigned short* lb0 = &Bs[wid * 16][0];
  unsigned short* lb1 = &Bs[64 + wid * 16][0];
  for (int k0 = 0; k0 < kmax; k0 += 32) {
    __syncthreads();
    gload16(pa0, la0);  gload16(pa1, la1);
    gload16(pb0, lb0);  gload16(pb1, lb1);
    pa0 += 32; pa1 += 32; pb0 += 32; pb1 += 32;
    __syncthreads();
    short8x af[4], bfr[4];
#pragma unroll
    for (int i = 0; i < 4; i++) af[i]  = *(const short8x*)&As[wm + i * 16 + l15][quad * 8];
#pragma unroll
    for (int i = 0; i < 4; i++) bfr[i] = *(const short8x*)&Bs[wn + i * 16 + l15][quad * 8];
#pragma unroll
    for (int mi = 0; mi < 4; mi++)
#pragma unroll
      for (int ni = 0; ni < 4; ni++)
        acc[mi][ni] = mfma16(af[mi], bfr[ni], acc[mi][ni]);
  }
#pragma unroll
  for (int mi = 0; mi < 4; mi++) {
#pragma unroll
    for (int ni = 0; ni < 4; ni++) {
      int gn = n0 + wn + ni * 16 + l15;
      if (gn < 2048) {
        // Q: uncompacted
        int which = gn >> 10, j = gn & 1023, h = j >> 6, dk = j & 63;
        int ks = dk >> 5, q = (dk >> 3) & 3, e = dk & 7;
        unsigned short* dst = which ? Qi : Qr;
#pragma unroll
        for (int r = 0; r < 4; r++) {
          int gm = m0 + wm + mi * 16 + quad * 4 + r;
          int b = gm >> 11, s = gm & 2047;
          int bh = b * HH + h, rb = s >> 4, l = s & 15;
          dst[(size_t)(((bh * 128 + rb) * 2 + ks) * 512 + (q * 16 + l) * 8 + e)] = f2b(acc[mi][ni][r]);
        }
      } else if (gn < 4096) {
        // K: compacted per (b, half)
        int which = gn >> 10, j = gn & 1023, h = j >> 6, dk = j & 63;
        int ks = dk >> 5, q = (dk >> 3) & 3, e = dk & 7;
        unsigned short* dst = (which == 2) ? Kr : Ki;
#pragma unroll
        for (int r = 0; r < 4; r++) {
          int gm = m0 + wm + mi * 16 + quad * 4 + r;
          int b = gm >> 11, s = gm & 2047;
          unsigned short pp = pos[b * 2048 + s];
          if (pp != 0xFFFFu) {
            int hf = s >> 10;
            int bh = b * HH + h, rb = hf * 64 + (pp >> 4), l = pp & 15;
            dst[(size_t)(((bh * 128 + rb) * 2 + ks) * 512 + (q * 16 + l) * 8 + e)] = f2b(acc[mi][ni][r]);
          }
        }
      } else {
        // V^T: compacted per (b, half)
        int j = gn - 4096, h = j >> 6, dk = j & 63;
        int rbv = dk >> 4, lv = dk & 15;
#pragma unroll
        for (int r = 0; r < 4; r++) {
          int gm = m0 + wm + mi * 16 + quad * 4 + r;
          int b = gm >> 11, s = gm & 2047;
          unsigned short pp = pos[b * 2048 + s];
          if (pp != 0xFFFFu) {
            int hf = s >> 10;
            int bh = b * HH + h, kc = hf * 32 + (pp >> 5), qv = (pp >> 3) & 3, ev = pp & 7;
            VT[(size_t)(((bh * 4 + rbv) * 64 + kc) * 512 + (qv * 16 + lv) * 8 + ev)] = f2b(acc[mi][ni][r]);
          }
        }
      }
    }
  }
}

// ---------------- flash attention over COMPACTED keys, 128-row Q-tiles (R15)
// grid (16,16,4) = 1024 blocks = 4/CU at 6-resident = single round. s2-loop
// (unroll 1) iterates the two 64-row subtiles with the exact old block body ->
// VGPR stays 40.
__global__ __launch_bounds__(256, 6) void flash_kernel(
    const unsigned short* __restrict__ Qr, const unsigned short* __restrict__ Qi,
    const unsigned short* __restrict__ Kr, const unsigned short* __restrict__ Ki,
    const unsigned short* __restrict__ VT, const int* __restrict__ cnt,
    float* __restrict__ ctxP0, float* __restrict__ ctxP1,
    float* __restrict__ Lp0, float* __restrict__ Lp1) {
  __shared__ __attribute__((aligned(16))) unsigned short Ps[4][16][72];
  const int tid = threadIdx.x;
  const int lane = tid & 63, wid = tid >> 6;
  const int l15 = lane & 15, quad = lane >> 4;
  // XCD swizzle (bijective, 1024 % 8 == 0): each XCD gets 8 heads of one z.
  int lin = blockIdx.x + 16 * (blockIdx.y + 16 * blockIdx.z);
  lin = ((lin & 7) << 7) | (lin >> 3);
  const int qt2 = (lin & 15) * 128;
  const int h = (lin >> 4) & 15;
  const int z = lin >> 8;
  const int b = z >> 1, half = z & 1;
  const int bh = b * HH + h;
  float* __restrict__ cp = half ? ctxP1 : ctxP0;
  float* __restrict__ lp = half ? Lp1 : Lp0;
  const int cntbh = cnt[b * 2 + half];
  const int kend = ((cntbh + 63) >> 6) << 6;
  const int kt0 = half * 1024;

#pragma unroll 1
  for (int s2 = 0; s2 < 2; s2++) {
    const int qt = qt2 + s2 * 64;
    const int rb = (qt >> 4) + wid;
    const int qbase = (bh * 128 + rb) * 1024 + lane * 8;
    short8x fqr0 = *(const short8x*)(Qr + qbase);
    short8x fqr1 = *(const short8x*)(Qr + qbase + 512);
    short8x fqi0 = *(const short8x*)(Qi + qbase);
    short8x fqi1 = *(const short8x*)(Qi + qbase + 512);
    f32x4 ctxacc[4] = {};
    float lsum[4] = {0.f, 0.f, 0.f, 0.f};

    for (int ktl = 0; ktl < kend; ktl += 64) {
      const int kt = kt0 + ktl;
#pragma unroll
      for (int nb = 0; nb < 4; nb++) {
        const int j = ktl + nb * 16 + l15;           // compacted-local index
        const int koff = (bh * 128 + (kt >> 4) + nb) * 1024 + lane * 8;
        short8x bkr0 = *(const short8x*)(Kr + koff);
        short8x bkr1 = *(const short8x*)(Kr + koff + 512);
        short8x bki0 = *(const short8x*)(Ki + koff);
        short8x bki1 = *(const short8x*)(Ki + koff + 512);
        f32x4 sr = {0.f, 0.f, 0.f, 0.f};
        sr = mfma16(fqr0, bkr0, sr);  sr = mfma16(fqr1, bkr1, sr);
        sr = mfma16(fqi0, bki0, sr);  sr = mfma16(fqi1, bki1, sr);
        f32x4 sa = {0.f, 0.f, 0.f, 0.f};
        sa = mfma16(fqi0, bkr0, sa);  sa = mfma16(fqi1, bkr1, sa);
        f32x4 sb = {0.f, 0.f, 0.f, 0.f};
        sb = mfma16(fqr0, bki0, sb);  sb = mfma16(fqr1, bki1, sb);
#pragma unroll
        for (int r = 0; r < 4; r++) {
          float a = sr[r];
          float d = sa[r] - sb[r];
          float r2 = __builtin_fmaf(a, a, d * d);
          float inv = __builtin_amdgcn_rsqf(r2);
          float arg = inv * __builtin_fmaf(C1F, r2, C2F * a);
          float p = (j < cntbh) ? __builtin_amdgcn_exp2f(arg) : 0.0f;  // select, not mul
          lsum[r] += p;
          Ps[wid][quad * 4 + r][nb * 16 + l15] = f2b_fast(p);
        }
      }
      // PV (Ps per-wave; lgkmcnt wait suffices, no barrier). V pad rows pre-zeroed.
#pragma unroll
      for (int ks = 0; ks < 2; ks++)
#pragma unroll
        for (int db = 0; db < 4; db++) {
          int voff = ((bh * 4 + db) * 64 + (kt >> 5) + ks) * 512 + lane * 8;
          short8x bv = *(const short8x*)(VT + voff);
          short8x ap = *(const short8x*)&Ps[wid][l15][ks * 32 + quad * 8];
          ctxacc[db] = mfma16(ap, bv, ctxacc[db]);
        }
    }
    // reduce partial l over the 16 column-lanes
#pragma unroll
    for (int r = 0; r < 4; r++) {
#pragma unroll
      for (int off = 1; off < 16; off <<= 1) lsum[r] += __shfl_xor(lsum[r], off, 64);
    }
#pragma unroll
    for (int r = 0; r < 4; r++) {
      int s = qt + wid * 16 + quad * 4 + r;
#pragma unroll
      for (int db = 0; db < 4; db++)
        cp[((size_t)b * SS + s) * DD + h * DKK + db * 16 + l15] = ctxacc[db][r];
      if (l15 == 0) lp[(size_t)bh * SS + s] = lsum[r];
    }
  }
}

// ---------------- combine: ctx_bf16 = (P0+P1) / (L0+L1)
__global__ __launch_bounds__(256) void combine_kernel(
    const float* __restrict__ ctxP0, const float* __restrict__ ctxP1,
    const float* __restrict__ Lp0, const float* __restrict__ Lp1,
    unsigned short* __restrict__ ctx) {
  int idx = blockIdx.x * 256 + threadIdx.x;   // 1048576 threads
  int g = idx * 4;
  int c = g & 1023, s = (g >> 10) & 2047, b = g >> 21;
  int h = c >> 6;
  size_t loff = (size_t)(b * HH + h) * SS + s;
  float linv = 1.0f / (Lp0[loff] + Lp1[loff]);
  float4 p0 = *(const float4*)(ctxP0 + g);
  float4 p1 = *(const float4*)(ctxP1 + g);
  ushort4 o;
  o.x = f2b((p0.x + p1.x) * linv);
  o.y = f2b((p0.y + p1.y) * linv);
  o.z = f2b((p0.z + p1.z) * linv);
  o.w = f2b((p0.w + p1.w) * linv);
  *(ushort4*)(ctx + g) = o;
}

// ---------------- output GEMM: out = ctx @ WoT^T + bias (gload_lds staging)
__global__ __launch_bounds__(256, 2) void gemm_out_kernel(
    const unsigned short* __restrict__ A, const unsigned short* __restrict__ Bt,
    const float* __restrict__ bias, float* __restrict__ out) {
  constexpr int K = 1024;
  __shared__ __attribute__((aligned(16))) unsigned short As[128][32];
  __shared__ __attribute__((aligned(16))) unsigned short Bs[128][32];
  const int tid = threadIdx.x;
  const int m0 = blockIdx.x * 128;
  const int n0 = blockIdx.y * 128;
  const int lane = tid & 63, wid = tid >> 6;
  const int l15 = lane & 15, quad = lane >> 4;
  const int wm = (wid & 1) * 64, wn = (wid >> 1) * 64;
  const int r4 = lane >> 2, c8 = (lane & 3) * 8;
  f32x4 acc[4][4] = {};
  const unsigned short* pa0 = A + (size_t)(m0 + wid * 16 + r4) * K + c8;
  const unsigned short* pa1 = pa0 + (size_t)64 * K;
  const unsigned short* pb0 = Bt + (size_t)(n0 + wid * 16 + r4) * K + c8;
  const unsigned short* pb1 = pb0 + (size_t)64 * K;
  unsigned short* la0 = &As[wid * 16][0];
  unsigned short* la1 = &As[64 + wid * 16][0];
  unsigned short* lb0 = &Bs[wid * 16][0];
  unsigned short* lb1 = &Bs[64 + wid * 16][0];
  for (int k0 = 0; k0 < K; k0 += 32) {
    __syncthreads();
    gload16(pa0, la0);  gload16(pa1, la1);
    gload16(pb0, lb0);  gload16(pb1, lb1);
    pa0 += 32; pa1 += 32; pb0 += 32; pb1 += 32;
    __syncthreads();
    short8x af[4], bfr[4];
#pragma unroll
    for (int i = 0; i < 4; i++) af[i]  = *(const short8x*)&As[wm + i * 16 + l15][quad * 8];
#pragma unroll
    for (int i = 0; i < 4; i++) bfr[i] = *(const short8x*)&Bs[wn + i * 16 + l15][quad * 8];
#pragma unroll
    for (int mi = 0; mi < 4; mi++)
#pragma unroll
      for (int ni = 0; ni < 4; ni++)
        acc[mi][ni] = mfma16(af[mi], bfr[ni], acc[mi][ni]);
  }
#pragma unroll
  for (int mi = 0; mi < 4; mi++)
#pragma unroll
    for (int ni = 0; ni < 4; ni++) {
      int gn = n0 + wn + ni * 16 + l15;
      float bv = bias[gn];
#pragma unroll
      for (int r = 0; r < 4; r++) {
        int gm = m0 + wm + mi * 16 + quad * 4 + r;
        out[(size_t)gm * 1024 + gn] = acc[mi][ni][r] + bv;
      }
    }
}

// ---------------- probs_mean over COMPACTED keys; out2 pre-zeroed, valid columns
// scattered via idx.
__global__ __launch_bounds__(256, 4) void probsmean_kernel(
    const unsigned short* __restrict__ Qr, const unsigned short* __restrict__ Qi,
    const unsigned short* __restrict__ Kr, const unsigned short* __restrict__ Ki,
    const int* __restrict__ cnt, const unsigned short* __restrict__ idxT,
    const float* __restrict__ Lp0, const float* __restrict__ Lp1,
    float* __restrict__ out2) {
  const int tid = threadIdx.x, lane = tid & 63, wid = tid >> 6;
  const int l15 = lane & 15, quad = lane >> 4;
  const int qt = blockIdx.x * 64;
  const int b = blockIdx.z;
  const int c0 = cnt[b * 2], c1 = cnt[b * 2 + 1];
  const int t0n = (c0 + 63) >> 6;
  const int t1n = (c1 + 63) >> 6;
  const int t = blockIdx.y;
  int half, jl0, cnth;
  if (t < t0n)            { half = 0; jl0 = t * 64;         cnth = c0; }
  else if (t < t0n + t1n) { half = 1; jl0 = (t - t0n) * 64; cnth = c1; }
  else return;  // out2 pre-zeroed
  const int qrow0 = qt + wid * 16;
  const int qrb = (qt >> 4) + wid;
  const int ktb = half * 64 + (jl0 >> 4);
  int korig[4]; bool vld[4];
#pragma unroll
  for (int nb = 0; nb < 4; nb++) {
    int j = jl0 + nb * 16 + l15;
    vld[nb] = j < cnth;
    korig[nb] = idxT[(b * 2 + half) * 1024 + j];
  }
  float psum[4][4] = {};  // [nb][r]
  for (int h = 0; h < HH; h++) {
    const int bh = b * HH + h;
    const int qoff = (bh * 128 + qrb) * 1024 + lane * 8;
    short8x fqr0 = *(const short8x*)(Qr + qoff);
    short8x fqr1 = *(const short8x*)(Qr + qoff + 512);
    short8x fqi0 = *(const short8x*)(Qi + qoff);
    short8x fqi1 = *(const short8x*)(Qi + qoff + 512);
    const float4 lv0 = *(const float4*)(Lp0 + (size_t)bh * SS + qrow0 + quad * 4);
    const float4 lv1 = *(const float4*)(Lp1 + (size_t)bh * SS + qrow0 + quad * 4);
    float li[4];
    li[0] = 1.0f / (lv0.x + lv1.x); li[1] = 1.0f / (lv0.y + lv1.y);
    li[2] = 1.0f / (lv0.z + lv1.z); li[3] = 1.0f / (lv0.w + lv1.w);
#pragma unroll
    for (int nb = 0; nb < 4; nb++) {
      const int koff = (bh * 128 + ktb + nb) * 1024 + lane * 8;
      short8x bkr0 = *(const short8x*)(Kr + koff);
      short8x bkr1 = *(const short8x*)(Kr + koff + 512);
      short8x bki0 = *(const short8x*)(Ki + koff);
      short8x bki1 = *(const short8x*)(Ki + koff + 512);
      f32x4 sr = {0.f, 0.f, 0.f, 0.f};
      sr = mfma16(fqr0, bkr0, sr);  sr = mfma16(fqr1, bkr1, sr);
      sr = mfma16(fqi0, bki0, sr);  sr = mfma16(fqi1, bki1, sr);
      f32x4 sa = {0.f, 0.f, 0.f, 0.f};  // Qi.Kr
      sa = mfma16(fqi0, bkr0, sa);  sa = mfma16(fqi1, bkr1, sa);
      f32x4 sb = {0.f, 0.f, 0.f, 0.f};  // Qr.Ki
      sb = mfma16(fqr0, bki0, sb);  sb = mfma16(fqr1, bki1, sb);
#pragma unroll
      for (int r = 0; r < 4; r++) {
        float a = sr[r];
        float d = sa[r] - sb[r];
        float r2 = __builtin_fmaf(a, a, d * d);
        float inv = __builtin_amdgcn_rsqf(r2);
        float arg = inv * __builtin_fmaf(C1F, r2, C2F * a);
        float p = vld[nb] ? __builtin_amdgcn_exp2f(arg) * li[r] : 0.0f;  // select
        psum[nb][r] += p;
      }
    }
  }
#pragma unroll
  for (int nb = 0; nb < 4; nb++)
#pragma unroll
    for (int r = 0; r < 4; r++) {
      if (vld[nb]) {
        int qrow = qrow0 + quad * 4 + r;
        out2[((size_t)b * SS + qrow) * SS + korig[nb]] = psum[nb][r] * 0.0625f;
      }
    }
}

extern "C" void kernel_launch(void* const* d_in, const int* in_sizes, int n_in,
                              void* d_out, int out_size, void* d_ws, size_t ws_size,
                              hipStream_t stream) {
  const float* z_real = (const float*)d_in[0];
  const float* z_imag = (const float*)d_in[1];
  const float* Wq_r = (const float*)d_in[2];
  const float* Wq_i = (const float*)d_in[3];
  const float* Wk_r = (const float*)d_in[4];
  const float* Wk_i = (const float*)d_in[5];
  const float* Wv   = (const float*)d_in[6];
  const float* Wo_w = (const float*)d_in[7];
  const float* Wo_b = (const float*)d_in[8];
  const int*   mask = (const int*)d_in[9];
  char* ws = (char*)d_ws;

  // ws layout (bytes). ctxP0/ctxP1 ALIAS WcatT/Xcat: dead after gemm_proj (stream-serial).
  constexpr size_t QKV_BYTES = 8388608;  // B*H*S*DK*2
  unsigned short* Qr   = (unsigned short*)(ws + 0);
  unsigned short* Qi   = (unsigned short*)(ws + QKV_BYTES);
  unsigned short* Kr   = (unsigned short*)(ws + 2 * QKV_BYTES);
  unsigned short* Ki   = (unsigned short*)(ws + 3 * QKV_BYTES);
  unsigned short* VT   = (unsigned short*)(ws + 4 * QKV_BYTES);
  unsigned short* ctx  = (unsigned short*)(ws + 5 * QKV_BYTES);              // 8 MB bf16
  unsigned short* WcatT= (unsigned short*)(ws + 50331648);                   // 20 MB
  unsigned short* WoT  = (unsigned short*)(ws + 71303168);                   // 2 MB
  unsigned short* Xcat = (unsigned short*)(ws + 73400320);                   // 16 MB
  float* ctxP0 = (float*)(ws + 50331648);                                    // aliases WcatT (16 MB)
  float* ctxP1 = (float*)(ws + 73400320);                                    // aliases Xcat (16 MB)
  float* Lp0   = (float*)(ws + 90177536);                                    // 256 KB
  float* Lp1   = (float*)(ws + 90439680);                                    // 256 KB

  float* out  = (float*)d_out;
  float* out2 = out + (size_t)BB * SS * DD;

  // Compaction tables live in d_out scratch (`out` region): dead until gemm_out,
  // which runs last. probsmean (reads idx) ordered before combine/gemm_out.
  unsigned short* posT = (unsigned short*)out;       // [2][2048] = 8 KB
  unsigned short* idxT = posT + 4096;                // [2][2][1024] = 8 KB
  int* cntT = (int*)(idxT + 4096);                   // [2][2]

  pack_w_kernel<<<dim3(2816), dim3(256), 0, stream>>>(Wq_r, Wq_i, Wk_r, Wk_i, Wv, Wo_w, WcatT, WoT);
  pack_x_kernel<<<dim3(32768), dim3(256), 0, stream>>>(z_real, z_imag, Xcat);
  zero_kernel<<<dim3(2048), dim3(256), 0, stream>>>((float4*)VT);            // 8 MB: V pad rows = 0
  zero_kernel<<<dim3(8192), dim3(256), 0, stream>>>((float4*)out2);          // 32 MB: masked cols = 0
  mask_scan_kernel<<<dim3(4), dim3(256), 0, stream>>>(mask, posT, idxT, cntT);
  gemm_proj_kernel<<<dim3(32, 40), dim3(256), 0, stream>>>(Xcat, WcatT, posT, Qr, Qi, Kr, Ki, VT);
  flash_kernel<<<dim3(16, 16, 4), dim3(256), 0, stream>>>(Qr, Qi, Kr, Ki, VT, cntT, ctxP0, ctxP1, Lp0, Lp1);
  probsmean_kernel<<<dim3(32, 32, 2), dim3(256), 0, stream>>>(Qr, Qi, Kr, Ki, cntT, idxT, Lp0, Lp1, out2);
  combine_kernel<<<dim3(4096), dim3(256), 0, stream>>>(ctxP0, ctxP1, Lp0, Lp1, ctx);
  gemm_out_kernel<<<dim3(32, 8), dim3(256), 0, stream>>>(ctx, WoT, Wo_b, out);
}

// Round 9
// 404.023 us; speedup vs baseline: 1.8095x; 1.0501x over previous
//
#include <hip/hip_runtime.h>
#include <cstdint>
#include <cstddef>

#define BB 2
#define SS 2048
#define DD 1024
#define HH 16
#define DKK 64

typedef __attribute__((ext_vector_type(8))) short short8x;
typedef __attribute__((ext_vector_type(4))) float f32x4;

__device__ __forceinline__ unsigned short f2b(float f) {
  union { float f; unsigned u; } v; v.f = f;
  unsigned r = (v.u + 0x7fffu + ((v.u >> 16) & 1u)) >> 16;  // RNE
  return (unsigned short)r;
}

// hot-path bf16: round-half-up, 2 VALU (vs ~5 for RNE). Used only for Ps probabilities.
__device__ __forceinline__ unsigned short f2b_fast(float f) {
  union { float f; unsigned u; } v; v.f = f;
  return (unsigned short)((v.u + 0x8000u) >> 16);
}

__device__ __forceinline__ f32x4 mfma16(short8x a, short8x b, f32x4 c) {
  return __builtin_amdgcn_mfma_f32_16x16x32_bf16(a, b, c, 0, 0, 0);
}

// async global->LDS, 16B per lane. LDS dest = wave-uniform base + lane*16.
__device__ __forceinline__ void gload16(const unsigned short* g, unsigned short* l) {
  __builtin_amdgcn_global_load_lds(
      (__attribute__((address_space(1))) unsigned int*)g,
      (__attribute__((address_space(3))) unsigned int*)l,
      16, 0, 0);
}

// Fragment-major Q/K layout (R5). R6: fixed m=0. R7: K-split + combine. R8: raw-HW
// transcendentals. R9 FAILED (flash spill at 8/EU). R10: XCD swizzle on flash.
// R11-R14: gemm_proj (256,5)+gload_lds+V-K1024 (114.5us); K-compaction (R12).
// R15: pack_w tiled transpose; flash 128-row Q-tiles (424us total).
// R16 (this round):
//  (a) flash kt-OUTER / subtile-INNER: R15's two 64-row subtiles each re-loaded the
//      same K and V frags (K/V depend on kt only). Flash is L2-load-bound (MFMA
//      floor ~1us, VALU ~15us, loads ~45us). Hoisting the subtile loop inside kt
//      halves K+V traffic. Costs: 2x Q frags/ctxacc/lsum (~110 VGPR) + Ps[2] (18.4KB
//      LDS). Grid 1024 = 4/CU grid-limited -> (256,4) raises VGPR cap to 128 (a
//      (256,6) bound would cap at 85 = forced spill for zero occupancy gain).
//  (b) gemm_out 64x128 tiles: grid 256 = 1 block/CU = 4 waves/CU (worst-case
//      latency hiding). (64,8) = 512 = 2/CU single round; WoT (2MB) is L2-resident
//      so doubled B re-reads are free.
#define C1F 0.0225421076f  // (1/64)*log2e
#define C2F 0.0541010849f  // (0.3/8)*log2e

// ---------------- pack weights: tiled transpose, coalesced both sides
__global__ __launch_bounds__(256) void pack_w_kernel(
    const float* __restrict__ Wq_r, const float* __restrict__ Wq_i,
    const float* __restrict__ Wk_r, const float* __restrict__ Wk_i,
    const float* __restrict__ Wv, const float* __restrict__ Wo,
    unsigned short* __restrict__ WcatT, unsigned short* __restrict__ WoT) {
  __shared__ float tile[64][65];
  const int tid = threadIdx.x;
  int bid = blockIdx.x;
  if (bid < 2560) {
    const int kt = bid & 31, nt = bid >> 5;
    const int k0 = kt * 64, n0 = nt * 64;
    const int q = n0 >> 10, j0 = n0 & 1023;
    const float* src;
    float sgn = 1.0f;
    bool zero = false;
    if (k0 < 1024) {
      src = (q == 0) ? Wq_r : (q == 1) ? Wq_i : (q == 2) ? Wk_r : (q == 3) ? Wk_i : Wv;
    } else {
      if (q == 0)      { src = Wq_i; sgn = -1.0f; }
      else if (q == 1) { src = Wq_r; }
      else if (q == 2) { src = Wk_i; sgn = -1.0f; }
      else if (q == 3) { src = Wk_r; }
      else             { src = Wv; zero = true; }
    }
    const int ks0 = k0 & 1023;
    if (!zero) {
#pragma unroll
      for (int i = 0; i < 16; i++) {
        int idx = i * 256 + tid;
        int r = idx >> 6, c = idx & 63;
        tile[r][c] = src[(size_t)(ks0 + r) * 1024 + j0 + c];
      }
      __syncthreads();
#pragma unroll
      for (int i = 0; i < 16; i++) {
        int idx = i * 256 + tid;
        int nr = idx >> 6, kc = idx & 63;
        WcatT[(size_t)(n0 + nr) * 2048 + k0 + kc] = f2b(sgn * tile[kc][nr]);
      }
    } else {
#pragma unroll
      for (int i = 0; i < 16; i++) {
        int idx = i * 256 + tid;
        int nr = idx >> 6, kc = idx & 63;
        WcatT[(size_t)(n0 + nr) * 2048 + k0 + kc] = 0;
      }
    }
  } else {
    bid -= 2560;
    const int kt = bid & 15, nt = bid >> 4;
    const int k0 = kt * 64, n0 = nt * 64;
#pragma unroll
    for (int i = 0; i < 16; i++) {
      int idx = i * 256 + tid;
      int r = idx >> 6, c = idx & 63;
      tile[r][c] = Wo[(size_t)(k0 + r) * 1024 + n0 + c];
    }
    __syncthreads();
#pragma unroll
    for (int i = 0; i < 16; i++) {
      int idx = i * 256 + tid;
      int nr = idx >> 6, kc = idx & 63;
      WoT[(size_t)(n0 + nr) * 1024 + k0 + kc] = f2b(tile[kc][nr]);
    }
  }
}

// ---------------- pack X: Xcat[4096][2048] = [z_real | z_imag] (bf16)
__global__ void pack_x_kernel(const float* __restrict__ zr, const float* __restrict__ zi,
                              unsigned short* __restrict__ X) {
  int gid = blockIdx.x * 256 + threadIdx.x;  // 4096*2048
  int k = gid & 2047, m = gid >> 11;
  float v = (k < 1024) ? zr[m * 1024 + k] : zi[m * 1024 + (k - 1024)];
  X[gid] = f2b(v);
}

// ---------------- generic zero (float4 granularity)
__global__ void zero_kernel(float4* __restrict__ p) {
  p[(size_t)blockIdx.x * 256 + threadIdx.x] = float4{0.f, 0.f, 0.f, 0.f};
}

// ---------------- mask scan: per (b,half) compaction tables
__global__ void mask_scan_kernel(const int* __restrict__ mask,
                                 unsigned short* __restrict__ pos,
                                 unsigned short* __restrict__ idx,
                                 int* __restrict__ cnt) {
  const int b = blockIdx.x >> 1, half = blockIdx.x & 1;
  __shared__ int sums[256];
  const int t = threadIdx.x;
  const int s0 = half * 1024 + t * 4;
  int m[4];
  int loc = 0;
#pragma unroll
  for (int i = 0; i < 4; i++) { m[i] = mask[b * 2048 + s0 + i]; loc += m[i]; }
  sums[t] = loc;
  __syncthreads();
  for (int off = 1; off < 256; off <<= 1) {
    int v = (t >= off) ? sums[t - off] : 0;
    __syncthreads();
    sums[t] += v;
    __syncthreads();
  }
  int excl = sums[t] - loc;
#pragma unroll
  for (int i = 0; i < 4; i++) {
    int sg = s0 + i;
    if (m[i]) {
      pos[b * 2048 + sg] = (unsigned short)excl;
      idx[(b * 2 + half) * 1024 + excl] = (unsigned short)sg;
      excl++;
    } else {
      pos[b * 2048 + sg] = 0xFFFFu;
    }
  }
  if (t == 255) cnt[b * 2 + half] = sums[255];
}

// ---------------- projection GEMM: gload_lds staging; epilogue writes fragment-major
// Q (uncompacted) and COMPACTED K / V^T via pos lookup.
__global__ __launch_bounds__(256, 5) void gemm_proj_kernel(
    const unsigned short* __restrict__ A, const unsigned short* __restrict__ Bt,
    const unsigned short* __restrict__ pos,
    unsigned short* __restrict__ Qr, unsigned short* __restrict__ Qi,
    unsigned short* __restrict__ Kr, unsigned short* __restrict__ Ki,
    unsigned short* __restrict__ VT) {
  constexpr int K = 2048;
  __shared__ __attribute__((aligned(16))) unsigned short As[128][32];
  __shared__ __attribute__((aligned(16))) unsigned short Bs[128][32];
  const int tid = threadIdx.x;
  const int m0 = blockIdx.x * 128;
  const int n0 = blockIdx.y * 128;
  const int lane = tid & 63, wid = tid >> 6;
  const int l15 = lane & 15, quad = lane >> 4;
  const int wm = (wid & 1) * 64, wn = (wid >> 1) * 64;
  const int r4 = lane >> 2, c8 = (lane & 3) * 8;
  // V columns (n >= 4096) have zero weights for k >= 1024: skip exactly.
  const int kmax = (n0 >= 4096) ? 1024 : K;
  f32x4 acc[4][4] = {};
  const unsigned short* pa0 = A + (size_t)(m0 + wid * 16 + r4) * K + c8;
  const unsigned short* pa1 = pa0 + (size_t)64 * K;
  const unsigned short* pb0 = Bt + (size_t)(n0 + wid * 16 + r4) * K + c8;
  const unsigned short* pb1 = pb0 + (size_t)64 * K;
  unsigned short* la0 = &As[wid * 16][0];
  unsigned short* la1 = &As[64 + wid * 16][0];
  unsigned short* lb0 = &Bs[wid * 16][0];
  unsigned short* lb1 = &Bs[64 + wid * 16][0];
  for (int k0 = 0; k0 < kmax; k0 += 32) {
    __syncthreads();
    gload16(pa0, la0);  gload16(pa1, la1);
    gload16(pb0, lb0);  gload16(pb1, lb1);
    pa0 += 32; pa1 += 32; pb0 += 32; pb1 += 32;
    __syncthreads();
    short8x af[4], bfr[4];
#pragma unroll
    for (int i = 0; i < 4; i++) af[i]  = *(const short8x*)&As[wm + i * 16 + l15][quad * 8];
#pragma unroll
    for (int i = 0; i < 4; i++) bfr[i] = *(const short8x*)&Bs[wn + i * 16 + l15][quad * 8];
#pragma unroll
    for (int mi = 0; mi < 4; mi++)
#pragma unroll
      for (int ni = 0; ni < 4; ni++)
        acc[mi][ni] = mfma16(af[mi], bfr[ni], acc[mi][ni]);
  }
#pragma unroll
  for (int mi = 0; mi < 4; mi++) {
#pragma unroll
    for (int ni = 0; ni < 4; ni++) {
      int gn = n0 + wn + ni * 16 + l15;
      if (gn < 2048) {
        // Q: uncompacted
        int which = gn >> 10, j = gn & 1023, h = j >> 6, dk = j & 63;
        int ks = dk >> 5, q = (dk >> 3) & 3, e = dk & 7;
        unsigned short* dst = which ? Qi : Qr;
#pragma unroll
        for (int r = 0; r < 4; r++) {
          int gm = m0 + wm + mi * 16 + quad * 4 + r;
          int b = gm >> 11, s = gm & 2047;
          int bh = b * HH + h, rb = s >> 4, l = s & 15;
          dst[(size_t)(((bh * 128 + rb) * 2 + ks) * 512 + (q * 16 + l) * 8 + e)] = f2b(acc[mi][ni][r]);
        }
      } else if (gn < 4096) {
        // K: compacted per (b, half)
        int which = gn >> 10, j = gn & 1023, h = j >> 6, dk = j & 63;
        int ks = dk >> 5, q = (dk >> 3) & 3, e = dk & 7;
        unsigned short* dst = (which == 2) ? Kr : Ki;
#pragma unroll
        for (int r = 0; r < 4; r++) {
          int gm = m0 + wm + mi * 16 + quad * 4 + r;
          int b = gm >> 11, s = gm & 2047;
          unsigned short pp = pos[b * 2048 + s];
          if (pp != 0xFFFFu) {
            int hf = s >> 10;
            int bh = b * HH + h, rb = hf * 64 + (pp >> 4), l = pp & 15;
            dst[(size_t)(((bh * 128 + rb) * 2 + ks) * 512 + (q * 16 + l) * 8 + e)] = f2b(acc[mi][ni][r]);
          }
        }
      } else {
        // V^T: compacted per (b, half)
        int j = gn - 4096, h = j >> 6, dk = j & 63;
        int rbv = dk >> 4, lv = dk & 15;
#pragma unroll
        for (int r = 0; r < 4; r++) {
          int gm = m0 + wm + mi * 16 + quad * 4 + r;
          int b = gm >> 11, s = gm & 2047;
          unsigned short pp = pos[b * 2048 + s];
          if (pp != 0xFFFFu) {
            int hf = s >> 10;
            int bh = b * HH + h, kc = hf * 32 + (pp >> 5), qv = (pp >> 3) & 3, ev = pp & 7;
            VT[(size_t)(((bh * 4 + rbv) * 64 + kc) * 512 + (qv * 16 + lv) * 8 + ev)] = f2b(acc[mi][ni][r]);
          }
        }
      }
    }
  }
}

// ---------------- flash attention over COMPACTED keys, kt-outer/subtile-inner (R16)
// K frags loaded once per (kt,nb) feed BOTH 64-row subtiles; V loaded once per
// (kt,ks,db) feeds both PV MFMAs -> K/V L2 traffic halved vs R15. Ps doubled
// ([2] subtile buffers, 18.4KB). Grid 1024 = 4/CU (grid-limited) -> (256,4)
// raises VGPR cap to 128 for the ~110 needed; residency unchanged.
__global__ __launch_bounds__(256, 4) void flash_kernel(
    const unsigned short* __restrict__ Qr, const unsigned short* __restrict__ Qi,
    const unsigned short* __restrict__ Kr, const unsigned short* __restrict__ Ki,
    const unsigned short* __restrict__ VT, const int* __restrict__ cnt,
    float* __restrict__ ctxP0, float* __restrict__ ctxP1,
    float* __restrict__ Lp0, float* __restrict__ Lp1) {
  __shared__ __attribute__((aligned(16))) unsigned short Ps[2][4][16][72];
  const int tid = threadIdx.x;
  const int lane = tid & 63, wid = tid >> 6;
  const int l15 = lane & 15, quad = lane >> 4;
  // XCD swizzle (bijective, 1024 % 8 == 0): each XCD gets 8 heads of one z.
  int lin = blockIdx.x + 16 * (blockIdx.y + 16 * blockIdx.z);
  lin = ((lin & 7) << 7) | (lin >> 3);
  const int qt2 = (lin & 15) * 128;
  const int h = (lin >> 4) & 15;
  const int z = lin >> 8;
  const int b = z >> 1, half = z & 1;
  const int bh = b * HH + h;
  float* __restrict__ cp = half ? ctxP1 : ctxP0;
  float* __restrict__ lp = half ? Lp1 : Lp0;
  const int cntbh = cnt[b * 2 + half];
  const int kend = ((cntbh + 63) >> 6) << 6;
  const int kt0 = half * 1024;

  // Q fragments for both 64-row subtiles (static-indexed arrays; unrolled use only)
  short8x fqr0[2], fqr1[2], fqi0[2], fqi1[2];
#pragma unroll
  for (int s2 = 0; s2 < 2; s2++) {
    const int rb = ((qt2 + s2 * 64) >> 4) + wid;
    const int qb = (bh * 128 + rb) * 1024 + lane * 8;
    fqr0[s2] = *(const short8x*)(Qr + qb);
    fqr1[s2] = *(const short8x*)(Qr + qb + 512);
    fqi0[s2] = *(const short8x*)(Qi + qb);
    fqi1[s2] = *(const short8x*)(Qi + qb + 512);
  }
  f32x4 ctxacc[2][4] = {};
  float lsum[2][4] = {{0.f, 0.f, 0.f, 0.f}, {0.f, 0.f, 0.f, 0.f}};

  for (int ktl = 0; ktl < kend; ktl += 64) {
    const int kt = kt0 + ktl;
#pragma unroll
    for (int nb = 0; nb < 4; nb++) {
      const int j = ktl + nb * 16 + l15;           // compacted-local index
      const int koff = (bh * 128 + (kt >> 4) + nb) * 1024 + lane * 8;
      short8x bkr0 = *(const short8x*)(Kr + koff);
      short8x bkr1 = *(const short8x*)(Kr + koff + 512);
      short8x bki0 = *(const short8x*)(Ki + koff);
      short8x bki1 = *(const short8x*)(Ki + koff + 512);
#pragma unroll
      for (int s2 = 0; s2 < 2; s2++) {
        f32x4 sr = {0.f, 0.f, 0.f, 0.f};
        sr = mfma16(fqr0[s2], bkr0, sr);  sr = mfma16(fqr1[s2], bkr1, sr);
        sr = mfma16(fqi0[s2], bki0, sr);  sr = mfma16(fqi1[s2], bki1, sr);
        f32x4 sa = {0.f, 0.f, 0.f, 0.f};
        sa = mfma16(fqi0[s2], bkr0, sa);  sa = mfma16(fqi1[s2], bkr1, sa);
        f32x4 sb = {0.f, 0.f, 0.f, 0.f};
        sb = mfma16(fqr0[s2], bki0, sb);  sb = mfma16(fqr1[s2], bki1, sb);
#pragma unroll
        for (int r = 0; r < 4; r++) {
          float a = sr[r];
          float d = sa[r] - sb[r];
          float r2 = __builtin_fmaf(a, a, d * d);
          float inv = __builtin_amdgcn_rsqf(r2);
          float arg = inv * __builtin_fmaf(C1F, r2, C2F * a);
          float p = (j < cntbh) ? __builtin_amdgcn_exp2f(arg) : 0.0f;  // select, not mul
          lsum[s2][r] += p;
          Ps[s2][wid][quad * 4 + r][nb * 16 + l15] = f2b_fast(p);
        }
      }
    }
    // PV: V loaded once, feeds both subtiles. V pad rows pre-zeroed.
#pragma unroll
    for (int ks = 0; ks < 2; ks++)
#pragma unroll
      for (int db = 0; db < 4; db++) {
        int voff = ((bh * 4 + db) * 64 + (kt >> 5) + ks) * 512 + lane * 8;
        short8x bv = *(const short8x*)(VT + voff);
        short8x ap0 = *(const short8x*)&Ps[0][wid][l15][ks * 32 + quad * 8];
        short8x ap1 = *(const short8x*)&Ps[1][wid][l15][ks * 32 + quad * 8];
        ctxacc[0][db] = mfma16(ap0, bv, ctxacc[0][db]);
        ctxacc[1][db] = mfma16(ap1, bv, ctxacc[1][db]);
      }
  }
#pragma unroll
  for (int s2 = 0; s2 < 2; s2++) {
#pragma unroll
    for (int r = 0; r < 4; r++) {
#pragma unroll
      for (int off = 1; off < 16; off <<= 1) lsum[s2][r] += __shfl_xor(lsum[s2][r], off, 64);
    }
#pragma unroll
    for (int r = 0; r < 4; r++) {
      int s = qt2 + s2 * 64 + wid * 16 + quad * 4 + r;
#pragma unroll
      for (int db = 0; db < 4; db++)
        cp[((size_t)b * SS + s) * DD + h * DKK + db * 16 + l15] = ctxacc[s2][db][r];
      if (l15 == 0) lp[(size_t)bh * SS + s] = lsum[s2][r];
    }
  }
}

// ---------------- combine: ctx_bf16 = (P0+P1) / (L0+L1)
__global__ __launch_bounds__(256) void combine_kernel(
    const float* __restrict__ ctxP0, const float* __restrict__ ctxP1,
    const float* __restrict__ Lp0, const float* __restrict__ Lp1,
    unsigned short* __restrict__ ctx) {
  int idx = blockIdx.x * 256 + threadIdx.x;   // 1048576 threads
  int g = idx * 4;
  int c = g & 1023, s = (g >> 10) & 2047, b = g >> 21;
  int h = c >> 6;
  size_t loff = (size_t)(b * HH + h) * SS + s;
  float linv = 1.0f / (Lp0[loff] + Lp1[loff]);
  float4 p0 = *(const float4*)(ctxP0 + g);
  float4 p1 = *(const float4*)(ctxP1 + g);
  ushort4 o;
  o.x = f2b((p0.x + p1.x) * linv);
  o.y = f2b((p0.y + p1.y) * linv);
  o.z = f2b((p0.z + p1.z) * linv);
  o.w = f2b((p0.w + p1.w) * linv);
  *(ushort4*)(ctx + g) = o;
}

// ---------------- output GEMM: out = ctx @ WoT^T + bias
// R16: 64x128 tiles, grid (64,8) = 512 blocks = 2/CU (was 256 = 1/CU, 4 waves/CU).
__global__ __launch_bounds__(256, 2) void gemm_out_kernel(
    const unsigned short* __restrict__ A, const unsigned short* __restrict__ Bt,
    const float* __restrict__ bias, float* __restrict__ out) {
  constexpr int K = 1024;
  __shared__ __attribute__((aligned(16))) unsigned short As[64][32];
  __shared__ __attribute__((aligned(16))) unsigned short Bs[128][32];
  const int tid = threadIdx.x;
  const int m0 = blockIdx.x * 64;
  const int n0 = blockIdx.y * 128;
  const int lane = tid & 63, wid = tid >> 6;
  const int l15 = lane & 15, quad = lane >> 4;
  const int wm = (wid & 1) * 32, wn = (wid >> 1) * 64;
  const int r4 = lane >> 2, c8 = (lane & 3) * 8;
  f32x4 acc[2][4] = {};
  const unsigned short* pa0 = A + (size_t)(m0 + wid * 16 + r4) * K + c8;
  const unsigned short* pb0 = Bt + (size_t)(n0 + wid * 16 + r4) * K + c8;
  const unsigned short* pb1 = pb0 + (size_t)64 * K;
  unsigned short* la0 = &As[wid * 16][0];
  unsigned short* lb0 = &Bs[wid * 16][0];
  unsigned short* lb1 = &Bs[64 + wid * 16][0];
  for (int k0 = 0; k0 < K; k0 += 32) {
    __syncthreads();
    gload16(pa0, la0);
    gload16(pb0, lb0);  gload16(pb1, lb1);
    pa0 += 32; pb0 += 32; pb1 += 32;
    __syncthreads();
    short8x af[2], bfr[4];
#pragma unroll
    for (int i = 0; i < 2; i++) af[i]  = *(const short8x*)&As[wm + i * 16 + l15][quad * 8];
#pragma unroll
    for (int i = 0; i < 4; i++) bfr[i] = *(const short8x*)&Bs[wn + i * 16 + l15][quad * 8];
#pragma unroll
    for (int mi = 0; mi < 2; mi++)
#pragma unroll
      for (int ni = 0; ni < 4; ni++)
        acc[mi][ni] = mfma16(af[mi], bfr[ni], acc[mi][ni]);
  }
#pragma unroll
  for (int mi = 0; mi < 2; mi++)
#pragma unroll
    for (int ni = 0; ni < 4; ni++) {
      int gn = n0 + wn + ni * 16 + l15;
      float bv = bias[gn];
#pragma unroll
      for (int r = 0; r < 4; r++) {
        int gm = m0 + wm + mi * 16 + quad * 4 + r;
        out[(size_t)gm * 1024 + gn] = acc[mi][ni][r] + bv;
      }
    }
}

// ---------------- probs_mean over COMPACTED keys; out2 pre-zeroed, valid columns
// scattered via idx.
__global__ __launch_bounds__(256, 4) void probsmean_kernel(
    const unsigned short* __restrict__ Qr, const unsigned short* __restrict__ Qi,
    const unsigned short* __restrict__ Kr, const unsigned short* __restrict__ Ki,
    const int* __restrict__ cnt, const unsigned short* __restrict__ idxT,
    const float* __restrict__ Lp0, const float* __restrict__ Lp1,
    float* __restrict__ out2) {
  const int tid = threadIdx.x, lane = tid & 63, wid = tid >> 6;
  const int l15 = lane & 15, quad = lane >> 4;
  const int qt = blockIdx.x * 64;
  const int b = blockIdx.z;
  const int c0 = cnt[b * 2], c1 = cnt[b * 2 + 1];
  const int t0n = (c0 + 63) >> 6;
  const int t1n = (c1 + 63) >> 6;
  const int t = blockIdx.y;
  int half, jl0, cnth;
  if (t < t0n)            { half = 0; jl0 = t * 64;         cnth = c0; }
  else if (t < t0n + t1n) { half = 1; jl0 = (t - t0n) * 64; cnth = c1; }
  else return;  // out2 pre-zeroed
  const int qrow0 = qt + wid * 16;
  const int qrb = (qt >> 4) + wid;
  const int ktb = half * 64 + (jl0 >> 4);
  int korig[4]; bool vld[4];
#pragma unroll
  for (int nb = 0; nb < 4; nb++) {
    int j = jl0 + nb * 16 + l15;
    vld[nb] = j < cnth;
    korig[nb] = idxT[(b * 2 + half) * 1024 + j];
  }
  float psum[4][4] = {};  // [nb][r]
  for (int h = 0; h < HH; h++) {
    const int bh = b * HH + h;
    const int qoff = (bh * 128 + qrb) * 1024 + lane * 8;
    short8x fqr0 = *(const short8x*)(Qr + qoff);
    short8x fqr1 = *(const short8x*)(Qr + qoff + 512);
    short8x fqi0 = *(const short8x*)(Qi + qoff);
    short8x fqi1 = *(const short8x*)(Qi + qoff + 512);
    const float4 lv0 = *(const float4*)(Lp0 + (size_t)bh * SS + qrow0 + quad * 4);
    const float4 lv1 = *(const float4*)(Lp1 + (size_t)bh * SS + qrow0 + quad * 4);
    float li[4];
    li[0] = 1.0f / (lv0.x + lv1.x); li[1] = 1.0f / (lv0.y + lv1.y);
    li[2] = 1.0f / (lv0.z + lv1.z); li[3] = 1.0f / (lv0.w + lv1.w);
#pragma unroll
    for (int nb = 0; nb < 4; nb++) {
      const int koff = (bh * 128 + ktb + nb) * 1024 + lane * 8;
      short8x bkr0 = *(const short8x*)(Kr + koff);
      short8x bkr1 = *(const short8x*)(Kr + koff + 512);
      short8x bki0 = *(const short8x*)(Ki + koff);
      short8x bki1 = *(const short8x*)(Ki + koff + 512);
      f32x4 sr = {0.f, 0.f, 0.f, 0.f};
      sr = mfma16(fqr0, bkr0, sr);  sr = mfma16(fqr1, bkr1, sr);
      sr = mfma16(fqi0, bki0, sr);  sr = mfma16(fqi1, bki1, sr);
      f32x4 sa = {0.f, 0.f, 0.f, 0.f};  // Qi.Kr
      sa = mfma16(fqi0, bkr0, sa);  sa = mfma16(fqi1, bkr1, sa);
      f32x4 sb = {0.f, 0.f, 0.f, 0.f};  // Qr.Ki
      sb = mfma16(fqr0, bki0, sb);  sb = mfma16(fqr1, bki1, sb);
#pragma unroll
      for (int r = 0; r < 4; r++) {
        float a = sr[r];
        float d = sa[r] - sb[r];
        float r2 = __builtin_fmaf(a, a, d * d);
        float inv = __builtin_amdgcn_rsqf(r2);
        float arg = inv * __builtin_fmaf(C1F, r2, C2F * a);
        float p = vld[nb] ? __builtin_amdgcn_exp2f(arg) * li[r] : 0.0f;  // select
        psum[nb][r] += p;
      }
    }
  }
#pragma unroll
  for (int nb = 0; nb < 4; nb++)
#pragma unroll
    for (int r = 0; r < 4; r++) {
      if (vld[nb]) {
        int qrow = qrow0 + quad * 4 + r;
        out2[((size_t)b * SS + qrow) * SS + korig[nb]] = psum[nb][r] * 0.0625f;
      }
    }
}

extern "C" void kernel_launch(void* const* d_in, const int* in_sizes, int n_in,
                              void* d_out, int out_size, void* d_ws, size_t ws_size,
                              hipStream_t stream) {
  const float* z_real = (const float*)d_in[0];
  const float* z_imag = (const float*)d_in[1];
  const float* Wq_r = (const float*)d_in[2];
  const float* Wq_i = (const float*)d_in[3];
  const float* Wk_r = (const float*)d_in[4];
  const float* Wk_i = (const float*)d_in[5];
  const float* Wv   = (const float*)d_in[6];
  const float* Wo_w = (const float*)d_in[7];
  const float* Wo_b = (const float*)d_in[8];
  const int*   mask = (const int*)d_in[9];
  char* ws = (char*)d_ws;

  // ws layout (bytes). ctxP0/ctxP1 ALIAS WcatT/Xcat: dead after gemm_proj (stream-serial).
  constexpr size_t QKV_BYTES = 8388608;  // B*H*S*DK*2
  unsigned short* Qr   = (unsigned short*)(ws + 0);
  unsigned short* Qi   = (unsigned short*)(ws + QKV_BYTES);
  unsigned short* Kr   = (unsigned short*)(ws + 2 * QKV_BYTES);
  unsigned short* Ki   = (unsigned short*)(ws + 3 * QKV_BYTES);
  unsigned short* VT   = (unsigned short*)(ws + 4 * QKV_BYTES);
  unsigned short* ctx  = (unsigned short*)(ws + 5 * QKV_BYTES);              // 8 MB bf16
  unsigned short* WcatT= (unsigned short*)(ws + 50331648);                   // 20 MB
  unsigned short* WoT  = (unsigned short*)(ws + 71303168);                   // 2 MB
  unsigned short* Xcat = (unsigned short*)(ws + 73400320);                   // 16 MB
  float* ctxP0 = (float*)(ws + 50331648);                                    // aliases WcatT (16 MB)
  float* ctxP1 = (float*)(ws + 73400320);                                    // aliases Xcat (16 MB)
  float* Lp0   = (float*)(ws + 90177536);                                    // 256 KB
  float* Lp1   = (float*)(ws + 90439680);                                    // 256 KB

  float* out  = (float*)d_out;
  float* out2 = out + (size_t)BB * SS * DD;

  // Compaction tables live in d_out scratch (`out` region): dead until gemm_out,
  // which runs last. probsmean (reads idx) ordered before combine/gemm_out.
  unsigned short* posT = (unsigned short*)out;       // [2][2048] = 8 KB
  unsigned short* idxT = posT + 4096;                // [2][2][1024] = 8 KB
  int* cntT = (int*)(idxT + 4096);                   // [2][2]

  pack_w_kernel<<<dim3(2816), dim3(256), 0, stream>>>(Wq_r, Wq_i, Wk_r, Wk_i, Wv, Wo_w, WcatT, WoT);
  pack_x_kernel<<<dim3(32768), dim3(256), 0, stream>>>(z_real, z_imag, Xcat);
  zero_kernel<<<dim3(2048), dim3(256), 0, stream>>>((float4*)VT);            // 8 MB: V pad rows = 0
  zero_kernel<<<dim3(8192), dim3(256), 0, stream>>>((float4*)out2);          // 32 MB: masked cols = 0
  mask_scan_kernel<<<dim3(4), dim3(256), 0, stream>>>(mask, posT, idxT, cntT);
  gemm_proj_kernel<<<dim3(32, 40), dim3(256), 0, stream>>>(Xcat, WcatT, posT, Qr, Qi, Kr, Ki, VT);
  flash_kernel<<<dim3(16, 16, 4), dim3(256), 0, stream>>>(Qr, Qi, Kr, Ki, VT, cntT, ctxP0, ctxP1, Lp0, Lp1);
  probsmean_kernel<<<dim3(32, 32, 2), dim3(256), 0, stream>>>(Qr, Qi, Kr, Ki, cntT, idxT, Lp0, Lp1, out2);
  combine_kernel<<<dim3(4096), dim3(256), 0, stream>>>(ctxP0, ctxP1, Lp0, Lp1, ctx);
  gemm_out_kernel<<<dim3(64, 8), dim3(256), 0, stream>>>(ctx, WoT, Wo_b, out);
}

// Round 10
// 397.299 us; speedup vs baseline: 1.8402x; 1.0169x over previous
//
#include <hip/hip_runtime.h>
#include <cstdint>
#include <cstddef>

#define BB 2
#define SS 2048
#define DD 1024
#define HH 16
#define DKK 64

typedef __attribute__((ext_vector_type(8))) short short8x;
typedef __attribute__((ext_vector_type(4))) float f32x4;

__device__ __forceinline__ unsigned short f2b(float f) {
  union { float f; unsigned u; } v; v.f = f;
  unsigned r = (v.u + 0x7fffu + ((v.u >> 16) & 1u)) >> 16;  // RNE
  return (unsigned short)r;
}

// hot-path bf16: round-half-up, 2 VALU (vs ~5 for RNE). Used only for Ps probabilities.
__device__ __forceinline__ unsigned short f2b_fast(float f) {
  union { float f; unsigned u; } v; v.f = f;
  return (unsigned short)((v.u + 0x8000u) >> 16);
}

__device__ __forceinline__ f32x4 mfma16(short8x a, short8x b, f32x4 c) {
  return __builtin_amdgcn_mfma_f32_16x16x32_bf16(a, b, c, 0, 0, 0);
}

// async global->LDS, 16B per lane. LDS dest = wave-uniform base + lane*16 (implicit).
__device__ __forceinline__ void gload16(const unsigned short* g, unsigned short* l) {
  __builtin_amdgcn_global_load_lds(
      (__attribute__((address_space(1))) unsigned int*)g,
      (__attribute__((address_space(3))) unsigned int*)l,
      16, 0, 0);
}

// Fragment-major Q/K layout (R5). R6: fixed m=0. R7: K-split + combine. R8: raw-HW
// transcendentals. R9 FAILED (flash spill at 8/EU). R10: XCD swizzle on flash.
// R11-R14: gemm_proj (256,5)+gload_lds+V-K1024 (114.5us); K-compaction (R12).
// R15: pack_w tiled transpose; flash 128-row Q-tiles. R16: flash kt-outer/subtile-
// inner (K/V traffic halved); gemm_out 64x128 (404us total).
// R17 (this round):
//  (a) flash+probsmean K-LDS-STAGING: K frag addresses depend on (kt,nb) only, NOT
//      wid -> all 4 waves loaded identical 16KB/iter from L2 (flash 512MB, probsmean
//      1.1GB total). Stage 16x1KB frags via gload16 (wave w: frags 4w..4w+3) -> /4.
//      LDS: flash 18.4+16=34.8KB x4 = 139KB < 160 (V stays global); probsmean 16KB.
//  (b) pack_x vectorized (Common-mistake #2): was 1 scalar 2B store/thread; now
//      8 elems/thread (2x float4 in, 2x ushort4 out).
#define C1F 0.0225421076f  // (1/64)*log2e
#define C2F 0.0541010849f  // (0.3/8)*log2e

// ---------------- pack weights: tiled transpose, coalesced both sides
__global__ __launch_bounds__(256) void pack_w_kernel(
    const float* __restrict__ Wq_r, const float* __restrict__ Wq_i,
    const float* __restrict__ Wk_r, const float* __restrict__ Wk_i,
    const float* __restrict__ Wv, const float* __restrict__ Wo,
    unsigned short* __restrict__ WcatT, unsigned short* __restrict__ WoT) {
  __shared__ float tile[64][65];
  const int tid = threadIdx.x;
  int bid = blockIdx.x;
  if (bid < 2560) {
    const int kt = bid & 31, nt = bid >> 5;
    const int k0 = kt * 64, n0 = nt * 64;
    const int q = n0 >> 10, j0 = n0 & 1023;
    const float* src;
    float sgn = 1.0f;
    bool zero = false;
    if (k0 < 1024) {
      src = (q == 0) ? Wq_r : (q == 1) ? Wq_i : (q == 2) ? Wk_r : (q == 3) ? Wk_i : Wv;
    } else {
      if (q == 0)      { src = Wq_i; sgn = -1.0f; }
      else if (q == 1) { src = Wq_r; }
      else if (q == 2) { src = Wk_i; sgn = -1.0f; }
      else if (q == 3) { src = Wk_r; }
      else             { src = Wv; zero = true; }
    }
    const int ks0 = k0 & 1023;
    if (!zero) {
#pragma unroll
      for (int i = 0; i < 16; i++) {
        int idx = i * 256 + tid;
        int r = idx >> 6, c = idx & 63;
        tile[r][c] = src[(size_t)(ks0 + r) * 1024 + j0 + c];
      }
      __syncthreads();
#pragma unroll
      for (int i = 0; i < 16; i++) {
        int idx = i * 256 + tid;
        int nr = idx >> 6, kc = idx & 63;
        WcatT[(size_t)(n0 + nr) * 2048 + k0 + kc] = f2b(sgn * tile[kc][nr]);
      }
    } else {
#pragma unroll
      for (int i = 0; i < 16; i++) {
        int idx = i * 256 + tid;
        int nr = idx >> 6, kc = idx & 63;
        WcatT[(size_t)(n0 + nr) * 2048 + k0 + kc] = 0;
      }
    }
  } else {
    bid -= 2560;
    const int kt = bid & 15, nt = bid >> 4;
    const int k0 = kt * 64, n0 = nt * 64;
#pragma unroll
    for (int i = 0; i < 16; i++) {
      int idx = i * 256 + tid;
      int r = idx >> 6, c = idx & 63;
      tile[r][c] = Wo[(size_t)(k0 + r) * 1024 + n0 + c];
    }
    __syncthreads();
#pragma unroll
    for (int i = 0; i < 16; i++) {
      int idx = i * 256 + tid;
      int nr = idx >> 6, kc = idx & 63;
      WoT[(size_t)(n0 + nr) * 1024 + k0 + kc] = f2b(tile[kc][nr]);
    }
  }
}

// ---------------- pack X (R17: vectorized, 8 elems/thread)
__global__ void pack_x_kernel(const float* __restrict__ zr, const float* __restrict__ zi,
                              unsigned short* __restrict__ X) {
  int gid = blockIdx.x * 256 + threadIdx.x;  // 1048576 threads x 8 elems
  int k8 = (gid & 255) << 3;                 // 0..2047 step 8 (never straddles 1024)
  int m = gid >> 8;
  const float* src = (k8 < 1024) ? (zr + (size_t)m * 1024 + k8)
                                 : (zi + (size_t)m * 1024 + (k8 - 1024));
  float4 a = *(const float4*)src;
  float4 c = *(const float4*)(src + 4);
  ushort4 o0; o0.x = f2b(a.x); o0.y = f2b(a.y); o0.z = f2b(a.z); o0.w = f2b(a.w);
  ushort4 o1; o1.x = f2b(c.x); o1.y = f2b(c.y); o1.z = f2b(c.z); o1.w = f2b(c.w);
  *(ushort4*)(X + (size_t)gid * 8) = o0;
  *(ushort4*)(X + (size_t)gid * 8 + 4) = o1;
}

// ---------------- generic zero (float4 granularity)
__global__ void zero_kernel(float4* __restrict__ p) {
  p[(size_t)blockIdx.x * 256 + threadIdx.x] = float4{0.f, 0.f, 0.f, 0.f};
}

// ---------------- mask scan: per (b,half) compaction tables
__global__ void mask_scan_kernel(const int* __restrict__ mask,
                                 unsigned short* __restrict__ pos,
                                 unsigned short* __restrict__ idx,
                                 int* __restrict__ cnt) {
  const int b = blockIdx.x >> 1, half = blockIdx.x & 1;
  __shared__ int sums[256];
  const int t = threadIdx.x;
  const int s0 = half * 1024 + t * 4;
  int m[4];
  int loc = 0;
#pragma unroll
  for (int i = 0; i < 4; i++) { m[i] = mask[b * 2048 + s0 + i]; loc += m[i]; }
  sums[t] = loc;
  __syncthreads();
  for (int off = 1; off < 256; off <<= 1) {
    int v = (t >= off) ? sums[t - off] : 0;
    __syncthreads();
    sums[t] += v;
    __syncthreads();
  }
  int excl = sums[t] - loc;
#pragma unroll
  for (int i = 0; i < 4; i++) {
    int sg = s0 + i;
    if (m[i]) {
      pos[b * 2048 + sg] = (unsigned short)excl;
      idx[(b * 2 + half) * 1024 + excl] = (unsigned short)sg;
      excl++;
    } else {
      pos[b * 2048 + sg] = 0xFFFFu;
    }
  }
  if (t == 255) cnt[b * 2 + half] = sums[255];
}

// ---------------- projection GEMM: gload_lds staging; epilogue writes fragment-major
// Q (uncompacted) and COMPACTED K / V^T via pos lookup.
__global__ __launch_bounds__(256, 5) void gemm_proj_kernel(
    const unsigned short* __restrict__ A, const unsigned short* __restrict__ Bt,
    const unsigned short* __restrict__ pos,
    unsigned short* __restrict__ Qr, unsigned short* __restrict__ Qi,
    unsigned short* __restrict__ Kr, unsigned short* __restrict__ Ki,
    unsigned short* __restrict__ VT) {
  constexpr int K = 2048;
  __shared__ __attribute__((aligned(16))) unsigned short As[128][32];
  __shared__ __attribute__((aligned(16))) unsigned short Bs[128][32];
  const int tid = threadIdx.x;
  const int m0 = blockIdx.x * 128;
  const int n0 = blockIdx.y * 128;
  const int lane = tid & 63, wid = tid >> 6;
  const int l15 = lane & 15, quad = lane >> 4;
  const int wm = (wid & 1) * 64, wn = (wid >> 1) * 64;
  const int r4 = lane >> 2, c8 = (lane & 3) * 8;
  // V columns (n >= 4096) have zero weights for k >= 1024: skip exactly.
  const int kmax = (n0 >= 4096) ? 1024 : K;
  f32x4 acc[4][4] = {};
  const unsigned short* pa0 = A + (size_t)(m0 + wid * 16 + r4) * K + c8;
  const unsigned short* pa1 = pa0 + (size_t)64 * K;
  const unsigned short* pb0 = Bt + (size_t)(n0 + wid * 16 + r4) * K + c8;
  const unsigned short* pb1 = pb0 + (size_t)64 * K;
  unsigned short* la0 = &As[wid * 16][0];
  unsigned short* la1 = &As[64 + wid * 16][0];
  unsigned short* lb0 = &Bs[wid * 16][0];
  unsigned short* lb1 = &Bs[64 + wid * 16][0];
  for (int k0 = 0; k0 < kmax; k0 += 32) {
    __syncthreads();
    gload16(pa0, la0);  gload16(pa1, la1);
    gload16(pb0, lb0);  gload16(pb1, lb1);
    pa0 += 32; pa1 += 32; pb0 += 32; pb1 += 32;
    __syncthreads();
    short8x af[4], bfr[4];
#pragma unroll
    for (int i = 0; i < 4; i++) af[i]  = *(const short8x*)&As[wm + i * 16 + l15][quad * 8];
#pragma unroll
    for (int i = 0; i < 4; i++) bfr[i] = *(const short8x*)&Bs[wn + i * 16 + l15][quad * 8];
#pragma unroll
    for (int mi = 0; mi < 4; mi++)
#pragma unroll
      for (int ni = 0; ni < 4; ni++)
        acc[mi][ni] = mfma16(af[mi], bfr[ni], acc[mi][ni]);
  }
#pragma unroll
  for (int mi = 0; mi < 4; mi++) {
#pragma unroll
    for (int ni = 0; ni < 4; ni++) {
      int gn = n0 + wn + ni * 16 + l15;
      if (gn < 2048) {
        // Q: uncompacted
        int which = gn >> 10, j = gn & 1023, h = j >> 6, dk = j & 63;
        int ks = dk >> 5, q = (dk >> 3) & 3, e = dk & 7;
        unsigned short* dst = which ? Qi : Qr;
#pragma unroll
        for (int r = 0; r < 4; r++) {
          int gm = m0 + wm + mi * 16 + quad * 4 + r;
          int b = gm >> 11, s = gm & 2047;
          int bh = b * HH + h, rb = s >> 4, l = s & 15;
          dst[(size_t)(((bh * 128 + rb) * 2 + ks) * 512 + (q * 16 + l) * 8 + e)] = f2b(acc[mi][ni][r]);
        }
      } else if (gn < 4096) {
        // K: compacted per (b, half)
        int which = gn >> 10, j = gn & 1023, h = j >> 6, dk = j & 63;
        int ks = dk >> 5, q = (dk >> 3) & 3, e = dk & 7;
        unsigned short* dst = (which == 2) ? Kr : Ki;
#pragma unroll
        for (int r = 0; r < 4; r++) {
          int gm = m0 + wm + mi * 16 + quad * 4 + r;
          int b = gm >> 11, s = gm & 2047;
          unsigned short pp = pos[b * 2048 + s];
          if (pp != 0xFFFFu) {
            int hf = s >> 10;
            int bh = b * HH + h, rb = hf * 64 + (pp >> 4), l = pp & 15;
            dst[(size_t)(((bh * 128 + rb) * 2 + ks) * 512 + (q * 16 + l) * 8 + e)] = f2b(acc[mi][ni][r]);
          }
        }
      } else {
        // V^T: compacted per (b, half)
        int j = gn - 4096, h = j >> 6, dk = j & 63;
        int rbv = dk >> 4, lv = dk & 15;
#pragma unroll
        for (int r = 0; r < 4; r++) {
          int gm = m0 + wm + mi * 16 + quad * 4 + r;
          int b = gm >> 11, s = gm & 2047;
          unsigned short pp = pos[b * 2048 + s];
          if (pp != 0xFFFFu) {
            int hf = s >> 10;
            int bh = b * HH + h, kc = hf * 32 + (pp >> 5), qv = (pp >> 3) & 3, ev = pp & 7;
            VT[(size_t)(((bh * 4 + rbv) * 64 + kc) * 512 + (qv * 16 + lv) * 8 + ev)] = f2b(acc[mi][ni][r]);
          }
        }
      }
    }
  }
}

// ---------------- flash attention over COMPACTED keys, kt-outer/subtile-inner,
// K staged in LDS (R17): all 4 waves consumed identical K frags; wave w now stages
// frags 4w..4w+3 (1KB each) via gload16, reads via ds_read_b128. V stays global
// (LDS budget: Ps 18.4 + Ks 16 = 34.8KB x4 = 139KB).
__global__ __launch_bounds__(256, 4) void flash_kernel(
    const unsigned short* __restrict__ Qr, const unsigned short* __restrict__ Qi,
    const unsigned short* __restrict__ Kr, const unsigned short* __restrict__ Ki,
    const unsigned short* __restrict__ VT, const int* __restrict__ cnt,
    float* __restrict__ ctxP0, float* __restrict__ ctxP1,
    float* __restrict__ Lp0, float* __restrict__ Lp1) {
  __shared__ __attribute__((aligned(16))) unsigned short Ps[2][4][16][72];
  __shared__ __attribute__((aligned(16))) unsigned short Ks[2][4][2][512];
  const int tid = threadIdx.x;
  const int lane = tid & 63, wid = tid >> 6;
  const int l15 = lane & 15, quad = lane >> 4;
  // XCD swizzle (bijective, 1024 % 8 == 0): each XCD gets 8 heads of one z.
  int lin = blockIdx.x + 16 * (blockIdx.y + 16 * blockIdx.z);
  lin = ((lin & 7) << 7) | (lin >> 3);
  const int qt2 = (lin & 15) * 128;
  const int h = (lin >> 4) & 15;
  const int z = lin >> 8;
  const int b = z >> 1, half = z & 1;
  const int bh = b * HH + h;
  float* __restrict__ cp = half ? ctxP1 : ctxP0;
  float* __restrict__ lp = half ? Lp1 : Lp0;
  const int cntbh = cnt[b * 2 + half];
  const int kend = ((cntbh + 63) >> 6) << 6;
  const int kt0 = half * 1024;

  // Q fragments for both 64-row subtiles
  short8x fqr0[2], fqr1[2], fqi0[2], fqi1[2];
#pragma unroll
  for (int s2 = 0; s2 < 2; s2++) {
    const int rb = ((qt2 + s2 * 64) >> 4) + wid;
    const int qb = (bh * 128 + rb) * 1024 + lane * 8;
    fqr0[s2] = *(const short8x*)(Qr + qb);
    fqr1[s2] = *(const short8x*)(Qr + qb + 512);
    fqi0[s2] = *(const short8x*)(Qi + qb);
    fqi1[s2] = *(const short8x*)(Qi + qb + 512);
  }
  f32x4 ctxacc[2][4] = {};
  float lsum[2][4] = {{0.f, 0.f, 0.f, 0.f}, {0.f, 0.f, 0.f, 0.f}};

  // staging identity for this wave: frags f = wid*4+fi -> arr=f>>3, rbl=(f>>1)&3, ks=f&1
  const int sf0 = wid * 4;

  for (int ktl = 0; ktl < kend; ktl += 64) {
    const int kt = kt0 + ktl;
    const int rbb = bh * 128 + (kt >> 4);
    __syncthreads();   // protect prior-iteration Ks reads
#pragma unroll
    for (int fi = 0; fi < 4; fi++) {
      int f = sf0 + fi;
      int arr = f >> 3, rbl = (f >> 1) & 3, ks = f & 1;
      const unsigned short* src = (arr ? Ki : Kr) + ((size_t)(rbb + rbl) * 2 + ks) * 512 + lane * 8;
      gload16(src, &Ks[arr][rbl][ks][0]);
    }
    __syncthreads();   // staged data visible to all waves
#pragma unroll
    for (int nb = 0; nb < 4; nb++) {
      const int j = ktl + nb * 16 + l15;           // compacted-local index
      short8x bkr0 = *(const short8x*)&Ks[0][nb][0][lane * 8];
      short8x bkr1 = *(const short8x*)&Ks[0][nb][1][lane * 8];
      short8x bki0 = *(const short8x*)&Ks[1][nb][0][lane * 8];
      short8x bki1 = *(const short8x*)&Ks[1][nb][1][lane * 8];
#pragma unroll
      for (int s2 = 0; s2 < 2; s2++) {
        f32x4 sr = {0.f, 0.f, 0.f, 0.f};
        sr = mfma16(fqr0[s2], bkr0, sr);  sr = mfma16(fqr1[s2], bkr1, sr);
        sr = mfma16(fqi0[s2], bki0, sr);  sr = mfma16(fqi1[s2], bki1, sr);
        f32x4 sa = {0.f, 0.f, 0.f, 0.f};
        sa = mfma16(fqi0[s2], bkr0, sa);  sa = mfma16(fqi1[s2], bkr1, sa);
        f32x4 sb = {0.f, 0.f, 0.f, 0.f};
        sb = mfma16(fqr0[s2], bki0, sb);  sb = mfma16(fqr1[s2], bki1, sb);
#pragma unroll
        for (int r = 0; r < 4; r++) {
          float a = sr[r];
          float d = sa[r] - sb[r];
          float r2 = __builtin_fmaf(a, a, d * d);
          float inv = __builtin_amdgcn_rsqf(r2);
          float arg = inv * __builtin_fmaf(C1F, r2, C2F * a);
          float p = (j < cntbh) ? __builtin_amdgcn_exp2f(arg) : 0.0f;  // select, not mul
          lsum[s2][r] += p;
          Ps[s2][wid][quad * 4 + r][nb * 16 + l15] = f2b_fast(p);
        }
      }
    }
    // PV: V loaded once (global), feeds both subtiles. V pad rows pre-zeroed.
#pragma unroll
    for (int ks = 0; ks < 2; ks++)
#pragma unroll
      for (int db = 0; db < 4; db++) {
        int voff = ((bh * 4 + db) * 64 + (kt >> 5) + ks) * 512 + lane * 8;
        short8x bv = *(const short8x*)(VT + voff);
        short8x ap0 = *(const short8x*)&Ps[0][wid][l15][ks * 32 + quad * 8];
        short8x ap1 = *(const short8x*)&Ps[1][wid][l15][ks * 32 + quad * 8];
        ctxacc[0][db] = mfma16(ap0, bv, ctxacc[0][db]);
        ctxacc[1][db] = mfma16(ap1, bv, ctxacc[1][db]);
      }
  }
#pragma unroll
  for (int s2 = 0; s2 < 2; s2++) {
#pragma unroll
    for (int r = 0; r < 4; r++) {
#pragma unroll
      for (int off = 1; off < 16; off <<= 1) lsum[s2][r] += __shfl_xor(lsum[s2][r], off, 64);
    }
#pragma unroll
    for (int r = 0; r < 4; r++) {
      int s = qt2 + s2 * 64 + wid * 16 + quad * 4 + r;
#pragma unroll
      for (int db = 0; db < 4; db++)
        cp[((size_t)b * SS + s) * DD + h * DKK + db * 16 + l15] = ctxacc[s2][db][r];
      if (l15 == 0) lp[(size_t)bh * SS + s] = lsum[s2][r];
    }
  }
}

// ---------------- combine: ctx_bf16 = (P0+P1) / (L0+L1)
__global__ __launch_bounds__(256) void combine_kernel(
    const float* __restrict__ ctxP0, const float* __restrict__ ctxP1,
    const float* __restrict__ Lp0, const float* __restrict__ Lp1,
    unsigned short* __restrict__ ctx) {
  int idx = blockIdx.x * 256 + threadIdx.x;   // 1048576 threads
  int g = idx * 4;
  int c = g & 1023, s = (g >> 10) & 2047, b = g >> 21;
  int h = c >> 6;
  size_t loff = (size_t)(b * HH + h) * SS + s;
  float linv = 1.0f / (Lp0[loff] + Lp1[loff]);
  float4 p0 = *(const float4*)(ctxP0 + g);
  float4 p1 = *(const float4*)(ctxP1 + g);
  ushort4 o;
  o.x = f2b((p0.x + p1.x) * linv);
  o.y = f2b((p0.y + p1.y) * linv);
  o.z = f2b((p0.z + p1.z) * linv);
  o.w = f2b((p0.w + p1.w) * linv);
  *(ushort4*)(ctx + g) = o;
}

// ---------------- output GEMM: out = ctx @ WoT^T + bias (64x128 tiles, 512 blocks)
__global__ __launch_bounds__(256, 2) void gemm_out_kernel(
    const unsigned short* __restrict__ A, const unsigned short* __restrict__ Bt,
    const float* __restrict__ bias, float* __restrict__ out) {
  constexpr int K = 1024;
  __shared__ __attribute__((aligned(16))) unsigned short As[64][32];
  __shared__ __attribute__((aligned(16))) unsigned short Bs[128][32];
  const int tid = threadIdx.x;
  const int m0 = blockIdx.x * 64;
  const int n0 = blockIdx.y * 128;
  const int lane = tid & 63, wid = tid >> 6;
  const int l15 = lane & 15, quad = lane >> 4;
  const int wm = (wid & 1) * 32, wn = (wid >> 1) * 64;
  const int r4 = lane >> 2, c8 = (lane & 3) * 8;
  f32x4 acc[2][4] = {};
  const unsigned short* pa0 = A + (size_t)(m0 + wid * 16 + r4) * K + c8;
  const unsigned short* pb0 = Bt + (size_t)(n0 + wid * 16 + r4) * K + c8;
  const unsigned short* pb1 = pb0 + (size_t)64 * K;
  unsigned short* la0 = &As[wid * 16][0];
  unsigned short* lb0 = &Bs[wid * 16][0];
  unsigned short* lb1 = &Bs[64 + wid * 16][0];
  for (int k0 = 0; k0 < K; k0 += 32) {
    __syncthreads();
    gload16(pa0, la0);
    gload16(pb0, lb0);  gload16(pb1, lb1);
    pa0 += 32; pb0 += 32; pb1 += 32;
    __syncthreads();
    short8x af[2], bfr[4];
#pragma unroll
    for (int i = 0; i < 2; i++) af[i]  = *(const short8x*)&As[wm + i * 16 + l15][quad * 8];
#pragma unroll
    for (int i = 0; i < 4; i++) bfr[i] = *(const short8x*)&Bs[wn + i * 16 + l15][quad * 8];
#pragma unroll
    for (int mi = 0; mi < 2; mi++)
#pragma unroll
      for (int ni = 0; ni < 4; ni++)
        acc[mi][ni] = mfma16(af[mi], bfr[ni], acc[mi][ni]);
  }
#pragma unroll
  for (int mi = 0; mi < 2; mi++)
#pragma unroll
    for (int ni = 0; ni < 4; ni++) {
      int gn = n0 + wn + ni * 16 + l15;
      float bv = bias[gn];
#pragma unroll
      for (int r = 0; r < 4; r++) {
        int gm = m0 + wm + mi * 16 + quad * 4 + r;
        out[(size_t)gm * 1024 + gn] = acc[mi][ni][r] + bv;
      }
    }
}

// ---------------- probs_mean over COMPACTED keys, K staged in LDS (R17);
// out2 pre-zeroed, valid columns scattered via idx.
__global__ __launch_bounds__(256, 4) void probsmean_kernel(
    const unsigned short* __restrict__ Qr, const unsigned short* __restrict__ Qi,
    const unsigned short* __restrict__ Kr, const unsigned short* __restrict__ Ki,
    const int* __restrict__ cnt, const unsigned short* __restrict__ idxT,
    const float* __restrict__ Lp0, const float* __restrict__ Lp1,
    float* __restrict__ out2) {
  __shared__ __attribute__((aligned(16))) unsigned short Ks[2][4][2][512];
  const int tid = threadIdx.x, lane = tid & 63, wid = tid >> 6;
  const int l15 = lane & 15, quad = lane >> 4;
  const int qt = blockIdx.x * 64;
  const int b = blockIdx.z;
  const int c0 = cnt[b * 2], c1 = cnt[b * 2 + 1];
  const int t0n = (c0 + 63) >> 6;
  const int t1n = (c1 + 63) >> 6;
  const int t = blockIdx.y;
  int half, jl0, cnth;
  if (t < t0n)            { half = 0; jl0 = t * 64;         cnth = c0; }
  else if (t < t0n + t1n) { half = 1; jl0 = (t - t0n) * 64; cnth = c1; }
  else return;  // out2 pre-zeroed (block-uniform exit, before any barrier)
  const int qrow0 = qt + wid * 16;
  const int qrb = (qt >> 4) + wid;
  const int ktb = half * 64 + (jl0 >> 4);
  const int sf0 = wid * 4;
  int korig[4]; bool vld[4];
#pragma unroll
  for (int nb = 0; nb < 4; nb++) {
    int j = jl0 + nb * 16 + l15;
    vld[nb] = j < cnth;
    korig[nb] = idxT[(b * 2 + half) * 1024 + j];
  }
  float psum[4][4] = {};  // [nb][r]
  for (int h = 0; h < HH; h++) {
    const int bh = b * HH + h;
    const int qoff = (bh * 128 + qrb) * 1024 + lane * 8;
    short8x fqr0 = *(const short8x*)(Qr + qoff);
    short8x fqr1 = *(const short8x*)(Qr + qoff + 512);
    short8x fqi0 = *(const short8x*)(Qi + qoff);
    short8x fqi1 = *(const short8x*)(Qi + qoff + 512);
    const float4 lv0 = *(const float4*)(Lp0 + (size_t)bh * SS + qrow0 + quad * 4);
    const float4 lv1 = *(const float4*)(Lp1 + (size_t)bh * SS + qrow0 + quad * 4);
    float li[4];
    li[0] = 1.0f / (lv0.x + lv1.x); li[1] = 1.0f / (lv0.y + lv1.y);
    li[2] = 1.0f / (lv0.z + lv1.z); li[3] = 1.0f / (lv0.w + lv1.w);
    // stage this head's 16 K frags (wave w: frags 4w..4w+3)
    const int rbb = bh * 128 + ktb;
    __syncthreads();   // protect prior-iteration Ks reads
#pragma unroll
    for (int fi = 0; fi < 4; fi++) {
      int f = sf0 + fi;
      int arr = f >> 3, rbl = (f >> 1) & 3, ks = f & 1;
      const unsigned short* src = (arr ? Ki : Kr) + ((size_t)(rbb + rbl) * 2 + ks) * 512 + lane * 8;
      gload16(src, &Ks[arr][rbl][ks][0]);
    }
    __syncthreads();   // staged data visible
#pragma unroll
    for (int nb = 0; nb < 4; nb++) {
      short8x bkr0 = *(const short8x*)&Ks[0][nb][0][lane * 8];
      short8x bkr1 = *(const short8x*)&Ks[0][nb][1][lane * 8];
      short8x bki0 = *(const short8x*)&Ks[1][nb][0][lane * 8];
      short8x bki1 = *(const short8x*)&Ks[1][nb][1][lane * 8];
      f32x4 sr = {0.f, 0.f, 0.f, 0.f};
      sr = mfma16(fqr0, bkr0, sr);  sr = mfma16(fqr1, bkr1, sr);
      sr = mfma16(fqi0, bki0, sr);  sr = mfma16(fqi1, bki1, sr);
      f32x4 sa = {0.f, 0.f, 0.f, 0.f};  // Qi.Kr
      sa = mfma16(fqi0, bkr0, sa);  sa = mfma16(fqi1, bkr1, sa);
      f32x4 sb = {0.f, 0.f, 0.f, 0.f};  // Qr.Ki
      sb = mfma16(fqr0, bki0, sb);  sb = mfma16(fqr1, bki1, sb);
#pragma unroll
      for (int r = 0; r < 4; r++) {
        float a = sr[r];
        float d = sa[r] - sb[r];
        float r2 = __builtin_fmaf(a, a, d * d);
        float inv = __builtin_amdgcn_rsqf(r2);
        float arg = inv * __builtin_fmaf(C1F, r2, C2F * a);
        float p = vld[nb] ? __builtin_amdgcn_exp2f(arg) * li[r] : 0.0f;  // select
        psum[nb][r] += p;
      }
    }
  }
#pragma unroll
  for (int nb = 0; nb < 4; nb++)
#pragma unroll
    for (int r = 0; r < 4; r++) {
      if (vld[nb]) {
        int qrow = qrow0 + quad * 4 + r;
        out2[((size_t)b * SS + qrow) * SS + korig[nb]] = psum[nb][r] * 0.0625f;
      }
    }
}

extern "C" void kernel_launch(void* const* d_in, const int* in_sizes, int n_in,
                              void* d_out, int out_size, void* d_ws, size_t ws_size,
                              hipStream_t stream) {
  const float* z_real = (const float*)d_in[0];
  const float* z_imag = (const float*)d_in[1];
  const float* Wq_r = (const float*)d_in[2];
  const float* Wq_i = (const float*)d_in[3];
  const float* Wk_r = (const float*)d_in[4];
  const float* Wk_i = (const float*)d_in[5];
  const float* Wv   = (const float*)d_in[6];
  const float* Wo_w = (const float*)d_in[7];
  const float* Wo_b = (const float*)d_in[8];
  const int*   mask = (const int*)d_in[9];
  char* ws = (char*)d_ws;

  // ws layout (bytes). ctxP0/ctxP1 ALIAS WcatT/Xcat: dead after gemm_proj (stream-serial).
  constexpr size_t QKV_BYTES = 8388608;  // B*H*S*DK*2
  unsigned short* Qr   = (unsigned short*)(ws + 0);
  unsigned short* Qi   = (unsigned short*)(ws + QKV_BYTES);
  unsigned short* Kr   = (unsigned short*)(ws + 2 * QKV_BYTES);
  unsigned short* Ki   = (unsigned short*)(ws + 3 * QKV_BYTES);
  unsigned short* VT   = (unsigned short*)(ws + 4 * QKV_BYTES);
  unsigned short* ctx  = (unsigned short*)(ws + 5 * QKV_BYTES);              // 8 MB bf16
  unsigned short* WcatT= (unsigned short*)(ws + 50331648);                   // 20 MB
  unsigned short* WoT  = (unsigned short*)(ws + 71303168);                   // 2 MB
  unsigned short* Xcat = (unsigned short*)(ws + 73400320);                   // 16 MB
  float* ctxP0 = (float*)(ws + 50331648);                                    // aliases WcatT (16 MB)
  float* ctxP1 = (float*)(ws + 73400320);                                    // aliases Xcat (16 MB)
  float* Lp0   = (float*)(ws + 90177536);                                    // 256 KB
  float* Lp1   = (float*)(ws + 90439680);                                    // 256 KB

  float* out  = (float*)d_out;
  float* out2 = out + (size_t)BB * SS * DD;

  // Compaction tables live in d_out scratch (`out` region): dead until gemm_out,
  // which runs last. probsmean (reads idx) ordered before combine/gemm_out.
  unsigned short* posT = (unsigned short*)out;       // [2][2048] = 8 KB
  unsigned short* idxT = posT + 4096;                // [2][2][1024] = 8 KB
  int* cntT = (int*)(idxT + 4096);                   // [2][2]

  pack_w_kernel<<<dim3(2816), dim3(256), 0, stream>>>(Wq_r, Wq_i, Wk_r, Wk_i, Wv, Wo_w, WcatT, WoT);
  pack_x_kernel<<<dim3(4096), dim3(256), 0, stream>>>(z_real, z_imag, Xcat);
  zero_kernel<<<dim3(2048), dim3(256), 0, stream>>>((float4*)VT);            // 8 MB: V pad rows = 0
  zero_kernel<<<dim3(8192), dim3(256), 0, stream>>>((float4*)out2);          // 32 MB: masked cols = 0
  mask_scan_kernel<<<dim3(4), dim3(256), 0, stream>>>(mask, posT, idxT, cntT);
  gemm_proj_kernel<<<dim3(32, 40), dim3(256), 0, stream>>>(Xcat, WcatT, posT, Qr, Qi, Kr, Ki, VT);
  flash_kernel<<<dim3(16, 16, 4), dim3(256), 0, stream>>>(Qr, Qi, Kr, Ki, VT, cntT, ctxP0, ctxP1, Lp0, Lp1);
  probsmean_kernel<<<dim3(32, 32, 2), dim3(256), 0, stream>>>(Qr, Qi, Kr, Ki, cntT, idxT, Lp0, Lp1, out2);
  combine_kernel<<<dim3(4096), dim3(256), 0, stream>>>(ctxP0, ctxP1, Lp0, Lp1, ctx);
  gemm_out_kernel<<<dim3(64, 8), dim3(256), 0, stream>>>(ctx, WoT, Wo_b, out);
}

// Round 11
// 373.028 us; speedup vs baseline: 1.9599x; 1.0651x over previous
//
#include <hip/hip_runtime.h>
#include <cstdint>
#include <cstddef>

#define BB 2
#define SS 2048
#define DD 1024
#define HH 16
#define DKK 64

typedef __attribute__((ext_vector_type(8))) short short8x;
typedef __attribute__((ext_vector_type(4))) float f32x4;

__device__ __forceinline__ unsigned short f2b(float f) {
  union { float f; unsigned u; } v; v.f = f;
  unsigned r = (v.u + 0x7fffu + ((v.u >> 16) & 1u)) >> 16;  // RNE
  return (unsigned short)r;
}

// hot-path bf16: round-half-up, 2 VALU (vs ~5 for RNE). Used only for Ps probabilities.
__device__ __forceinline__ unsigned short f2b_fast(float f) {
  union { float f; unsigned u; } v; v.f = f;
  return (unsigned short)((v.u + 0x8000u) >> 16);
}

__device__ __forceinline__ f32x4 mfma16(short8x a, short8x b, f32x4 c) {
  return __builtin_amdgcn_mfma_f32_16x16x32_bf16(a, b, c, 0, 0, 0);
}

// async global->LDS, 16B per lane. LDS dest = wave-uniform base + lane*16 (implicit).
__device__ __forceinline__ void gload16(const unsigned short* g, unsigned short* l) {
  __builtin_amdgcn_global_load_lds(
      (__attribute__((address_space(1))) unsigned int*)g,
      (__attribute__((address_space(3))) unsigned int*)l,
      16, 0, 0);
}

// Fragment-major Q/K layout (R5). R6: fixed m=0. R7: K-split + combine. R8: raw-HW
// transcendentals. R9 FAILED (flash spill at 8/EU). R10: XCD swizzle on flash.
// R11-R14: gemm_proj (256,5)+gload_lds+V-K1024. R12: K-compaction. R15: pack_w
// transpose + flash 128-row tiles. R16: flash kt-outer (K/V traffic /2), gemm_out
// 64x128. R17: flash/probsmean K-LDS staging, pack_x vectorized (397us).
// R18 (this round): COMPACTED-M K/V PROJECTION. gemm_proj computed K/V for all
// 4096 rows then discarded the masked half in the epilogue. K/V n-range = 60% of
// the GEMM; half its rows were dead. pack_x now also scatters unmasked rows into
// Xc2 (segment g=b*2+half at rows [g*1024, g*1024+cnt[g]) -> row index == slot pp,
// pos-lookup epilogue disappears). gemm_proj: n-tiles<16 = Q path (full Xcat);
// >=16 = K/V path (Xc2, early-exit tiles past cnt). Active blocks 1280 -> ~920
// (0.72x FLOPs). Bitwise-identical K/V (same per-element MFMA sequence; garbage
// pad rows only affect discarded outputs). Xc2 aliases out2 scratch (dead until
// probsmean; zero_out2 moved after gemm_proj). mask_scan moved before pack_x.
#define C1F 0.0225421076f  // (1/64)*log2e
#define C2F 0.0541010849f  // (0.3/8)*log2e

// ---------------- pack weights: tiled transpose, coalesced both sides
__global__ __launch_bounds__(256) void pack_w_kernel(
    const float* __restrict__ Wq_r, const float* __restrict__ Wq_i,
    const float* __restrict__ Wk_r, const float* __restrict__ Wk_i,
    const float* __restrict__ Wv, const float* __restrict__ Wo,
    unsigned short* __restrict__ WcatT, unsigned short* __restrict__ WoT) {
  __shared__ float tile[64][65];
  const int tid = threadIdx.x;
  int bid = blockIdx.x;
  if (bid < 2560) {
    const int kt = bid & 31, nt = bid >> 5;
    const int k0 = kt * 64, n0 = nt * 64;
    const int q = n0 >> 10, j0 = n0 & 1023;
    const float* src;
    float sgn = 1.0f;
    bool zero = false;
    if (k0 < 1024) {
      src = (q == 0) ? Wq_r : (q == 1) ? Wq_i : (q == 2) ? Wk_r : (q == 3) ? Wk_i : Wv;
    } else {
      if (q == 0)      { src = Wq_i; sgn = -1.0f; }
      else if (q == 1) { src = Wq_r; }
      else if (q == 2) { src = Wk_i; sgn = -1.0f; }
      else if (q == 3) { src = Wk_r; }
      else             { src = Wv; zero = true; }
    }
    const int ks0 = k0 & 1023;
    if (!zero) {
#pragma unroll
      for (int i = 0; i < 16; i++) {
        int idx = i * 256 + tid;
        int r = idx >> 6, c = idx & 63;
        tile[r][c] = src[(size_t)(ks0 + r) * 1024 + j0 + c];
      }
      __syncthreads();
#pragma unroll
      for (int i = 0; i < 16; i++) {
        int idx = i * 256 + tid;
        int nr = idx >> 6, kc = idx & 63;
        WcatT[(size_t)(n0 + nr) * 2048 + k0 + kc] = f2b(sgn * tile[kc][nr]);
      }
    } else {
#pragma unroll
      for (int i = 0; i < 16; i++) {
        int idx = i * 256 + tid;
        int nr = idx >> 6, kc = idx & 63;
        WcatT[(size_t)(n0 + nr) * 2048 + k0 + kc] = 0;
      }
    }
  } else {
    bid -= 2560;
    const int kt = bid & 15, nt = bid >> 4;
    const int k0 = kt * 64, n0 = nt * 64;
#pragma unroll
    for (int i = 0; i < 16; i++) {
      int idx = i * 256 + tid;
      int r = idx >> 6, c = idx & 63;
      tile[r][c] = Wo[(size_t)(k0 + r) * 1024 + n0 + c];
    }
    __syncthreads();
#pragma unroll
    for (int i = 0; i < 16; i++) {
      int idx = i * 256 + tid;
      int nr = idx >> 6, kc = idx & 63;
      WoT[(size_t)(n0 + nr) * 1024 + k0 + kc] = f2b(tile[kc][nr]);
    }
  }
}

// ---------------- pack X (R18: also scatter unmasked rows into Xc2 segments)
__global__ void pack_x_kernel(const float* __restrict__ zr, const float* __restrict__ zi,
                              const unsigned short* __restrict__ pos,
                              unsigned short* __restrict__ X,
                              unsigned short* __restrict__ Xc2) {
  int gid = blockIdx.x * 256 + threadIdx.x;  // 1048576 threads x 8 elems
  int k8 = (gid & 255) << 3;                 // 0..2047 step 8 (never straddles 1024)
  int m = gid >> 8;
  const float* src = (k8 < 1024) ? (zr + (size_t)m * 1024 + k8)
                                 : (zi + (size_t)m * 1024 + (k8 - 1024));
  float4 a = *(const float4*)src;
  float4 c = *(const float4*)(src + 4);
  ushort4 o0; o0.x = f2b(a.x); o0.y = f2b(a.y); o0.z = f2b(a.z); o0.w = f2b(a.w);
  ushort4 o1; o1.x = f2b(c.x); o1.y = f2b(c.y); o1.z = f2b(c.z); o1.w = f2b(c.w);
  *(ushort4*)(X + (size_t)gid * 8) = o0;
  *(ushort4*)(X + (size_t)gid * 8 + 4) = o1;
  unsigned short pp = pos[m];
  if (pp != 0xFFFFu) {
    int b = m >> 11, s = m & 2047, half = s >> 10;
    size_t drow = (size_t)((b * 2 + half) * 1024 + pp);
    *(ushort4*)(Xc2 + drow * 2048 + k8) = o0;
    *(ushort4*)(Xc2 + drow * 2048 + k8 + 4) = o1;
  }
}

// ---------------- generic zero (float4 granularity)
__global__ void zero_kernel(float4* __restrict__ p) {
  p[(size_t)blockIdx.x * 256 + threadIdx.x] = float4{0.f, 0.f, 0.f, 0.f};
}

// ---------------- mask scan: per (b,half) compaction tables
__global__ void mask_scan_kernel(const int* __restrict__ mask,
                                 unsigned short* __restrict__ pos,
                                 unsigned short* __restrict__ idx,
                                 int* __restrict__ cnt) {
  const int b = blockIdx.x >> 1, half = blockIdx.x & 1;
  __shared__ int sums[256];
  const int t = threadIdx.x;
  const int s0 = half * 1024 + t * 4;
  int m[4];
  int loc = 0;
#pragma unroll
  for (int i = 0; i < 4; i++) { m[i] = mask[b * 2048 + s0 + i]; loc += m[i]; }
  sums[t] = loc;
  __syncthreads();
  for (int off = 1; off < 256; off <<= 1) {
    int v = (t >= off) ? sums[t - off] : 0;
    __syncthreads();
    sums[t] += v;
    __syncthreads();
  }
  int excl = sums[t] - loc;
#pragma unroll
  for (int i = 0; i < 4; i++) {
    int sg = s0 + i;
    if (m[i]) {
      pos[b * 2048 + sg] = (unsigned short)excl;
      idx[(b * 2 + half) * 1024 + excl] = (unsigned short)sg;
      excl++;
    } else {
      pos[b * 2048 + sg] = 0xFFFFu;
    }
  }
  if (t == 255) cnt[b * 2 + half] = sums[255];
}

// ---------------- projection GEMM (R18): Q path (by<16, full Xcat) and K/V path
// (by>=16, compacted Xc2; early-exit past cnt; slot == local row, no pos lookup).
__global__ __launch_bounds__(256, 5) void gemm_proj_kernel(
    const unsigned short* __restrict__ A, const unsigned short* __restrict__ Ac,
    const unsigned short* __restrict__ Bt, const int* __restrict__ cnt,
    unsigned short* __restrict__ Qr, unsigned short* __restrict__ Qi,
    unsigned short* __restrict__ Kr, unsigned short* __restrict__ Ki,
    unsigned short* __restrict__ VT) {
  constexpr int K = 2048;
  const int n0 = blockIdx.y * 128;
  const bool qpath = (n0 < 2048);
  const int m0 = blockIdx.x * 128;
  int cntg = 0;
  if (!qpath) {
    cntg = cnt[blockIdx.x >> 3];
    if (((blockIdx.x & 7) * 128) >= cntg) return;   // block-uniform, before barriers
  }
  __shared__ __attribute__((aligned(16))) unsigned short As[128][32];
  __shared__ __attribute__((aligned(16))) unsigned short Bs[128][32];
  const int tid = threadIdx.x;
  const int lane = tid & 63, wid = tid >> 6;
  const int l15 = lane & 15, quad = lane >> 4;
  const int wm = (wid & 1) * 64, wn = (wid >> 1) * 64;
  const int r4 = lane >> 2, c8 = (lane & 3) * 8;
  // V columns (n >= 4096) have zero weights for k >= 1024: skip exactly.
  const int kmax = (n0 >= 4096) ? 1024 : K;
  f32x4 acc[4][4] = {};
  const unsigned short* Ab = qpath ? A : Ac;
  const unsigned short* pa0 = Ab + (size_t)(m0 + wid * 16 + r4) * K + c8;
  const unsigned short* pa1 = pa0 + (size_t)64 * K;
  const unsigned short* pb0 = Bt + (size_t)(n0 + wid * 16 + r4) * K + c8;
  const unsigned short* pb1 = pb0 + (size_t)64 * K;
  unsigned short* la0 = &As[wid * 16][0];
  unsigned short* la1 = &As[64 + wid * 16][0];
  unsigned short* lb0 = &Bs[wid * 16][0];
  unsigned short* lb1 = &Bs[64 + wid * 16][0];
  for (int k0 = 0; k0 < kmax; k0 += 32) {
    __syncthreads();
    gload16(pa0, la0);  gload16(pa1, la1);
    gload16(pb0, lb0);  gload16(pb1, lb1);
    pa0 += 32; pa1 += 32; pb0 += 32; pb1 += 32;
    __syncthreads();
    short8x af[4], bfr[4];
#pragma unroll
    for (int i = 0; i < 4; i++) af[i]  = *(const short8x*)&As[wm + i * 16 + l15][quad * 8];
#pragma unroll
    for (int i = 0; i < 4; i++) bfr[i] = *(const short8x*)&Bs[wn + i * 16 + l15][quad * 8];
#pragma unroll
    for (int mi = 0; mi < 4; mi++)
#pragma unroll
      for (int ni = 0; ni < 4; ni++)
        acc[mi][ni] = mfma16(af[mi], bfr[ni], acc[mi][ni]);
  }
  if (qpath) {
#pragma unroll
    for (int mi = 0; mi < 4; mi++)
#pragma unroll
      for (int ni = 0; ni < 4; ni++) {
        int gn = n0 + wn + ni * 16 + l15;
        int which = gn >> 10, j = gn & 1023, h = j >> 6, dk = j & 63;
        int ks = dk >> 5, q = (dk >> 3) & 3, e = dk & 7;
        unsigned short* dst = which ? Qi : Qr;
#pragma unroll
        for (int r = 0; r < 4; r++) {
          int gm = m0 + wm + mi * 16 + quad * 4 + r;
          int b = gm >> 11, s = gm & 2047;
          int bh = b * HH + h, rb = s >> 4, l = s & 15;
          dst[(size_t)(((bh * 128 + rb) * 2 + ks) * 512 + (q * 16 + l) * 8 + e)] = f2b(acc[mi][ni][r]);
        }
      }
  } else {
    const int g = blockIdx.x >> 3;
    const int b = g >> 1, hf = g & 1;
#pragma unroll
    for (int mi = 0; mi < 4; mi++)
#pragma unroll
      for (int ni = 0; ni < 4; ni++) {
        int gn = n0 + wn + ni * 16 + l15;
        if (gn < 4096) {
          // K: slot = local row
          int which = gn >> 10, j = gn & 1023, h = j >> 6, dk = j & 63;
          int ks = dk >> 5, q = (dk >> 3) & 3, e = dk & 7;
          unsigned short* dst = (which == 2) ? Kr : Ki;
#pragma unroll
          for (int r = 0; r < 4; r++) {
            int gm = m0 + wm + mi * 16 + quad * 4 + r;
            int local = gm & 1023;
            if (local < cntg) {
              int bh = b * HH + h, rb = hf * 64 + (local >> 4), l = local & 15;
              dst[(size_t)(((bh * 128 + rb) * 2 + ks) * 512 + (q * 16 + l) * 8 + e)] = f2b(acc[mi][ni][r]);
            }
          }
        } else {
          // V^T: slot = local row
          int j = gn - 4096, h = j >> 6, dk = j & 63;
          int rbv = dk >> 4, lv = dk & 15;
#pragma unroll
          for (int r = 0; r < 4; r++) {
            int gm = m0 + wm + mi * 16 + quad * 4 + r;
            int local = gm & 1023;
            if (local < cntg) {
              int bh = b * HH + h, kc = hf * 32 + (local >> 5), qv = (local >> 3) & 3, ev = local & 7;
              VT[(size_t)(((bh * 4 + rbv) * 64 + kc) * 512 + (qv * 16 + lv) * 8 + ev)] = f2b(acc[mi][ni][r]);
            }
          }
        }
      }
  }
}

// ---------------- flash attention over COMPACTED keys, kt-outer/subtile-inner,
// K staged in LDS (R17). V stays global.
__global__ __launch_bounds__(256, 4) void flash_kernel(
    const unsigned short* __restrict__ Qr, const unsigned short* __restrict__ Qi,
    const unsigned short* __restrict__ Kr, const unsigned short* __restrict__ Ki,
    const unsigned short* __restrict__ VT, const int* __restrict__ cnt,
    float* __restrict__ ctxP0, float* __restrict__ ctxP1,
    float* __restrict__ Lp0, float* __restrict__ Lp1) {
  __shared__ __attribute__((aligned(16))) unsigned short Ps[2][4][16][72];
  __shared__ __attribute__((aligned(16))) unsigned short Ks[2][4][2][512];
  const int tid = threadIdx.x;
  const int lane = tid & 63, wid = tid >> 6;
  const int l15 = lane & 15, quad = lane >> 4;
  // XCD swizzle (bijective, 1024 % 8 == 0): each XCD gets 8 heads of one z.
  int lin = blockIdx.x + 16 * (blockIdx.y + 16 * blockIdx.z);
  lin = ((lin & 7) << 7) | (lin >> 3);
  const int qt2 = (lin & 15) * 128;
  const int h = (lin >> 4) & 15;
  const int z = lin >> 8;
  const int b = z >> 1, half = z & 1;
  const int bh = b * HH + h;
  float* __restrict__ cp = half ? ctxP1 : ctxP0;
  float* __restrict__ lp = half ? Lp1 : Lp0;
  const int cntbh = cnt[b * 2 + half];
  const int kend = ((cntbh + 63) >> 6) << 6;
  const int kt0 = half * 1024;

  // Q fragments for both 64-row subtiles
  short8x fqr0[2], fqr1[2], fqi0[2], fqi1[2];
#pragma unroll
  for (int s2 = 0; s2 < 2; s2++) {
    const int rb = ((qt2 + s2 * 64) >> 4) + wid;
    const int qb = (bh * 128 + rb) * 1024 + lane * 8;
    fqr0[s2] = *(const short8x*)(Qr + qb);
    fqr1[s2] = *(const short8x*)(Qr + qb + 512);
    fqi0[s2] = *(const short8x*)(Qi + qb);
    fqi1[s2] = *(const short8x*)(Qi + qb + 512);
  }
  f32x4 ctxacc[2][4] = {};
  float lsum[2][4] = {{0.f, 0.f, 0.f, 0.f}, {0.f, 0.f, 0.f, 0.f}};

  const int sf0 = wid * 4;

  for (int ktl = 0; ktl < kend; ktl += 64) {
    const int kt = kt0 + ktl;
    const int rbb = bh * 128 + (kt >> 4);
    __syncthreads();   // protect prior-iteration Ks reads
#pragma unroll
    for (int fi = 0; fi < 4; fi++) {
      int f = sf0 + fi;
      int arr = f >> 3, rbl = (f >> 1) & 3, ks = f & 1;
      const unsigned short* src = (arr ? Ki : Kr) + ((size_t)(rbb + rbl) * 2 + ks) * 512 + lane * 8;
      gload16(src, &Ks[arr][rbl][ks][0]);
    }
    __syncthreads();   // staged data visible to all waves
#pragma unroll
    for (int nb = 0; nb < 4; nb++) {
      const int j = ktl + nb * 16 + l15;           // compacted-local index
      short8x bkr0 = *(const short8x*)&Ks[0][nb][0][lane * 8];
      short8x bkr1 = *(const short8x*)&Ks[0][nb][1][lane * 8];
      short8x bki0 = *(const short8x*)&Ks[1][nb][0][lane * 8];
      short8x bki1 = *(const short8x*)&Ks[1][nb][1][lane * 8];
#pragma unroll
      for (int s2 = 0; s2 < 2; s2++) {
        f32x4 sr = {0.f, 0.f, 0.f, 0.f};
        sr = mfma16(fqr0[s2], bkr0, sr);  sr = mfma16(fqr1[s2], bkr1, sr);
        sr = mfma16(fqi0[s2], bki0, sr);  sr = mfma16(fqi1[s2], bki1, sr);
        f32x4 sa = {0.f, 0.f, 0.f, 0.f};
        sa = mfma16(fqi0[s2], bkr0, sa);  sa = mfma16(fqi1[s2], bkr1, sa);
        f32x4 sb = {0.f, 0.f, 0.f, 0.f};
        sb = mfma16(fqr0[s2], bki0, sb);  sb = mfma16(fqr1[s2], bki1, sb);
#pragma unroll
        for (int r = 0; r < 4; r++) {
          float a = sr[r];
          float d = sa[r] - sb[r];
          float r2 = __builtin_fmaf(a, a, d * d);
          float inv = __builtin_amdgcn_rsqf(r2);
          float arg = inv * __builtin_fmaf(C1F, r2, C2F * a);
          float p = (j < cntbh) ? __builtin_amdgcn_exp2f(arg) : 0.0f;  // select, not mul
          lsum[s2][r] += p;
          Ps[s2][wid][quad * 4 + r][nb * 16 + l15] = f2b_fast(p);
        }
      }
    }
    // PV: V loaded once (global), feeds both subtiles. V pad rows pre-zeroed.
#pragma unroll
    for (int ks = 0; ks < 2; ks++)
#pragma unroll
      for (int db = 0; db < 4; db++) {
        int voff = ((bh * 4 + db) * 64 + (kt >> 5) + ks) * 512 + lane * 8;
        short8x bv = *(const short8x*)(VT + voff);
        short8x ap0 = *(const short8x*)&Ps[0][wid][l15][ks * 32 + quad * 8];
        short8x ap1 = *(const short8x*)&Ps[1][wid][l15][ks * 32 + quad * 8];
        ctxacc[0][db] = mfma16(ap0, bv, ctxacc[0][db]);
        ctxacc[1][db] = mfma16(ap1, bv, ctxacc[1][db]);
      }
  }
#pragma unroll
  for (int s2 = 0; s2 < 2; s2++) {
#pragma unroll
    for (int r = 0; r < 4; r++) {
#pragma unroll
      for (int off = 1; off < 16; off <<= 1) lsum[s2][r] += __shfl_xor(lsum[s2][r], off, 64);
    }
#pragma unroll
    for (int r = 0; r < 4; r++) {
      int s = qt2 + s2 * 64 + wid * 16 + quad * 4 + r;
#pragma unroll
      for (int db = 0; db < 4; db++)
        cp[((size_t)b * SS + s) * DD + h * DKK + db * 16 + l15] = ctxacc[s2][db][r];
      if (l15 == 0) lp[(size_t)bh * SS + s] = lsum[s2][r];
    }
  }
}

// ---------------- combine: ctx_bf16 = (P0+P1) / (L0+L1)
__global__ __launch_bounds__(256) void combine_kernel(
    const float* __restrict__ ctxP0, const float* __restrict__ ctxP1,
    const float* __restrict__ Lp0, const float* __restrict__ Lp1,
    unsigned short* __restrict__ ctx) {
  int idx = blockIdx.x * 256 + threadIdx.x;   // 1048576 threads
  int g = idx * 4;
  int c = g & 1023, s = (g >> 10) & 2047, b = g >> 21;
  int h = c >> 6;
  size_t loff = (size_t)(b * HH + h) * SS + s;
  float linv = 1.0f / (Lp0[loff] + Lp1[loff]);
  float4 p0 = *(const float4*)(ctxP0 + g);
  float4 p1 = *(const float4*)(ctxP1 + g);
  ushort4 o;
  o.x = f2b((p0.x + p1.x) * linv);
  o.y = f2b((p0.y + p1.y) * linv);
  o.z = f2b((p0.z + p1.z) * linv);
  o.w = f2b((p0.w + p1.w) * linv);
  *(ushort4*)(ctx + g) = o;
}

// ---------------- output GEMM: out = ctx @ WoT^T + bias (64x128 tiles, 512 blocks)
__global__ __launch_bounds__(256, 2) void gemm_out_kernel(
    const unsigned short* __restrict__ A, const unsigned short* __restrict__ Bt,
    const float* __restrict__ bias, float* __restrict__ out) {
  constexpr int K = 1024;
  __shared__ __attribute__((aligned(16))) unsigned short As[64][32];
  __shared__ __attribute__((aligned(16))) unsigned short Bs[128][32];
  const int tid = threadIdx.x;
  const int m0 = blockIdx.x * 64;
  const int n0 = blockIdx.y * 128;
  const int lane = tid & 63, wid = tid >> 6;
  const int l15 = lane & 15, quad = lane >> 4;
  const int wm = (wid & 1) * 32, wn = (wid >> 1) * 64;
  const int r4 = lane >> 2, c8 = (lane & 3) * 8;
  f32x4 acc[2][4] = {};
  const unsigned short* pa0 = A + (size_t)(m0 + wid * 16 + r4) * K + c8;
  const unsigned short* pb0 = Bt + (size_t)(n0 + wid * 16 + r4) * K + c8;
  const unsigned short* pb1 = pb0 + (size_t)64 * K;
  unsigned short* la0 = &As[wid * 16][0];
  unsigned short* lb0 = &Bs[wid * 16][0];
  unsigned short* lb1 = &Bs[64 + wid * 16][0];
  for (int k0 = 0; k0 < K; k0 += 32) {
    __syncthreads();
    gload16(pa0, la0);
    gload16(pb0, lb0);  gload16(pb1, lb1);
    pa0 += 32; pb0 += 32; pb1 += 32;
    __syncthreads();
    short8x af[2], bfr[4];
#pragma unroll
    for (int i = 0; i < 2; i++) af[i]  = *(const short8x*)&As[wm + i * 16 + l15][quad * 8];
#pragma unroll
    for (int i = 0; i < 4; i++) bfr[i] = *(const short8x*)&Bs[wn + i * 16 + l15][quad * 8];
#pragma unroll
    for (int mi = 0; mi < 2; mi++)
#pragma unroll
      for (int ni = 0; ni < 4; ni++)
        acc[mi][ni] = mfma16(af[mi], bfr[ni], acc[mi][ni]);
  }
#pragma unroll
  for (int mi = 0; mi < 2; mi++)
#pragma unroll
    for (int ni = 0; ni < 4; ni++) {
      int gn = n0 + wn + ni * 16 + l15;
      float bv = bias[gn];
#pragma unroll
      for (int r = 0; r < 4; r++) {
        int gm = m0 + wm + mi * 16 + quad * 4 + r;
        out[(size_t)gm * 1024 + gn] = acc[mi][ni][r] + bv;
      }
    }
}

// ---------------- probs_mean over COMPACTED keys, K staged in LDS;
// out2 pre-zeroed, valid columns scattered via idx.
__global__ __launch_bounds__(256, 4) void probsmean_kernel(
    const unsigned short* __restrict__ Qr, const unsigned short* __restrict__ Qi,
    const unsigned short* __restrict__ Kr, const unsigned short* __restrict__ Ki,
    const int* __restrict__ cnt, const unsigned short* __restrict__ idxT,
    const float* __restrict__ Lp0, const float* __restrict__ Lp1,
    float* __restrict__ out2) {
  __shared__ __attribute__((aligned(16))) unsigned short Ks[2][4][2][512];
  const int tid = threadIdx.x, lane = tid & 63, wid = tid >> 6;
  const int l15 = lane & 15, quad = lane >> 4;
  const int qt = blockIdx.x * 64;
  const int b = blockIdx.z;
  const int c0 = cnt[b * 2], c1 = cnt[b * 2 + 1];
  const int t0n = (c0 + 63) >> 6;
  const int t1n = (c1 + 63) >> 6;
  const int t = blockIdx.y;
  int half, jl0, cnth;
  if (t < t0n)            { half = 0; jl0 = t * 64;         cnth = c0; }
  else if (t < t0n + t1n) { half = 1; jl0 = (t - t0n) * 64; cnth = c1; }
  else return;  // out2 pre-zeroed (block-uniform exit, before any barrier)
  const int qrow0 = qt + wid * 16;
  const int qrb = (qt >> 4) + wid;
  const int ktb = half * 64 + (jl0 >> 4);
  const int sf0 = wid * 4;
  int korig[4]; bool vld[4];
#pragma unroll
  for (int nb = 0; nb < 4; nb++) {
    int j = jl0 + nb * 16 + l15;
    vld[nb] = j < cnth;
    korig[nb] = idxT[(b * 2 + half) * 1024 + j];
  }
  float psum[4][4] = {};  // [nb][r]
  for (int h = 0; h < HH; h++) {
    const int bh = b * HH + h;
    const int qoff = (bh * 128 + qrb) * 1024 + lane * 8;
    short8x fqr0 = *(const short8x*)(Qr + qoff);
    short8x fqr1 = *(const short8x*)(Qr + qoff + 512);
    short8x fqi0 = *(const short8x*)(Qi + qoff);
    short8x fqi1 = *(const short8x*)(Qi + qoff + 512);
    const float4 lv0 = *(const float4*)(Lp0 + (size_t)bh * SS + qrow0 + quad * 4);
    const float4 lv1 = *(const float4*)(Lp1 + (size_t)bh * SS + qrow0 + quad * 4);
    float li[4];
    li[0] = 1.0f / (lv0.x + lv1.x); li[1] = 1.0f / (lv0.y + lv1.y);
    li[2] = 1.0f / (lv0.z + lv1.z); li[3] = 1.0f / (lv0.w + lv1.w);
    // stage this head's 16 K frags (wave w: frags 4w..4w+3)
    const int rbb = bh * 128 + ktb;
    __syncthreads();   // protect prior-iteration Ks reads
#pragma unroll
    for (int fi = 0; fi < 4; fi++) {
      int f = sf0 + fi;
      int arr = f >> 3, rbl = (f >> 1) & 3, ks = f & 1;
      const unsigned short* src = (arr ? Ki : Kr) + ((size_t)(rbb + rbl) * 2 + ks) * 512 + lane * 8;
      gload16(src, &Ks[arr][rbl][ks][0]);
    }
    __syncthreads();   // staged data visible
#pragma unroll
    for (int nb = 0; nb < 4; nb++) {
      short8x bkr0 = *(const short8x*)&Ks[0][nb][0][lane * 8];
      short8x bkr1 = *(const short8x*)&Ks[0][nb][1][lane * 8];
      short8x bki0 = *(const short8x*)&Ks[1][nb][0][lane * 8];
      short8x bki1 = *(const short8x*)&Ks[1][nb][1][lane * 8];
      f32x4 sr = {0.f, 0.f, 0.f, 0.f};
      sr = mfma16(fqr0, bkr0, sr);  sr = mfma16(fqr1, bkr1, sr);
      sr = mfma16(fqi0, bki0, sr);  sr = mfma16(fqi1, bki1, sr);
      f32x4 sa = {0.f, 0.f, 0.f, 0.f};  // Qi.Kr
      sa = mfma16(fqi0, bkr0, sa);  sa = mfma16(fqi1, bkr1, sa);
      f32x4 sb = {0.f, 0.f, 0.f, 0.f};  // Qr.Ki
      sb = mfma16(fqr0, bki0, sb);  sb = mfma16(fqr1, bki1, sb);
#pragma unroll
      for (int r = 0; r < 4; r++) {
        float a = sr[r];
        float d = sa[r] - sb[r];
        float r2 = __builtin_fmaf(a, a, d * d);
        float inv = __builtin_amdgcn_rsqf(r2);
        float arg = inv * __builtin_fmaf(C1F, r2, C2F * a);
        float p = vld[nb] ? __builtin_amdgcn_exp2f(arg) * li[r] : 0.0f;  // select
        psum[nb][r] += p;
      }
    }
  }
#pragma unroll
  for (int nb = 0; nb < 4; nb++)
#pragma unroll
    for (int r = 0; r < 4; r++) {
      if (vld[nb]) {
        int qrow = qrow0 + quad * 4 + r;
        out2[((size_t)b * SS + qrow) * SS + korig[nb]] = psum[nb][r] * 0.0625f;
      }
    }
}

extern "C" void kernel_launch(void* const* d_in, const int* in_sizes, int n_in,
                              void* d_out, int out_size, void* d_ws, size_t ws_size,
                              hipStream_t stream) {
  const float* z_real = (const float*)d_in[0];
  const float* z_imag = (const float*)d_in[1];
  const float* Wq_r = (const float*)d_in[2];
  const float* Wq_i = (const float*)d_in[3];
  const float* Wk_r = (const float*)d_in[4];
  const float* Wk_i = (const float*)d_in[5];
  const float* Wv   = (const float*)d_in[6];
  const float* Wo_w = (const float*)d_in[7];
  const float* Wo_b = (const float*)d_in[8];
  const int*   mask = (const int*)d_in[9];
  char* ws = (char*)d_ws;

  // ws layout (bytes). ctxP0/ctxP1 ALIAS WcatT/Xcat: dead after gemm_proj (stream-serial).
  constexpr size_t QKV_BYTES = 8388608;  // B*H*S*DK*2
  unsigned short* Qr   = (unsigned short*)(ws + 0);
  unsigned short* Qi   = (unsigned short*)(ws + QKV_BYTES);
  unsigned short* Kr   = (unsigned short*)(ws + 2 * QKV_BYTES);
  unsigned short* Ki   = (unsigned short*)(ws + 3 * QKV_BYTES);
  unsigned short* VT   = (unsigned short*)(ws + 4 * QKV_BYTES);
  unsigned short* ctx  = (unsigned short*)(ws + 5 * QKV_BYTES);              // 8 MB bf16
  unsigned short* WcatT= (unsigned short*)(ws + 50331648);                   // 20 MB
  unsigned short* WoT  = (unsigned short*)(ws + 71303168);                   // 2 MB
  unsigned short* Xcat = (unsigned short*)(ws + 73400320);                   // 16 MB
  float* ctxP0 = (float*)(ws + 50331648);                                    // aliases WcatT (16 MB)
  float* ctxP1 = (float*)(ws + 73400320);                                    // aliases Xcat (16 MB)
  float* Lp0   = (float*)(ws + 90177536);                                    // 256 KB
  float* Lp1   = (float*)(ws + 90439680);                                    // 256 KB

  float* out  = (float*)d_out;
  float* out2 = out + (size_t)BB * SS * DD;

  // Compaction tables in d_out scratch (dead until gemm_out; probsmean before it).
  unsigned short* posT = (unsigned short*)out;       // [2][2048] = 8 KB
  unsigned short* idxT = posT + 4096;                // [2][2][1024] = 8 KB
  int* cntT = (int*)(idxT + 4096);                   // [2][2]
  // Xc2 (compacted X rows for K/V projection, 16 MB) aliases out2 scratch:
  // dead after gemm_proj; out2 zeroing moved to after gemm_proj.
  unsigned short* Xc2 = (unsigned short*)out2;

  mask_scan_kernel<<<dim3(4), dim3(256), 0, stream>>>(mask, posT, idxT, cntT);
  pack_w_kernel<<<dim3(2816), dim3(256), 0, stream>>>(Wq_r, Wq_i, Wk_r, Wk_i, Wv, Wo_w, WcatT, WoT);
  pack_x_kernel<<<dim3(4096), dim3(256), 0, stream>>>(z_real, z_imag, posT, Xcat, Xc2);
  zero_kernel<<<dim3(2048), dim3(256), 0, stream>>>((float4*)VT);            // 8 MB: V pad rows = 0
  gemm_proj_kernel<<<dim3(32, 40), dim3(256), 0, stream>>>(Xcat, Xc2, WcatT, cntT, Qr, Qi, Kr, Ki, VT);
  zero_kernel<<<dim3(8192), dim3(256), 0, stream>>>((float4*)out2);          // 32 MB: masked cols = 0
  flash_kernel<<<dim3(16, 16, 4), dim3(256), 0, stream>>>(Qr, Qi, Kr, Ki, VT, cntT, ctxP0, ctxP1, Lp0, Lp1);
  probsmean_kernel<<<dim3(32, 32, 2), dim3(256), 0, stream>>>(Qr, Qi, Kr, Ki, cntT, idxT, Lp0, Lp1, out2);
  combine_kernel<<<dim3(4096), dim3(256), 0, stream>>>(ctxP0, ctxP1, Lp0, Lp1, ctx);
  gemm_out_kernel<<<dim3(64, 8), dim3(256), 0, stream>>>(ctx, WoT, Wo_b, out);
}

// Round 12
// 370.674 us; speedup vs baseline: 1.9723x; 1.0063x over previous
//
#include <hip/hip_runtime.h>
#include <cstdint>
#include <cstddef>

#define BB 2
#define SS 2048
#define DD 1024
#define HH 16
#define DKK 64

typedef __attribute__((ext_vector_type(8))) short short8x;
typedef __attribute__((ext_vector_type(4))) float f32x4;

__device__ __forceinline__ unsigned short f2b(float f) {
  union { float f; unsigned u; } v; v.f = f;
  unsigned r = (v.u + 0x7fffu + ((v.u >> 16) & 1u)) >> 16;  // RNE
  return (unsigned short)r;
}

// hot-path bf16: round-half-up, 2 VALU (vs ~5 for RNE). Used only for Ps probabilities.
__device__ __forceinline__ unsigned short f2b_fast(float f) {
  union { float f; unsigned u; } v; v.f = f;
  return (unsigned short)((v.u + 0x8000u) >> 16);
}

__device__ __forceinline__ f32x4 mfma16(short8x a, short8x b, f32x4 c) {
  return __builtin_amdgcn_mfma_f32_16x16x32_bf16(a, b, c, 0, 0, 0);
}

// async global->LDS, 16B per lane. LDS dest = wave-uniform base + lane*16 (implicit).
__device__ __forceinline__ void gload16(const unsigned short* g, unsigned short* l) {
  __builtin_amdgcn_global_load_lds(
      (__attribute__((address_space(1))) unsigned int*)g,
      (__attribute__((address_space(3))) unsigned int*)l,
      16, 0, 0);
}

// Fragment-major Q/K layout (R5). R6: fixed m=0. R7: K-split + combine. R8: raw-HW
// transcendentals. R9 FAILED (flash spill at 8/EU). R10: XCD swizzle on flash.
// R11-R14: gemm_proj (256,5)+gload_lds+V-K1024. R12: K-compaction. R15: pack_w
// transpose + flash 128-row tiles. R16: flash kt-outer, gemm_out 64x128.
// R17: K-LDS staging in flash/probsmean, pack_x vectorized. R18: compacted-M K/V
// projection (0.72x FLOPs) -- but occ 46->28: dead blocks clustered in dispatch
// order, live work (3.25 equiv/CU) quantized badly (107us vs ~83 ideal).
// R19 (this round): EXPLICIT BLOCK SCHEDULE for gemm_proj. build_sched (1 block)
// writes a 1280-entry (bx,by) table: phase1 = 512 Q tiles (K=2048), phase2 =
// 16*T active K tiles (T = sum ceil(cnt/128)), phase3 = 8*T V tiles (K=1024,
// lightest last ~ LPT). Blocks >= nact exit instantly AND are dispatched last ->
// pure backfill, no makespan cost. Active blocks = first nact dispatches = dense
// packing. Per-block arithmetic unchanged -> bitwise identical.
#define C1F 0.0225421076f  // (1/64)*log2e
#define C2F 0.0541010849f  // (0.3/8)*log2e

// ---------------- pack weights: tiled transpose, coalesced both sides
__global__ __launch_bounds__(256) void pack_w_kernel(
    const float* __restrict__ Wq_r, const float* __restrict__ Wq_i,
    const float* __restrict__ Wk_r, const float* __restrict__ Wk_i,
    const float* __restrict__ Wv, const float* __restrict__ Wo,
    unsigned short* __restrict__ WcatT, unsigned short* __restrict__ WoT) {
  __shared__ float tile[64][65];
  const int tid = threadIdx.x;
  int bid = blockIdx.x;
  if (bid < 2560) {
    const int kt = bid & 31, nt = bid >> 5;
    const int k0 = kt * 64, n0 = nt * 64;
    const int q = n0 >> 10, j0 = n0 & 1023;
    const float* src;
    float sgn = 1.0f;
    bool zero = false;
    if (k0 < 1024) {
      src = (q == 0) ? Wq_r : (q == 1) ? Wq_i : (q == 2) ? Wk_r : (q == 3) ? Wk_i : Wv;
    } else {
      if (q == 0)      { src = Wq_i; sgn = -1.0f; }
      else if (q == 1) { src = Wq_r; }
      else if (q == 2) { src = Wk_i; sgn = -1.0f; }
      else if (q == 3) { src = Wk_r; }
      else             { src = Wv; zero = true; }
    }
    const int ks0 = k0 & 1023;
    if (!zero) {
#pragma unroll
      for (int i = 0; i < 16; i++) {
        int idx = i * 256 + tid;
        int r = idx >> 6, c = idx & 63;
        tile[r][c] = src[(size_t)(ks0 + r) * 1024 + j0 + c];
      }
      __syncthreads();
#pragma unroll
      for (int i = 0; i < 16; i++) {
        int idx = i * 256 + tid;
        int nr = idx >> 6, kc = idx & 63;
        WcatT[(size_t)(n0 + nr) * 2048 + k0 + kc] = f2b(sgn * tile[kc][nr]);
      }
    } else {
#pragma unroll
      for (int i = 0; i < 16; i++) {
        int idx = i * 256 + tid;
        int nr = idx >> 6, kc = idx & 63;
        WcatT[(size_t)(n0 + nr) * 2048 + k0 + kc] = 0;
      }
    }
  } else {
    bid -= 2560;
    const int kt = bid & 15, nt = bid >> 4;
    const int k0 = kt * 64, n0 = nt * 64;
#pragma unroll
    for (int i = 0; i < 16; i++) {
      int idx = i * 256 + tid;
      int r = idx >> 6, c = idx & 63;
      tile[r][c] = Wo[(size_t)(k0 + r) * 1024 + n0 + c];
    }
    __syncthreads();
#pragma unroll
    for (int i = 0; i < 16; i++) {
      int idx = i * 256 + tid;
      int nr = idx >> 6, kc = idx & 63;
      WoT[(size_t)(n0 + nr) * 1024 + k0 + kc] = f2b(tile[kc][nr]);
    }
  }
}

// ---------------- pack X (scatter unmasked rows into Xc2 segments)
__global__ void pack_x_kernel(const float* __restrict__ zr, const float* __restrict__ zi,
                              const unsigned short* __restrict__ pos,
                              unsigned short* __restrict__ X,
                              unsigned short* __restrict__ Xc2) {
  int gid = blockIdx.x * 256 + threadIdx.x;  // 1048576 threads x 8 elems
  int k8 = (gid & 255) << 3;                 // 0..2047 step 8 (never straddles 1024)
  int m = gid >> 8;
  const float* src = (k8 < 1024) ? (zr + (size_t)m * 1024 + k8)
                                 : (zi + (size_t)m * 1024 + (k8 - 1024));
  float4 a = *(const float4*)src;
  float4 c = *(const float4*)(src + 4);
  ushort4 o0; o0.x = f2b(a.x); o0.y = f2b(a.y); o0.z = f2b(a.z); o0.w = f2b(a.w);
  ushort4 o1; o1.x = f2b(c.x); o1.y = f2b(c.y); o1.z = f2b(c.z); o1.w = f2b(c.w);
  *(ushort4*)(X + (size_t)gid * 8) = o0;
  *(ushort4*)(X + (size_t)gid * 8 + 4) = o1;
  unsigned short pp = pos[m];
  if (pp != 0xFFFFu) {
    int b = m >> 11, s = m & 2047, half = s >> 10;
    size_t drow = (size_t)((b * 2 + half) * 1024 + pp);
    *(ushort4*)(Xc2 + drow * 2048 + k8) = o0;
    *(ushort4*)(Xc2 + drow * 2048 + k8 + 4) = o1;
  }
}

// ---------------- generic zero (float4 granularity)
__global__ void zero_kernel(float4* __restrict__ p) {
  p[(size_t)blockIdx.x * 256 + threadIdx.x] = float4{0.f, 0.f, 0.f, 0.f};
}

// ---------------- mask scan: per (b,half) compaction tables
__global__ void mask_scan_kernel(const int* __restrict__ mask,
                                 unsigned short* __restrict__ pos,
                                 unsigned short* __restrict__ idx,
                                 int* __restrict__ cnt) {
  const int b = blockIdx.x >> 1, half = blockIdx.x & 1;
  __shared__ int sums[256];
  const int t = threadIdx.x;
  const int s0 = half * 1024 + t * 4;
  int m[4];
  int loc = 0;
#pragma unroll
  for (int i = 0; i < 4; i++) { m[i] = mask[b * 2048 + s0 + i]; loc += m[i]; }
  sums[t] = loc;
  __syncthreads();
  for (int off = 1; off < 256; off <<= 1) {
    int v = (t >= off) ? sums[t - off] : 0;
    __syncthreads();
    sums[t] += v;
    __syncthreads();
  }
  int excl = sums[t] - loc;
#pragma unroll
  for (int i = 0; i < 4; i++) {
    int sg = s0 + i;
    if (m[i]) {
      pos[b * 2048 + sg] = (unsigned short)excl;
      idx[(b * 2 + half) * 1024 + excl] = (unsigned short)sg;
      excl++;
    } else {
      pos[b * 2048 + sg] = 0xFFFFu;
    }
  }
  if (t == 255) cnt[b * 2 + half] = sums[255];
}

// ---------------- build schedule (R19): phase1 Q (512), phase2 K (16T), phase3 V (8T)
__global__ void build_sched_kernel(const int* __restrict__ cnt,
                                   ushort2* __restrict__ sched, int* __restrict__ nact) {
  __shared__ int off[5];
  const int t = threadIdx.x;
  if (t == 0) {
    int o = 0;
    for (int g = 0; g < 4; g++) { off[g] = o; o += (cnt[g] + 127) >> 7; }
    off[4] = o;
    *nact = 512 + 24 * o;
  }
  __syncthreads();
  const int T = off[4];
  const int total = 512 + 24 * T;
  for (int idx = t; idx < 1280; idx += 256) {
    ushort2 e;
    if (idx < 512) {
      e.x = (unsigned short)(idx & 31); e.y = (unsigned short)(idx >> 5);
    } else if (idx < 512 + 16 * T) {
      int k = idx - 512, mrank = k >> 4, ny = 16 + (k & 15);
      int g = 0;
      while (g < 3 && off[g + 1] <= mrank) g++;
      e.x = (unsigned short)(g * 8 + (mrank - off[g])); e.y = (unsigned short)ny;
    } else if (idx < total) {
      int k = idx - 512 - 16 * T, mrank = k >> 3, ny = 32 + (k & 7);
      int g = 0;
      while (g < 3 && off[g + 1] <= mrank) g++;
      e.x = (unsigned short)(g * 8 + (mrank - off[g])); e.y = (unsigned short)ny;
    } else {
      e.x = 0; e.y = 0;  // dead tail, never executed
    }
    sched[idx] = e;
  }
}

// ---------------- projection GEMM (R19): 1D grid, schedule-table driven.
__global__ __launch_bounds__(256, 5) void gemm_proj_kernel(
    const unsigned short* __restrict__ A, const unsigned short* __restrict__ Ac,
    const unsigned short* __restrict__ Bt, const int* __restrict__ cnt,
    const ushort2* __restrict__ sched, const int* __restrict__ nact,
    unsigned short* __restrict__ Qr, unsigned short* __restrict__ Qi,
    unsigned short* __restrict__ Kr, unsigned short* __restrict__ Ki,
    unsigned short* __restrict__ VT) {
  constexpr int K = 2048;
  if ((int)blockIdx.x >= *nact) return;           // dead tail (dispatched last)
  const ushort2 e = sched[blockIdx.x];
  const int bx = e.x, by = e.y;
  const int n0 = by * 128;
  const bool qpath = (n0 < 2048);
  const int m0 = bx * 128;
  int cntg = 0;
  if (!qpath) cntg = cnt[bx >> 3];
  __shared__ __attribute__((aligned(16))) unsigned short As[128][32];
  __shared__ __attribute__((aligned(16))) unsigned short Bs[128][32];
  const int tid = threadIdx.x;
  const int lane = tid & 63, wid = tid >> 6;
  const int l15 = lane & 15, quad = lane >> 4;
  const int wm = (wid & 1) * 64, wn = (wid >> 1) * 64;
  const int r4 = lane >> 2, c8 = (lane & 3) * 8;
  // V columns (n >= 4096) have zero weights for k >= 1024: skip exactly.
  const int kmax = (n0 >= 4096) ? 1024 : K;
  f32x4 acc[4][4] = {};
  const unsigned short* Ab = qpath ? A : Ac;
  const unsigned short* pa0 = Ab + (size_t)(m0 + wid * 16 + r4) * K + c8;
  const unsigned short* pa1 = pa0 + (size_t)64 * K;
  const unsigned short* pb0 = Bt + (size_t)(n0 + wid * 16 + r4) * K + c8;
  const unsigned short* pb1 = pb0 + (size_t)64 * K;
  unsigned short* la0 = &As[wid * 16][0];
  unsigned short* la1 = &As[64 + wid * 16][0];
  unsigned short* lb0 = &Bs[wid * 16][0];
  unsigned short* lb1 = &Bs[64 + wid * 16][0];
  for (int k0 = 0; k0 < kmax; k0 += 32) {
    __syncthreads();
    gload16(pa0, la0);  gload16(pa1, la1);
    gload16(pb0, lb0);  gload16(pb1, lb1);
    pa0 += 32; pa1 += 32; pb0 += 32; pb1 += 32;
    __syncthreads();
    short8x af[4], bfr[4];
#pragma unroll
    for (int i = 0; i < 4; i++) af[i]  = *(const short8x*)&As[wm + i * 16 + l15][quad * 8];
#pragma unroll
    for (int i = 0; i < 4; i++) bfr[i] = *(const short8x*)&Bs[wn + i * 16 + l15][quad * 8];
#pragma unroll
    for (int mi = 0; mi < 4; mi++)
#pragma unroll
      for (int ni = 0; ni < 4; ni++)
        acc[mi][ni] = mfma16(af[mi], bfr[ni], acc[mi][ni]);
  }
  if (qpath) {
#pragma unroll
    for (int mi = 0; mi < 4; mi++)
#pragma unroll
      for (int ni = 0; ni < 4; ni++) {
        int gn = n0 + wn + ni * 16 + l15;
        int which = gn >> 10, j = gn & 1023, h = j >> 6, dk = j & 63;
        int ks = dk >> 5, q = (dk >> 3) & 3, e2 = dk & 7;
        unsigned short* dst = which ? Qi : Qr;
#pragma unroll
        for (int r = 0; r < 4; r++) {
          int gm = m0 + wm + mi * 16 + quad * 4 + r;
          int b = gm >> 11, s = gm & 2047;
          int bh = b * HH + h, rb = s >> 4, l = s & 15;
          dst[(size_t)(((bh * 128 + rb) * 2 + ks) * 512 + (q * 16 + l) * 8 + e2)] = f2b(acc[mi][ni][r]);
        }
      }
  } else {
    const int g = bx >> 3;
    const int b = g >> 1, hf = g & 1;
#pragma unroll
    for (int mi = 0; mi < 4; mi++)
#pragma unroll
      for (int ni = 0; ni < 4; ni++) {
        int gn = n0 + wn + ni * 16 + l15;
        if (gn < 4096) {
          // K: slot = local row
          int which = gn >> 10, j = gn & 1023, h = j >> 6, dk = j & 63;
          int ks = dk >> 5, q = (dk >> 3) & 3, e2 = dk & 7;
          unsigned short* dst = (which == 2) ? Kr : Ki;
#pragma unroll
          for (int r = 0; r < 4; r++) {
            int gm = m0 + wm + mi * 16 + quad * 4 + r;
            int local = gm & 1023;
            if (local < cntg) {
              int bh = b * HH + h, rb = hf * 64 + (local >> 4), l = local & 15;
              dst[(size_t)(((bh * 128 + rb) * 2 + ks) * 512 + (q * 16 + l) * 8 + e2)] = f2b(acc[mi][ni][r]);
            }
          }
        } else {
          // V^T: slot = local row
          int j = gn - 4096, h = j >> 6, dk = j & 63;
          int rbv = dk >> 4, lv = dk & 15;
#pragma unroll
          for (int r = 0; r < 4; r++) {
            int gm = m0 + wm + mi * 16 + quad * 4 + r;
            int local = gm & 1023;
            if (local < cntg) {
              int bh = b * HH + h, kc = hf * 32 + (local >> 5), qv = (local >> 3) & 3, ev = local & 7;
              VT[(size_t)(((bh * 4 + rbv) * 64 + kc) * 512 + (qv * 16 + lv) * 8 + ev)] = f2b(acc[mi][ni][r]);
            }
          }
        }
      }
  }
}

// ---------------- flash attention over COMPACTED keys, kt-outer/subtile-inner,
// K staged in LDS. V stays global.
__global__ __launch_bounds__(256, 4) void flash_kernel(
    const unsigned short* __restrict__ Qr, const unsigned short* __restrict__ Qi,
    const unsigned short* __restrict__ Kr, const unsigned short* __restrict__ Ki,
    const unsigned short* __restrict__ VT, const int* __restrict__ cnt,
    float* __restrict__ ctxP0, float* __restrict__ ctxP1,
    float* __restrict__ Lp0, float* __restrict__ Lp1) {
  __shared__ __attribute__((aligned(16))) unsigned short Ps[2][4][16][72];
  __shared__ __attribute__((aligned(16))) unsigned short Ks[2][4][2][512];
  const int tid = threadIdx.x;
  const int lane = tid & 63, wid = tid >> 6;
  const int l15 = lane & 15, quad = lane >> 4;
  // XCD swizzle (bijective, 1024 % 8 == 0): each XCD gets 8 heads of one z.
  int lin = blockIdx.x + 16 * (blockIdx.y + 16 * blockIdx.z);
  lin = ((lin & 7) << 7) | (lin >> 3);
  const int qt2 = (lin & 15) * 128;
  const int h = (lin >> 4) & 15;
  const int z = lin >> 8;
  const int b = z >> 1, half = z & 1;
  const int bh = b * HH + h;
  float* __restrict__ cp = half ? ctxP1 : ctxP0;
  float* __restrict__ lp = half ? Lp1 : Lp0;
  const int cntbh = cnt[b * 2 + half];
  const int kend = ((cntbh + 63) >> 6) << 6;
  const int kt0 = half * 1024;

  // Q fragments for both 64-row subtiles
  short8x fqr0[2], fqr1[2], fqi0[2], fqi1[2];
#pragma unroll
  for (int s2 = 0; s2 < 2; s2++) {
    const int rb = ((qt2 + s2 * 64) >> 4) + wid;
    const int qb = (bh * 128 + rb) * 1024 + lane * 8;
    fqr0[s2] = *(const short8x*)(Qr + qb);
    fqr1[s2] = *(const short8x*)(Qr + qb + 512);
    fqi0[s2] = *(const short8x*)(Qi + qb);
    fqi1[s2] = *(const short8x*)(Qi + qb + 512);
  }
  f32x4 ctxacc[2][4] = {};
  float lsum[2][4] = {{0.f, 0.f, 0.f, 0.f}, {0.f, 0.f, 0.f, 0.f}};

  const int sf0 = wid * 4;

  for (int ktl = 0; ktl < kend; ktl += 64) {
    const int kt = kt0 + ktl;
    const int rbb = bh * 128 + (kt >> 4);
    __syncthreads();   // protect prior-iteration Ks reads
#pragma unroll
    for (int fi = 0; fi < 4; fi++) {
      int f = sf0 + fi;
      int arr = f >> 3, rbl = (f >> 1) & 3, ks = f & 1;
      const unsigned short* src = (arr ? Ki : Kr) + ((size_t)(rbb + rbl) * 2 + ks) * 512 + lane * 8;
      gload16(src, &Ks[arr][rbl][ks][0]);
    }
    __syncthreads();   // staged data visible to all waves
#pragma unroll
    for (int nb = 0; nb < 4; nb++) {
      const int j = ktl + nb * 16 + l15;           // compacted-local index
      short8x bkr0 = *(const short8x*)&Ks[0][nb][0][lane * 8];
      short8x bkr1 = *(const short8x*)&Ks[0][nb][1][lane * 8];
      short8x bki0 = *(const short8x*)&Ks[1][nb][0][lane * 8];
      short8x bki1 = *(const short8x*)&Ks[1][nb][1][lane * 8];
#pragma unroll
      for (int s2 = 0; s2 < 2; s2++) {
        f32x4 sr = {0.f, 0.f, 0.f, 0.f};
        sr = mfma16(fqr0[s2], bkr0, sr);  sr = mfma16(fqr1[s2], bkr1, sr);
        sr = mfma16(fqi0[s2], bki0, sr);  sr = mfma16(fqi1[s2], bki1, sr);
        f32x4 sa = {0.f, 0.f, 0.f, 0.f};
        sa = mfma16(fqi0[s2], bkr0, sa);  sa = mfma16(fqi1[s2], bkr1, sa);
        f32x4 sb = {0.f, 0.f, 0.f, 0.f};
        sb = mfma16(fqr0[s2], bki0, sb);  sb = mfma16(fqr1[s2], bki1, sb);
#pragma unroll
        for (int r = 0; r < 4; r++) {
          float a = sr[r];
          float d = sa[r] - sb[r];
          float r2 = __builtin_fmaf(a, a, d * d);
          float inv = __builtin_amdgcn_rsqf(r2);
          float arg = inv * __builtin_fmaf(C1F, r2, C2F * a);
          float p = (j < cntbh) ? __builtin_amdgcn_exp2f(arg) : 0.0f;  // select, not mul
          lsum[s2][r] += p;
          Ps[s2][wid][quad * 4 + r][nb * 16 + l15] = f2b_fast(p);
        }
      }
    }
    // PV: V loaded once (global), feeds both subtiles. V pad rows pre-zeroed.
#pragma unroll
    for (int ks = 0; ks < 2; ks++)
#pragma unroll
      for (int db = 0; db < 4; db++) {
        int voff = ((bh * 4 + db) * 64 + (kt >> 5) + ks) * 512 + lane * 8;
        short8x bv = *(const short8x*)(VT + voff);
        short8x ap0 = *(const short8x*)&Ps[0][wid][l15][ks * 32 + quad * 8];
        short8x ap1 = *(const short8x*)&Ps[1][wid][l15][ks * 32 + quad * 8];
        ctxacc[0][db] = mfma16(ap0, bv, ctxacc[0][db]);
        ctxacc[1][db] = mfma16(ap1, bv, ctxacc[1][db]);
      }
  }
#pragma unroll
  for (int s2 = 0; s2 < 2; s2++) {
#pragma unroll
    for (int r = 0; r < 4; r++) {
#pragma unroll
      for (int off = 1; off < 16; off <<= 1) lsum[s2][r] += __shfl_xor(lsum[s2][r], off, 64);
    }
#pragma unroll
    for (int r = 0; r < 4; r++) {
      int s = qt2 + s2 * 64 + wid * 16 + quad * 4 + r;
#pragma unroll
      for (int db = 0; db < 4; db++)
        cp[((size_t)b * SS + s) * DD + h * DKK + db * 16 + l15] = ctxacc[s2][db][r];
      if (l15 == 0) lp[(size_t)bh * SS + s] = lsum[s2][r];
    }
  }
}

// ---------------- combine: ctx_bf16 = (P0+P1) / (L0+L1)
__global__ __launch_bounds__(256) void combine_kernel(
    const float* __restrict__ ctxP0, const float* __restrict__ ctxP1,
    const float* __restrict__ Lp0, const float* __restrict__ Lp1,
    unsigned short* __restrict__ ctx) {
  int idx = blockIdx.x * 256 + threadIdx.x;   // 1048576 threads
  int g = idx * 4;
  int c = g & 1023, s = (g >> 10) & 2047, b = g >> 21;
  int h = c >> 6;
  size_t loff = (size_t)(b * HH + h) * SS + s;
  float linv = 1.0f / (Lp0[loff] + Lp1[loff]);
  float4 p0 = *(const float4*)(ctxP0 + g);
  float4 p1 = *(const float4*)(ctxP1 + g);
  ushort4 o;
  o.x = f2b((p0.x + p1.x) * linv);
  o.y = f2b((p0.y + p1.y) * linv);
  o.z = f2b((p0.z + p1.z) * linv);
  o.w = f2b((p0.w + p1.w) * linv);
  *(ushort4*)(ctx + g) = o;
}

// ---------------- output GEMM: out = ctx @ WoT^T + bias (64x128 tiles, 512 blocks)
__global__ __launch_bounds__(256, 2) void gemm_out_kernel(
    const unsigned short* __restrict__ A, const unsigned short* __restrict__ Bt,
    const float* __restrict__ bias, float* __restrict__ out) {
  constexpr int K = 1024;
  __shared__ __attribute__((aligned(16))) unsigned short As[64][32];
  __shared__ __attribute__((aligned(16))) unsigned short Bs[128][32];
  const int tid = threadIdx.x;
  const int m0 = blockIdx.x * 64;
  const int n0 = blockIdx.y * 128;
  const int lane = tid & 63, wid = tid >> 6;
  const int l15 = lane & 15, quad = lane >> 4;
  const int wm = (wid & 1) * 32, wn = (wid >> 1) * 64;
  const int r4 = lane >> 2, c8 = (lane & 3) * 8;
  f32x4 acc[2][4] = {};
  const unsigned short* pa0 = A + (size_t)(m0 + wid * 16 + r4) * K + c8;
  const unsigned short* pb0 = Bt + (size_t)(n0 + wid * 16 + r4) * K + c8;
  const unsigned short* pb1 = pb0 + (size_t)64 * K;
  unsigned short* la0 = &As[wid * 16][0];
  unsigned short* lb0 = &Bs[wid * 16][0];
  unsigned short* lb1 = &Bs[64 + wid * 16][0];
  for (int k0 = 0; k0 < K; k0 += 32) {
    __syncthreads();
    gload16(pa0, la0);
    gload16(pb0, lb0);  gload16(pb1, lb1);
    pa0 += 32; pb0 += 32; pb1 += 32;
    __syncthreads();
    short8x af[2], bfr[4];
#pragma unroll
    for (int i = 0; i < 2; i++) af[i]  = *(const short8x*)&As[wm + i * 16 + l15][quad * 8];
#pragma unroll
    for (int i = 0; i < 4; i++) bfr[i] = *(const short8x*)&Bs[wn + i * 16 + l15][quad * 8];
#pragma unroll
    for (int mi = 0; mi < 2; mi++)
#pragma unroll
      for (int ni = 0; ni < 4; ni++)
        acc[mi][ni] = mfma16(af[mi], bfr[ni], acc[mi][ni]);
  }
#pragma unroll
  for (int mi = 0; mi < 2; mi++)
#pragma unroll
    for (int ni = 0; ni < 4; ni++) {
      int gn = n0 + wn + ni * 16 + l15;
      float bv = bias[gn];
#pragma unroll
      for (int r = 0; r < 4; r++) {
        int gm = m0 + wm + mi * 16 + quad * 4 + r;
        out[(size_t)gm * 1024 + gn] = acc[mi][ni][r] + bv;
      }
    }
}

// ---------------- probs_mean over COMPACTED keys, K staged in LDS;
// out2 pre-zeroed, valid columns scattered via idx.
__global__ __launch_bounds__(256, 4) void probsmean_kernel(
    const unsigned short* __restrict__ Qr, const unsigned short* __restrict__ Qi,
    const unsigned short* __restrict__ Kr, const unsigned short* __restrict__ Ki,
    const int* __restrict__ cnt, const unsigned short* __restrict__ idxT,
    const float* __restrict__ Lp0, const float* __restrict__ Lp1,
    float* __restrict__ out2) {
  __shared__ __attribute__((aligned(16))) unsigned short Ks[2][4][2][512];
  const int tid = threadIdx.x, lane = tid & 63, wid = tid >> 6;
  const int l15 = lane & 15, quad = lane >> 4;
  const int qt = blockIdx.x * 64;
  const int b = blockIdx.z;
  const int c0 = cnt[b * 2], c1 = cnt[b * 2 + 1];
  const int t0n = (c0 + 63) >> 6;
  const int t1n = (c1 + 63) >> 6;
  const int t = blockIdx.y;
  int half, jl0, cnth;
  if (t < t0n)            { half = 0; jl0 = t * 64;         cnth = c0; }
  else if (t < t0n + t1n) { half = 1; jl0 = (t - t0n) * 64; cnth = c1; }
  else return;  // out2 pre-zeroed (block-uniform exit, before any barrier)
  const int qrow0 = qt + wid * 16;
  const int qrb = (qt >> 4) + wid;
  const int ktb = half * 64 + (jl0 >> 4);
  const int sf0 = wid * 4;
  int korig[4]; bool vld[4];
#pragma unroll
  for (int nb = 0; nb < 4; nb++) {
    int j = jl0 + nb * 16 + l15;
    vld[nb] = j < cnth;
    korig[nb] = idxT[(b * 2 + half) * 1024 + j];
  }
  float psum[4][4] = {};  // [nb][r]
  for (int h = 0; h < HH; h++) {
    const int bh = b * HH + h;
    const int qoff = (bh * 128 + qrb) * 1024 + lane * 8;
    short8x fqr0 = *(const short8x*)(Qr + qoff);
    short8x fqr1 = *(const short8x*)(Qr + qoff + 512);
    short8x fqi0 = *(const short8x*)(Qi + qoff);
    short8x fqi1 = *(const short8x*)(Qi + qoff + 512);
    const float4 lv0 = *(const float4*)(Lp0 + (size_t)bh * SS + qrow0 + quad * 4);
    const float4 lv1 = *(const float4*)(Lp1 + (size_t)bh * SS + qrow0 + quad * 4);
    float li[4];
    li[0] = 1.0f / (lv0.x + lv1.x); li[1] = 1.0f / (lv0.y + lv1.y);
    li[2] = 1.0f / (lv0.z + lv1.z); li[3] = 1.0f / (lv0.w + lv1.w);
    // stage this head's 16 K frags (wave w: frags 4w..4w+3)
    const int rbb = bh * 128 + ktb;
    __syncthreads();   // protect prior-iteration Ks reads
#pragma unroll
    for (int fi = 0; fi < 4; fi++) {
      int f = sf0 + fi;
      int arr = f >> 3, rbl = (f >> 1) & 3, ks = f & 1;
      const unsigned short* src = (arr ? Ki : Kr) + ((size_t)(rbb + rbl) * 2 + ks) * 512 + lane * 8;
      gload16(src, &Ks[arr][rbl][ks][0]);
    }
    __syncthreads();   // staged data visible
#pragma unroll
    for (int nb = 0; nb < 4; nb++) {
      short8x bkr0 = *(const short8x*)&Ks[0][nb][0][lane * 8];
      short8x bkr1 = *(const short8x*)&Ks[0][nb][1][lane * 8];
      short8x bki0 = *(const short8x*)&Ks[1][nb][0][lane * 8];
      short8x bki1 = *(const short8x*)&Ks[1][nb][1][lane * 8];
      f32x4 sr = {0.f, 0.f, 0.f, 0.f};
      sr = mfma16(fqr0, bkr0, sr);  sr = mfma16(fqr1, bkr1, sr);
      sr = mfma16(fqi0, bki0, sr);  sr = mfma16(fqi1, bki1, sr);
      f32x4 sa = {0.f, 0.f, 0.f, 0.f};  // Qi.Kr
      sa = mfma16(fqi0, bkr0, sa);  sa = mfma16(fqi1, bkr1, sa);
      f32x4 sb = {0.f, 0.f, 0.f, 0.f};  // Qr.Ki
      sb = mfma16(fqr0, bki0, sb);  sb = mfma16(fqr1, bki1, sb);
#pragma unroll
      for (int r = 0; r < 4; r++) {
        float a = sr[r];
        float d = sa[r] - sb[r];
        float r2 = __builtin_fmaf(a, a, d * d);
        float inv = __builtin_amdgcn_rsqf(r2);
        float arg = inv * __builtin_fmaf(C1F, r2, C2F * a);
        float p = vld[nb] ? __builtin_amdgcn_exp2f(arg) * li[r] : 0.0f;  // select
        psum[nb][r] += p;
      }
    }
  }
#pragma unroll
  for (int nb = 0; nb < 4; nb++)
#pragma unroll
    for (int r = 0; r < 4; r++) {
      if (vld[nb]) {
        int qrow = qrow0 + quad * 4 + r;
        out2[((size_t)b * SS + qrow) * SS + korig[nb]] = psum[nb][r] * 0.0625f;
      }
    }
}

extern "C" void kernel_launch(void* const* d_in, const int* in_sizes, int n_in,
                              void* d_out, int out_size, void* d_ws, size_t ws_size,
                              hipStream_t stream) {
  const float* z_real = (const float*)d_in[0];
  const float* z_imag = (const float*)d_in[1];
  const float* Wq_r = (const float*)d_in[2];
  const float* Wq_i = (const float*)d_in[3];
  const float* Wk_r = (const float*)d_in[4];
  const float* Wk_i = (const float*)d_in[5];
  const float* Wv   = (const float*)d_in[6];
  const float* Wo_w = (const float*)d_in[7];
  const float* Wo_b = (const float*)d_in[8];
  const int*   mask = (const int*)d_in[9];
  char* ws = (char*)d_ws;

  // ws layout (bytes). ctxP0/ctxP1 ALIAS WcatT/Xcat: dead after gemm_proj (stream-serial).
  constexpr size_t QKV_BYTES = 8388608;  // B*H*S*DK*2
  unsigned short* Qr   = (unsigned short*)(ws + 0);
  unsigned short* Qi   = (unsigned short*)(ws + QKV_BYTES);
  unsigned short* Kr   = (unsigned short*)(ws + 2 * QKV_BYTES);
  unsigned short* Ki   = (unsigned short*)(ws + 3 * QKV_BYTES);
  unsigned short* VT   = (unsigned short*)(ws + 4 * QKV_BYTES);
  unsigned short* ctx  = (unsigned short*)(ws + 5 * QKV_BYTES);              // 8 MB bf16
  unsigned short* WcatT= (unsigned short*)(ws + 50331648);                   // 20 MB
  unsigned short* WoT  = (unsigned short*)(ws + 71303168);                   // 2 MB
  unsigned short* Xcat = (unsigned short*)(ws + 73400320);                   // 16 MB
  float* ctxP0 = (float*)(ws + 50331648);                                    // aliases WcatT (16 MB)
  float* ctxP1 = (float*)(ws + 73400320);                                    // aliases Xcat (16 MB)
  float* Lp0   = (float*)(ws + 90177536);                                    // 256 KB
  float* Lp1   = (float*)(ws + 90439680);                                    // 256 KB

  float* out  = (float*)d_out;
  float* out2 = out + (size_t)BB * SS * DD;

  // Compaction tables + schedule in d_out scratch (dead until gemm_out;
  // probsmean reads idxT before combine/gemm_out).
  unsigned short* posT = (unsigned short*)out;       // [2][2048] = 8 KB
  unsigned short* idxT = posT + 4096;                // [2][2][1024] = 8 KB
  int* cntT = (int*)(idxT + 4096);                   // [2][2] = 16 B
  int* nactT = cntT + 4;                             // 4 B
  ushort2* schedT = (ushort2*)(cntT + 8);            // 1280 x 4 B = 5 KB
  // Xc2 (compacted X rows for K/V projection, 16 MB) aliases out2 scratch:
  // dead after gemm_proj; out2 zeroing moved to after gemm_proj.
  unsigned short* Xc2 = (unsigned short*)out2;

  mask_scan_kernel<<<dim3(4), dim3(256), 0, stream>>>(mask, posT, idxT, cntT);
  build_sched_kernel<<<dim3(1), dim3(256), 0, stream>>>(cntT, schedT, nactT);
  pack_w_kernel<<<dim3(2816), dim3(256), 0, stream>>>(Wq_r, Wq_i, Wk_r, Wk_i, Wv, Wo_w, WcatT, WoT);
  pack_x_kernel<<<dim3(4096), dim3(256), 0, stream>>>(z_real, z_imag, posT, Xcat, Xc2);
  zero_kernel<<<dim3(2048), dim3(256), 0, stream>>>((float4*)VT);            // 8 MB: V pad rows = 0
  gemm_proj_kernel<<<dim3(1280), dim3(256), 0, stream>>>(Xcat, Xc2, WcatT, cntT, schedT, nactT, Qr, Qi, Kr, Ki, VT);
  zero_kernel<<<dim3(8192), dim3(256), 0, stream>>>((float4*)out2);          // 32 MB: masked cols = 0
  flash_kernel<<<dim3(16, 16, 4), dim3(256), 0, stream>>>(Qr, Qi, Kr, Ki, VT, cntT, ctxP0, ctxP1, Lp0, Lp1);
  probsmean_kernel<<<dim3(32, 32, 2), dim3(256), 0, stream>>>(Qr, Qi, Kr, Ki, cntT, idxT, Lp0, Lp1, out2);
  combine_kernel<<<dim3(4096), dim3(256), 0, stream>>>(ctxP0, ctxP1, Lp0, Lp1, ctx);
  gemm_out_kernel<<<dim3(64, 8), dim3(256), 0, stream>>>(ctx, WoT, Wo_b, out);
}